// Round 7
// baseline (1022.601 us; speedup 1.0000x reference)
//
#include <hip/hip_runtime.h>
#include <hip/hip_fp16.h>

typedef unsigned short u16;
typedef unsigned int u32;
typedef unsigned long long u64;
typedef __attribute__((ext_vector_type(8))) short bf16x8;   // 8 bf16 = 4 VGPRs
typedef __attribute__((ext_vector_type(4))) float f32x4;    // MFMA 16x16 accumulator

#define NI_ 100000
#define NC_ 10000
#define EII_ 800000
#define ECC_ 100000
#define ECI_ 400000
#define EIC_ 400000
#define B_ 512
#define T_ 50
#define NBK_ 108          // 49 II + 49 CI + 5 CC + 5 IC (2048-dst buckets)
#define ECH_ 4096         // edges per binning chunk

__device__ __forceinline__ float bf2f(u16 u) { return __uint_as_float(((u32)u) << 16); }
__device__ __forceinline__ u16 f2bf(float x) {
    u32 u = __float_as_uint(x);
    return (u16)((u + 0x7FFFu + ((u >> 16) & 1u)) >> 16);   // RNE
}
__device__ __forceinline__ float sigm(float x) { return 1.f / (1.f + expf(-x)); }
__device__ __forceinline__ float gldf(const void* p, size_t i, int isf) {
    return isf ? ((const float*)p)[i] : bf2f(((const u16*)p)[i]);
}
__device__ __forceinline__ float lrelu_c(float v) {
    v = (v >= 0.f) ? v : 0.2f * v;
    return fminf(fmaxf(v, -60.f), 60.f);
}

// init: dtype detect + MFMA layout self-check
__global__ void k_init(const void* __restrict__ item, int* __restrict__ flag)
{
    const int tid = threadIdx.x;
    if (tid < 64) {
        const int l = tid;
        bf16x8 a, b;
        #pragma unroll
        for (int j = 0; j < 8; ++j) {
            int ka = (l >> 4) * 8 + j;
            float av = (float)((((l & 15) * 5 + ka * 3) & 15) - 7);
            float bv = (float)(((ka * 7 + (l & 15) * 11) & 15) - 8);
            a[j] = (short)f2bf(av);
            b[j] = (short)f2bf(bv);
        }
        f32x4 d = {0.f, 0.f, 0.f, 0.f};
        d = __builtin_amdgcn_mfma_f32_16x16x32_bf16(a, b, d, 0, 0, 0);
        bool ok = true;
        #pragma unroll
        for (int j = 0; j < 4; ++j) {
            int row = (l >> 4) * 4 + j, col = l & 15;
            float ref = 0.f;
            for (int k = 0; k < 32; ++k)
                ref += (float)(((row * 5 + k * 3) & 15) - 7) * (float)(((k * 7 + col * 11) & 15) - 8);
            ok = ok && (d[j] == ref);
        }
        unsigned long long vote = __ballot(ok);
        if (l == 0) flag[1] = (vote == ~0ull) ? 1 : 0;
    } else if (tid == 64) {
        const u16* p = (const u16*)item;
        int cnt = 0;
        for (int i = 0; i < 128; ++i) {
            float v = bf2f(p[i]);
            if (fabsf(v) <= 0.0886f) ++cnt;
        }
        flag[0] = (cnt >= 120) ? 0 : 1;
    }
}

__global__ void s_sig(float* __restrict__ out, long n, float code)
{
    long i = (long)blockIdx.x * 256 + threadIdx.x;
    if (i < n) out[i] = (i == 0) ? code : 0.f;
}

// ============ merged pre-pass: hc0 gather | cursor zero | weight pack | war vecs ============
// roles by block range: [0,5000) hc0, [5000,5860) zero, [5860,5940) prepw2, [5940,5943) wvec3
__global__ __launch_bounds__(256) void k_pre(
    const void* __restrict__ cate, const int* __restrict__ cid, float* __restrict__ hc0,
    int* __restrict__ cu0, int* __restrict__ cu1, int* __restrict__ cu2, int* __restrict__ cu3,
    const void* __restrict__ Wp, const void* __restrict__ Wg1, const void* __restrict__ gW,
    u16* __restrict__ whi, u16* __restrict__ wlo,
    const void* __restrict__ ar, float* __restrict__ wars,
    const int* __restrict__ fl)
{
    const int det = fl[0];
    int bid = blockIdx.x, tid = threadIdx.x;
    if (bid < 5000) {
        long i = (long)bid * 256 + tid;
        if (i < (long)NC_ * 128)
            hc0[i] = gldf(cate, (size_t)cid[i >> 7] * 128 + (i & 127), det);
        return;
    }
    bid -= 5000;
    if (bid < 860) {
        int i = bid * 256 + tid;
        if (i < NI_) { cu0[i] = 0; return; } i -= NI_;
        if (i < NI_) { cu1[i] = 0; return; } i -= NI_;
        if (i < NC_) { cu2[i] = 0; return; } i -= NC_;
        if (i < NC_) cu3[i] = 0;
        return;
    }
    bid -= 860;
    if (bid < 80) {
        int s = bid * 256 + tid;
        if (s >= 20480) return;
        const void* src; int K, local; size_t soff;
        if (s < 4096)       { src = Wp;  K = 256; local = s;        soff = 0; }
        else if (s < 8192)  { src = Wg1; K = 256; local = s - 4096; soff = 0; }
        else {
            int t = s - 8192; int m = t >> 11; local = t & 2047; K = 128;
            const int MK[6] = {0, 1, 2, 3, 4, 6};
            src = gW; soff = (size_t)MK[m] * 16384;
        }
        const int KK = K >> 5;
        int r = local & 15, g = (local >> 4) & 3, q2 = local >> 6;
        int kk = q2 % KK, ni = q2 / KK;
        bf16x8 hv, lv;
        #pragma unroll
        for (int j = 0; j < 8; ++j) {
            float x = gldf(src, soff + (size_t)(kk * 32 + 8 * g + j) * 128 + ni * 16 + r, det);
            u16 hb = f2bf(x);
            hv[j] = (short)hb;
            lv[j] = (short)f2bf(x - bf2f(hb));
        }
        *(bf16x8*)(whi + (size_t)s * 8) = hv;
        *(bf16x8*)(wlo + (size_t)s * 8) = lv;
        return;
    }
    bid -= 80;
    if (tid < 128) {
        // wars: g=0 -> (0,2), g=1 -> (0,3), g=2 -> (1,2)
        const int WO[3] = {2 * 16384, 3 * 16384, 6 * 16384};
        const int AO[3] = {2 * 128, 3 * 128, 6 * 128};
        int g = bid, k = tid;
        float a = 0.f;
        for (int c = 0; c < 128; ++c)
            a += gldf(gW, (size_t)WO[g] + (size_t)k * 128 + c, det) * gldf(ar, AO[g] + c, det);
        wars[g * 128 + k] = a;
    }
}

// ================= batched CSR build =================
__global__ __launch_bounds__(256) void k_hist4(
    const int* d0, int E0, const int* d1, int E1,
    const int* d2, int E2, const int* d3, int E3,
    int* c0, int* c1, int* c2, int* c3)
{
    int i = blockIdx.x * 256 + threadIdx.x;
    if (i < E0) { atomicAdd(&c0[d0[i]], 1); return; } i -= E0;
    if (i < E1) { atomicAdd(&c1[d1[i]], 1); return; } i -= E1;
    if (i < E2) { atomicAdd(&c2[d2[i]], 1); return; } i -= E2;
    if (i < E3) atomicAdd(&c3[d3[i]], 1);
}

__device__ __forceinline__ void map4(
    int b, int n0, int n1, int n2, int n3, int& g, int& lb)
{
    int nB0 = (n0 + 1023) >> 10, nB1 = (n1 + 1023) >> 10;
    int nB2 = (n2 + 1023) >> 10;
    if (b < nB0) { g = 0; lb = b; return; } b -= nB0;
    if (b < nB1) { g = 1; lb = b; return; } b -= nB1;
    if (b < nB2) { g = 2; lb = b; return; } b -= nB2;
    g = 3; lb = b;
}

__global__ __launch_bounds__(256) void k_bsum4(
    const int* c0, int n0, const int* c1, int n1,
    const int* c2, int n2, const int* c3, int n3, int* bsum)
{
    int g, lb;
    map4(blockIdx.x, n0, n1, n2, n3, g, lb);
    const int* cnt = (g == 0) ? c0 : (g == 1) ? c1 : (g == 2) ? c2 : c3;
    const int n = (g == 0) ? n0 : (g == 1) ? n1 : (g == 2) ? n2 : n3;
    __shared__ int sh[256];
    int t = threadIdx.x, base = lb * 1024 + t * 4;
    int s = 0;
    #pragma unroll
    for (int j = 0; j < 4; ++j) if (base + j < n) s += cnt[base + j];
    sh[t] = s; __syncthreads();
    for (int o = 128; o > 0; o >>= 1) { if (t < o) sh[t] += sh[t + o]; __syncthreads(); }
    if (t == 0) bsum[g * 256 + lb] = sh[0];
}

__global__ void k_scanb4(
    int* bsum, int n0, int n1, int n2, int n3,
    int* r0, int* r1, int* r2, int* r3)
{
    if (threadIdx.x != 0) return;
    int g = blockIdx.x;
    int n = (g == 0) ? n0 : (g == 1) ? n1 : (g == 2) ? n2 : n3;
    int* rp = (g == 0) ? r0 : (g == 1) ? r1 : (g == 2) ? r2 : r3;
    int nB = (n + 1023) >> 10;
    int run = 0;
    for (int i = 0; i < nB; ++i) { int v = bsum[g * 256 + i]; bsum[g * 256 + i] = run; run += v; }
    rp[n] = run;
}

__global__ __launch_bounds__(256) void k_scanfinal4(
    int* c0, int n0, int* c1, int n1, int* c2, int n2, int* c3, int n3,
    const int* bsum, int* r0, int* r1, int* r2, int* r3)
{
    int g, lb;
    map4(blockIdx.x, n0, n1, n2, n3, g, lb);
    int* cnt = (g == 0) ? c0 : (g == 1) ? c1 : (g == 2) ? c2 : c3;
    const int n = (g == 0) ? n0 : (g == 1) ? n1 : (g == 2) ? n2 : n3;
    int* rowptr = (g == 0) ? r0 : (g == 1) ? r1 : (g == 2) ? r2 : r3;
    __shared__ int sh[256];
    int t = threadIdx.x, base = lb * 1024 + t * 4;
    int c0v = (base + 0 < n) ? cnt[base + 0] : 0;
    int c1v = (base + 1 < n) ? cnt[base + 1] : 0;
    int c2v = (base + 2 < n) ? cnt[base + 2] : 0;
    int c3v = (base + 3 < n) ? cnt[base + 3] : 0;
    int tsum = c0v + c1v + c2v + c3v;
    sh[t] = tsum; __syncthreads();
    for (int s = 1; s < 256; s <<= 1) {
        int v = (t >= s) ? sh[t - s] : 0;
        __syncthreads();
        sh[t] += v;
        __syncthreads();
    }
    int off = bsum[g * 256 + lb] + sh[t] - tsum;
    if (base + 0 < n) { rowptr[base + 0] = off; off += c0v; }
    if (base + 1 < n) { rowptr[base + 1] = off; off += c1v; }
    if (base + 2 < n) { rowptr[base + 2] = off; off += c2v; }
    if (base + 3 < n) { rowptr[base + 3] = off; off += c3v; }
}

// bucket cursors (108) seeded from rowptr at 2048-dst boundaries
__global__ void k_gcur(
    const int* rpII, const int* rpCI, const int* rpCC, const int* rpIC, int* gcur)
{
    int t = threadIdx.x;
    if (t < 49)       gcur[t] = rpII[t << 11];
    else if (t < 98)  gcur[t] = rpCI[(t - 49) << 11];
    else if (t < 103) gcur[t] = rpCC[(t - 98) << 11];
    else if (t < NBK_) gcur[t] = rpIC[(t - 103) << 11];
}

// phase A: bin edges by 2048-dst bucket; LDS-compact, burst-write (src<<11|dstlocal)
__global__ __launch_bounds__(256) void k_binA(
    const int* s0, const int* d0, const int* s1, const int* d1,
    const int* s2, const int* d2, const int* s3, const int* d3,
    int* __restrict__ gcur,
    u32* __restrict__ b0, u32* __restrict__ b1,
    u32* __restrict__ b2, u32* __restrict__ b3)
{
    __shared__ u32 stag[ECH_];
    __shared__ int cnt[NBK_], base_l[NBK_ + 1], gbase[NBK_], cur_l[NBK_];
    const int tid = threadIdx.x;
    const long estart = (long)blockIdx.x * ECH_;
    const long ET = (long)EII_ + ECI_ + ECC_ + EIC_;
    for (int b = tid; b < NBK_; b += 256) cnt[b] = 0;
    __syncthreads();
    int gidv[16]; u32 pk[16];
    #pragma unroll
    for (int j = 0; j < 16; ++j) {
        long i = estart + j * 256 + tid;
        gidv[j] = -1;
        if (i < ET) {
            int src, dst, boff;
            long ii = i;
            if (ii < EII_) { src = s0[ii]; dst = d0[ii]; boff = 0; }
            else { ii -= EII_;
            if (ii < ECI_) { src = s1[ii]; dst = d1[ii]; boff = 49; }
            else { ii -= ECI_;
            if (ii < ECC_) { src = s2[ii]; dst = d2[ii]; boff = 98; }
            else { ii -= ECC_; src = s3[ii]; dst = d3[ii]; boff = 103; } } }
            int gid = boff + (dst >> 11);
            gidv[j] = gid;
            pk[j] = ((u32)src << 11) | (u32)(dst & 2047);
            atomicAdd(&cnt[gid], 1);
        }
    }
    __syncthreads();
    if (tid == 0) {
        int run = 0;
        for (int b = 0; b < NBK_; ++b) { base_l[b] = run; run += cnt[b]; }
        base_l[NBK_] = run;
    }
    __syncthreads();
    if (tid < NBK_) {
        gbase[tid] = cnt[tid] ? atomicAdd(&gcur[tid], cnt[tid]) : 0;
        cur_l[tid] = base_l[tid];
    }
    __syncthreads();
    #pragma unroll
    for (int j = 0; j < 16; ++j)
        if (gidv[j] >= 0) {
            int l = atomicAdd(&cur_l[gidv[j]], 1);
            stag[l] = pk[j];
        }
    __syncthreads();
    const int total = base_l[NBK_];
    for (int t = tid; t < total; t += 256) {
        int lo = 0, hi = NBK_ - 1;
        while (lo < hi) { int mid = (lo + hi + 1) >> 1; if (base_l[mid] <= t) lo = mid; else hi = mid - 1; }
        int pos = gbase[lo] + (t - base_l[lo]);
        u32* bp = (lo < 49) ? b0 : (lo < 98) ? b1 : (lo < 103) ? b2 : b3;
        bp[pos] = stag[t];
    }
}

// phase B: per-bucket fine fill — scattered writes confined to one block's window
__global__ __launch_bounds__(256) void k_binB(
    const int* rpII, const int* rpCI, const int* rpCC, const int* rpIC,
    const u32* b0, const u32* b1, const u32* b2, const u32* b3,
    int* csII, int* csCI, int* csCC, int* csIC)
{
    __shared__ int cur[2048];
    const int gid = blockIdx.x, tid = threadIdx.x;
    const int* rp; const u32* bp; int* cs; int b, n;
    if (gid < 49)       { rp = rpII; bp = b0; cs = csII; b = gid;       n = NI_; }
    else if (gid < 98)  { rp = rpCI; bp = b1; cs = csCI; b = gid - 49;  n = NI_; }
    else if (gid < 103) { rp = rpCC; bp = b2; cs = csCC; b = gid - 98;  n = NC_; }
    else                { rp = rpIC; bp = b3; cs = csIC; b = gid - 103; n = NC_; }
    const int dz = b << 11;
    const int d1v = (dz + 2048 < n) ? dz + 2048 : n;
    const int ndl = d1v - dz;
    for (int dl = tid; dl < ndl; dl += 256) cur[dl] = rp[dz + dl];
    __syncthreads();
    const int e0 = rp[dz], e1 = rp[d1v];
    for (int e = e0 + tid; e < e1; e += 256) {
        u32 p = bp[e];
        int dl = (int)(p & 2047);
        int pos = atomicAdd(&cur[dl], 1);
        cs[pos] = (int)(p >> 11);
    }
}

// ========== GAT aggregation (fused, shuffle-cached alphas, fp16 z, 8-wide ILP) ==========
__device__ __forceinline__ void gat_gather(
    const int* __restrict__ rp, const int* __restrict__ cs,
    const float* __restrict__ sl, float srd, const __half2* __restrict__ z,
    int w, int lane, float& a0, float& a1)
{
    const int start = rp[w], end = rp[w + 1];
    if (end <= start) return;
    const int cnt = end - start;
    int   sE = 0; float eE = 0.f;
    if (lane < cnt) {
        sE = cs[start + lane];
        eE = expf(lrelu_c(sl[sE] + srd));
    }
    float local = eE;
    for (int k = start + 64 + lane; k < end; k += 64)
        local += expf(lrelu_c(sl[cs[k]] + srd));
    #pragma unroll
    for (int o = 32; o > 0; o >>= 1) local += __shfl_xor(local, o, 64);
    const float inv = 1.f / local;
    const int m = (cnt < 64) ? cnt : 64;
    int k = 0;
    for (; k + 8 <= m; k += 8) {
        int   s[8]; float lw[8]; float2 f[8];
        #pragma unroll
        for (int u = 0; u < 8; ++u) {
            s[u]  = __shfl(sE, k + u, 64);
            lw[u] = __shfl(eE, k + u, 64) * inv;
        }
        #pragma unroll
        for (int u = 0; u < 8; ++u) f[u] = __half22float2(z[(size_t)s[u] * 64 + lane]);
        #pragma unroll
        for (int u = 0; u < 8; ++u) { a0 += lw[u] * f[u].x; a1 += lw[u] * f[u].y; }
    }
    for (; k + 4 <= m; k += 4) {
        int s0 = __shfl(sE, k, 64),     s1 = __shfl(sE, k + 1, 64);
        int s2 = __shfl(sE, k + 2, 64), s3 = __shfl(sE, k + 3, 64);
        float l0 = __shfl(eE, k, 64) * inv,     l1 = __shfl(eE, k + 1, 64) * inv;
        float l2 = __shfl(eE, k + 2, 64) * inv, l3 = __shfl(eE, k + 3, 64) * inv;
        float2 f0 = __half22float2(z[(size_t)s0 * 64 + lane]);
        float2 f1 = __half22float2(z[(size_t)s1 * 64 + lane]);
        float2 f2 = __half22float2(z[(size_t)s2 * 64 + lane]);
        float2 f3 = __half22float2(z[(size_t)s3 * 64 + lane]);
        a0 += l0 * f0.x + l1 * f1.x + l2 * f2.x + l3 * f3.x;
        a1 += l0 * f0.y + l1 * f1.y + l2 * f2.y + l3 * f3.y;
    }
    for (; k < m; ++k) {
        int s = __shfl(sE, k, 64);
        float al = __shfl(eE, k, 64) * inv;
        float2 f = __half22float2(z[(size_t)s * 64 + lane]);
        a0 += al * f.x;
        a1 += al * f.y;
    }
    for (int kk = start + 64; kk < end; ++kk) {   // rare: degree > 64
        int s = cs[kk];
        float al = expf(lrelu_c(sl[s] + srd)) * inv;
        float2 f = __half22float2(z[(size_t)s * 64 + lane]);
        a0 += al * f.x;
        a1 += al * f.y;
    }
}

// acc = 2*h0 + gb[b0] + gb[b1] + sum_A(alpha*zA[src]) + sum_B(alpha*zB[src])
__global__ __launch_bounds__(256) void t_gat_fused(
    const int* __restrict__ rpA, const int* __restrict__ csA,
    const float* __restrict__ slA, const float* __restrict__ srA, const __half2* __restrict__ zA_,
    const int* __restrict__ rpB, const int* __restrict__ csB,
    const float* __restrict__ slB, const float* __restrict__ war, const __half2* __restrict__ zB_,
    const float* __restrict__ h0, const void* __restrict__ gb, int b0off, int b1off,
    const int* __restrict__ fl, float* __restrict__ acc, int ndst)
{
    int w = blockIdx.x * 4 + (threadIdx.x >> 6);
    int lane = threadIdx.x & 63;
    if (w >= ndst) return;
    const int det = *fl;
    const int d0 = 2 * lane, d1 = 2 * lane + 1;
    float2 h0v = *(const float2*)(h0 + (size_t)w * 128 + d0);
    float2 wv  = *(const float2*)(war + d0);
    float srB = h0v.x * wv.x + h0v.y * wv.y;
    #pragma unroll
    for (int off = 32; off > 0; off >>= 1) srB += __shfl_xor(srB, off, 64);
    float a0 = 2.f * h0v.x + gldf(gb, b0off + d0, det) + gldf(gb, b1off + d0, det);
    float a1 = 2.f * h0v.y + gldf(gb, b0off + d1, det) + gldf(gb, b1off + d1, det);
    gat_gather(rpA, csA, slA, srA[w], zA_, w, lane, a0, a1);
    gat_gather(rpB, csB, slB, srB,    zB_, w, lane, a0, a1);
    *(float2*)(acc + (size_t)w * 128 + d0) = make_float2(a0, a1);
}

// attention-phase weight pack (w_1 + glu1_w), re-done each iter (wt2 overlays HiA)
__global__ __launch_bounds__(256) void k_prepw3(
    const void* __restrict__ w1, const void* __restrict__ g1w,
    const int* __restrict__ fl, u16* __restrict__ whi, u16* __restrict__ wlo)
{
    int s = blockIdx.x * 256 + threadIdx.x;
    if (s >= 6144) return;
    const int det = *fl;
    const void* src; int K, local;
    if (s < 4096) { src = w1;  K = 256; local = s; }
    else          { src = g1w; K = 128; local = s - 4096; }
    const int KK = K >> 5;
    int r = local & 15, g = (local >> 4) & 3, q2 = local >> 6;
    int kk = q2 % KK, ni = q2 / KK;
    bf16x8 hv, lv;
    #pragma unroll
    for (int j = 0; j < 8; ++j) {
        float x = gldf(src, (size_t)(kk * 32 + 8 * g + j) * 128 + ni * 16 + r, det);
        u16 hb = f2bf(x);
        hv[j] = (short)hb;
        lv[j] = (short)f2bf(x - bf2f(hb));
    }
    *(bf16x8*)(whi + (size_t)s * 8) = hv;
    *(bf16x8*)(wlo + (size_t)s * 8) = lv;
}

// hi0 = [item[iid] | cate[icate]] @ W_pos   (K=256)
__global__ __launch_bounds__(256, 2) void m_hi0(
    const void* __restrict__ item, const void* __restrict__ cate,
    const int* __restrict__ iid, const int* __restrict__ icate,
    const u16* __restrict__ whi, const u16* __restrict__ wlo,
    const int* __restrict__ fl, const int* __restrict__ mfok,
    float* __restrict__ out, int nrows)
{
    if (*mfok == 0) return;
    __shared__ __align__(16) short Ah[2048 * 8];   // 32 KB
    __shared__ __align__(16) short Alo[2048 * 8];  // 32 KB
    const int det = *fl;
    const int tid = threadIdx.x, l = tid & 63, w = tid >> 6;
    const int base = blockIdx.x * 64;
    {
        int row = tid >> 2, q = tid & 3;
        int n = base + row, mi = row >> 4, r = row & 15;
        const int it = (n < nrows) ? iid[n] : 0;
        const int ct = (n < nrows) ? icate[n] : 0;
        #pragma unroll
        for (int i = 0; i < 8; ++i) {
            int c = q + 4 * i, kk = c >> 2, g = c & 3;
            int slot = ((mi * 8 + kk) * 4 + g) * 16 + r;
            bf16x8 hv = {0,0,0,0,0,0,0,0}, lv = {0,0,0,0,0,0,0,0};
            if (n < nrows) {
                #pragma unroll
                for (int j = 0; j < 8; ++j) {
                    float x = (c < 16) ? gldf(item, (size_t)it * 128 + c * 8 + j, det)
                                       : gldf(cate, (size_t)ct * 128 + (c - 16) * 8 + j, det);
                    u16 hb2 = f2bf(x);
                    hv[j] = (short)hb2;
                    lv[j] = (short)f2bf(x - bf2f(hb2));
                }
            }
            *(bf16x8*)&Ah[slot * 8]  = hv;
            *(bf16x8*)&Alo[slot * 8] = lv;
        }
    }
    bf16x8 breg[2][8];
    #pragma unroll
    for (int t = 0; t < 2; ++t)
        #pragma unroll
        for (int kk = 0; kk < 8; ++kk)
            breg[t][kk] = *(const bf16x8*)(whi + ((size_t)((w * 2 + t) * 8 + kk) * 64 + l) * 8);
    __syncthreads();
    f32x4 acc[4][2];
    #pragma unroll
    for (int mi = 0; mi < 4; ++mi) { acc[mi][0] = (f32x4){0.f,0.f,0.f,0.f}; acc[mi][1] = (f32x4){0.f,0.f,0.f,0.f}; }
    auto pass = [&](const short* AS) {
        #pragma unroll
        for (int kk = 0; kk < 8; ++kk) {
            bf16x8 a[4];
            #pragma unroll
            for (int mi = 0; mi < 4; ++mi) a[mi] = *(const bf16x8*)&AS[((mi * 8 + kk) * 64 + l) * 8];
            #pragma unroll
            for (int mi = 0; mi < 4; ++mi) {
                acc[mi][0] = __builtin_amdgcn_mfma_f32_16x16x32_bf16(a[mi], breg[0][kk], acc[mi][0], 0, 0, 0);
                acc[mi][1] = __builtin_amdgcn_mfma_f32_16x16x32_bf16(a[mi], breg[1][kk], acc[mi][1], 0, 0, 0);
            }
        }
    };
    pass(Ah);
    pass(Alo);
    #pragma unroll
    for (int t = 0; t < 2; ++t)
        #pragma unroll
        for (int kk = 0; kk < 8; ++kk)
            breg[t][kk] = *(const bf16x8*)(wlo + ((size_t)((w * 2 + t) * 8 + kk) * 64 + l) * 8);
    pass(Ah);
    const int g = l >> 4, r = l & 15, wn0 = w * 32;
    #pragma unroll
    for (int mi = 0; mi < 4; ++mi)
        #pragma unroll
        for (int j = 0; j < 4; ++j) {
            int row = base + mi * 16 + 4 * g + j;
            if (row < nrows) {
                out[(size_t)row * 128 + wn0 + r]      = acc[mi][0][j];
                out[(size_t)row * 128 + wn0 + 16 + r] = acc[mi][1][j];
            }
        }
}

// z = h @ W (K=128, fp32 h) -> fp16 z + fused sl = z@al, sr = z@ar
__global__ __launch_bounds__(256, 2) void m_zgemm(
    const float* __restrict__ h, int nrows,
    const u16* __restrict__ whi, const u16* __restrict__ wlo,
    const void* __restrict__ al, int aloff, const void* __restrict__ ar, int aroff,
    const int* __restrict__ fl, const int* __restrict__ mfok,
    __half* __restrict__ z, float* __restrict__ sl, float* __restrict__ sr)
{
    if (*mfok == 0) return;
    __shared__ __align__(16) short Ah[1024 * 8];   // 16 KB
    __shared__ __align__(16) short Alo[1024 * 8];  // 16 KB
    __shared__ float part[2][4][64];               // 2 KB
    const int det = *fl;
    const int tid = threadIdx.x, l = tid & 63, w = tid >> 6;
    const int base = blockIdx.x * 64;
    {
        int row = tid >> 2, q = tid & 3;
        int n = base + row, mi = row >> 4, r = row & 15;
        #pragma unroll
        for (int i = 0; i < 4; ++i) {
            int c = q + 4 * i, kk = c >> 2, g = c & 3;
            int slot = ((mi * 4 + kk) * 4 + g) * 16 + r;
            bf16x8 hv = {0,0,0,0,0,0,0,0}, lv = {0,0,0,0,0,0,0,0};
            if (n < nrows) {
                const float* sp = h + (size_t)n * 128 + c * 8;
                #pragma unroll
                for (int j = 0; j < 8; ++j) {
                    float x = sp[j];
                    u16 hb = f2bf(x);
                    hv[j] = (short)hb;
                    lv[j] = (short)f2bf(x - bf2f(hb));
                }
            }
            *(bf16x8*)&Ah[slot * 8]  = hv;
            *(bf16x8*)&Alo[slot * 8] = lv;
        }
    }
    bf16x8 breg[2][4];
    #pragma unroll
    for (int t = 0; t < 2; ++t)
        #pragma unroll
        for (int kk = 0; kk < 4; ++kk)
            breg[t][kk] = *(const bf16x8*)(whi + ((size_t)((w * 2 + t) * 4 + kk) * 64 + l) * 8);
    __syncthreads();
    f32x4 acc[4][2];
    #pragma unroll
    for (int mi = 0; mi < 4; ++mi) { acc[mi][0] = (f32x4){0.f,0.f,0.f,0.f}; acc[mi][1] = (f32x4){0.f,0.f,0.f,0.f}; }
    auto pass = [&](const short* AS) {
        #pragma unroll
        for (int kk = 0; kk < 4; ++kk) {
            bf16x8 a[4];
            #pragma unroll
            for (int mi = 0; mi < 4; ++mi) a[mi] = *(const bf16x8*)&AS[((mi * 4 + kk) * 64 + l) * 8];
            #pragma unroll
            for (int mi = 0; mi < 4; ++mi) {
                acc[mi][0] = __builtin_amdgcn_mfma_f32_16x16x32_bf16(a[mi], breg[0][kk], acc[mi][0], 0, 0, 0);
                acc[mi][1] = __builtin_amdgcn_mfma_f32_16x16x32_bf16(a[mi], breg[1][kk], acc[mi][1], 0, 0, 0);
            }
        }
    };
    pass(Ah);
    pass(Alo);
    #pragma unroll
    for (int t = 0; t < 2; ++t)
        #pragma unroll
        for (int kk = 0; kk < 4; ++kk)
            breg[t][kk] = *(const bf16x8*)(wlo + ((size_t)((w * 2 + t) * 4 + kk) * 64 + l) * 8);
    pass(Ah);
    const int g = l >> 4, r = l & 15, wn0 = w * 32;
    const float alv0 = gldf(al, (size_t)aloff + wn0 + r, det);
    const float alv1 = gldf(al, (size_t)aloff + wn0 + 16 + r, det);
    const float arv0 = gldf(ar, (size_t)aroff + wn0 + r, det);
    const float arv1 = gldf(ar, (size_t)aroff + wn0 + 16 + r, det);
    #pragma unroll
    for (int mi = 0; mi < 4; ++mi)
        #pragma unroll
        for (int j = 0; j < 4; ++j) {
            int row = base + mi * 16 + 4 * g + j;
            float d0 = acc[mi][0][j], d1 = acc[mi][1][j];
            if (row < nrows) {
                z[(size_t)row * 128 + wn0 + r]      = __float2half_rn(d0);
                z[(size_t)row * 128 + wn0 + 16 + r] = __float2half_rn(d1);
            }
            float pl = d0 * alv0 + d1 * alv1;
            float pr = d0 * arv0 + d1 * arv1;
            #pragma unroll
            for (int m2 = 1; m2 < 16; m2 <<= 1) {
                pl += __shfl_xor(pl, m2, 64);
                pr += __shfl_xor(pr, m2, 64);
            }
            if (r == 0) {
                part[0][w][mi * 16 + 4 * g + j] = pl;
                part[1][w][mi * 16 + 4 * g + j] = pr;
            }
        }
    __syncthreads();
    if (tid < 128) {
        int which = tid >> 6, t = tid & 63;
        int n2 = base + t;
        if (n2 < nrows) {
            float s = part[which][0][t] + part[which][1][t] + part[which][2][t] + part[which][3][t];
            (which ? sr : sl)[n2] = s;
        }
    }
}

// dual-weight z-gemm
__global__ __launch_bounds__(256, 2) void m_zgemm2(
    const float* __restrict__ h, int nrows,
    const u16* __restrict__ whi1, const u16* __restrict__ wlo1,
    int alo1, int aro1, __half* __restrict__ z1,
    float* __restrict__ sl1, float* __restrict__ sr1,
    const u16* __restrict__ whi2, const u16* __restrict__ wlo2,
    int alo2, int aro2, __half* __restrict__ z2,
    float* __restrict__ sl2, float* __restrict__ sr2,
    const void* __restrict__ al, const void* __restrict__ ar,
    const int* __restrict__ fl, const int* __restrict__ mfok)
{
    if (*mfok == 0) return;
    __shared__ __align__(16) short Ah[1024 * 8];   // 16 KB
    __shared__ __align__(16) short Alo[1024 * 8];  // 16 KB
    __shared__ float part[2][4][64];               // 2 KB
    const int det = *fl;
    const int tid = threadIdx.x, l = tid & 63, w = tid >> 6;
    const int base = blockIdx.x * 64;
    {
        int row = tid >> 2, q = tid & 3;
        int n = base + row, mi = row >> 4, r = row & 15;
        #pragma unroll
        for (int i = 0; i < 4; ++i) {
            int c = q + 4 * i, kk = c >> 2, g = c & 3;
            int slot = ((mi * 4 + kk) * 4 + g) * 16 + r;
            bf16x8 hv = {0,0,0,0,0,0,0,0}, lv = {0,0,0,0,0,0,0,0};
            if (n < nrows) {
                const float* sp = h + (size_t)n * 128 + c * 8;
                #pragma unroll
                for (int j = 0; j < 8; ++j) {
                    float x = sp[j];
                    u16 hb = f2bf(x);
                    hv[j] = (short)hb;
                    lv[j] = (short)f2bf(x - bf2f(hb));
                }
            }
            *(bf16x8*)&Ah[slot * 8]  = hv;
            *(bf16x8*)&Alo[slot * 8] = lv;
        }
    }
    __syncthreads();
    const int g = l >> 4, r = l & 15, wn0 = w * 32;
    auto doSet = [&](const u16* whi, const u16* wlo, int aloff, int aroff,
                     __half* z, float* sl, float* sr) {
        bf16x8 breg[2][4];
        #pragma unroll
        for (int t = 0; t < 2; ++t)
            #pragma unroll
            for (int kk = 0; kk < 4; ++kk)
                breg[t][kk] = *(const bf16x8*)(whi + ((size_t)((w * 2 + t) * 4 + kk) * 64 + l) * 8);
        f32x4 acc[4][2];
        #pragma unroll
        for (int mi = 0; mi < 4; ++mi) { acc[mi][0] = (f32x4){0.f,0.f,0.f,0.f}; acc[mi][1] = (f32x4){0.f,0.f,0.f,0.f}; }
        auto pass = [&](const short* AS) {
            #pragma unroll
            for (int kk = 0; kk < 4; ++kk) {
                bf16x8 a[4];
                #pragma unroll
                for (int mi = 0; mi < 4; ++mi) a[mi] = *(const bf16x8*)&AS[((mi * 4 + kk) * 64 + l) * 8];
                #pragma unroll
                for (int mi = 0; mi < 4; ++mi) {
                    acc[mi][0] = __builtin_amdgcn_mfma_f32_16x16x32_bf16(a[mi], breg[0][kk], acc[mi][0], 0, 0, 0);
                    acc[mi][1] = __builtin_amdgcn_mfma_f32_16x16x32_bf16(a[mi], breg[1][kk], acc[mi][1], 0, 0, 0);
                }
            }
        };
        pass(Ah);
        pass(Alo);
        #pragma unroll
        for (int t = 0; t < 2; ++t)
            #pragma unroll
            for (int kk = 0; kk < 4; ++kk)
                breg[t][kk] = *(const bf16x8*)(wlo + ((size_t)((w * 2 + t) * 4 + kk) * 64 + l) * 8);
        pass(Ah);
        const float alv0 = gldf(al, (size_t)aloff + wn0 + r, det);
        const float alv1 = gldf(al, (size_t)aloff + wn0 + 16 + r, det);
        const float arv0 = gldf(ar, (size_t)aroff + wn0 + r, det);
        const float arv1 = gldf(ar, (size_t)aroff + wn0 + 16 + r, det);
        #pragma unroll
        for (int mi = 0; mi < 4; ++mi)
            #pragma unroll
            for (int j = 0; j < 4; ++j) {
                int row = base + mi * 16 + 4 * g + j;
                float d0 = acc[mi][0][j], d1 = acc[mi][1][j];
                if (row < nrows) {
                    z[(size_t)row * 128 + wn0 + r]      = __float2half_rn(d0);
                    z[(size_t)row * 128 + wn0 + 16 + r] = __float2half_rn(d1);
                }
                float pl = d0 * alv0 + d1 * alv1;
                float pr = d0 * arv0 + d1 * arv1;
                #pragma unroll
                for (int m2 = 1; m2 < 16; m2 <<= 1) {
                    pl += __shfl_xor(pl, m2, 64);
                    pr += __shfl_xor(pr, m2, 64);
                }
                if (r == 0) {
                    part[0][w][mi * 16 + 4 * g + j] = pl;
                    part[1][w][mi * 16 + 4 * g + j] = pr;
                }
            }
        __syncthreads();
        if (tid < 128) {
            int which = tid >> 6, t = tid & 63;
            int n2 = base + t;
            if (n2 < nrows) {
                float s = part[which][0][t] + part[which][1][t] + part[which][2][t] + part[which][3][t];
                (which ? sr : sl)[n2] = s;
            }
        }
        __syncthreads();
    };
    doSet(whi1, wlo1, alo1, aro1, z1, sl1, sr1);
    doSet(whi2, wlo2, alo2, aro2, z2, sl2, sr2);
}

// feat = g*h0 + (1-g)*h1, g = sigm([h0|h1] @ W + b)   (K=256)
__global__ __launch_bounds__(256, 2) void m_gatefeat(
    const float* __restrict__ h0, const float* __restrict__ h1,
    const u16* __restrict__ whi, const u16* __restrict__ wlo,
    const void* __restrict__ bias,
    const int* __restrict__ fl, const int* __restrict__ mfok,
    float* __restrict__ feat, int nrows)
{
    if (*mfok == 0) return;
    __shared__ __align__(16) short Ah[2048 * 8];   // 32 KB
    __shared__ __align__(16) short Alo[2048 * 8];  // 32 KB
    const int det = *fl;
    const int tid = threadIdx.x, l = tid & 63, w = tid >> 6;
    const int base = blockIdx.x * 64;
    {
        int row = tid >> 2, q = tid & 3;
        int n = base + row, mi = row >> 4, r = row & 15;
        #pragma unroll
        for (int i = 0; i < 8; ++i) {
            int c = q + 4 * i, kk = c >> 2, g = c & 3;
            int slot = ((mi * 8 + kk) * 4 + g) * 16 + r;
            bf16x8 hv = {0,0,0,0,0,0,0,0}, lv = {0,0,0,0,0,0,0,0};
            if (n < nrows) {
                const float* sp = ((c < 16) ? h0 : h1) + (size_t)n * 128 + (c & 15) * 8;
                #pragma unroll
                for (int j = 0; j < 8; ++j) {
                    float x = sp[j];
                    u16 hb = f2bf(x);
                    hv[j] = (short)hb;
                    lv[j] = (short)f2bf(x - bf2f(hb));
                }
            }
            *(bf16x8*)&Ah[slot * 8]  = hv;
            *(bf16x8*)&Alo[slot * 8] = lv;
        }
    }
    bf16x8 breg[2][8];
    #pragma unroll
    for (int t = 0; t < 2; ++t)
        #pragma unroll
        for (int kk = 0; kk < 8; ++kk)
            breg[t][kk] = *(const bf16x8*)(whi + ((size_t)((w * 2 + t) * 8 + kk) * 64 + l) * 8);
    __syncthreads();
    f32x4 acc[4][2];
    #pragma unroll
    for (int mi = 0; mi < 4; ++mi) { acc[mi][0] = (f32x4){0.f,0.f,0.f,0.f}; acc[mi][1] = (f32x4){0.f,0.f,0.f,0.f}; }
    auto pass = [&](const short* AS) {
        #pragma unroll
        for (int kk = 0; kk < 8; ++kk) {
            bf16x8 a[4];
            #pragma unroll
            for (int mi = 0; mi < 4; ++mi) a[mi] = *(const bf16x8*)&AS[((mi * 8 + kk) * 64 + l) * 8];
            #pragma unroll
            for (int mi = 0; mi < 4; ++mi) {
                acc[mi][0] = __builtin_amdgcn_mfma_f32_16x16x32_bf16(a[mi], breg[0][kk], acc[mi][0], 0, 0, 0);
                acc[mi][1] = __builtin_amdgcn_mfma_f32_16x16x32_bf16(a[mi], breg[1][kk], acc[mi][1], 0, 0, 0);
            }
        }
    };
    pass(Ah);
    pass(Alo);
    #pragma unroll
    for (int t = 0; t < 2; ++t)
        #pragma unroll
        for (int kk = 0; kk < 8; ++kk)
            breg[t][kk] = *(const bf16x8*)(wlo + ((size_t)((w * 2 + t) * 8 + kk) * 64 + l) * 8);
    pass(Ah);
    const int g = l >> 4, r = l & 15, wn0 = w * 32;
    const float bv0 = gldf(bias, wn0 + r, det);
    const float bv1 = gldf(bias, wn0 + 16 + r, det);
    #pragma unroll
    for (int mi = 0; mi < 4; ++mi)
        #pragma unroll
        for (int j = 0; j < 4; ++j) {
            int row = base + mi * 16 + 4 * g + j;
            if (row < nrows) {
                size_t o0 = (size_t)row * 128 + wn0 + r;
                size_t o1 = o0 + 16;
                float ga  = sigm(acc[mi][0][j] + bv0);
                float gb2 = sigm(acc[mi][1][j] + bv1);
                feat[o0] = ga  * h0[o0] + (1.f - ga)  * h1[o0];
                feat[o1] = gb2 * h0[o1] + (1.f - gb2) * h1[o1];
            }
        }
}

// nh = tanh([pos(t) | hall0] @ w_1)   (K=256)
__global__ __launch_bounds__(256, 2) void m_nh(
    const void* __restrict__ pos, const float* __restrict__ hall0,
    const u16* __restrict__ whi, const u16* __restrict__ wlo,
    const int* __restrict__ fl, const int* __restrict__ mfok,
    float* __restrict__ nh, int nrows)
{
    if (*mfok == 0) return;
    __shared__ __align__(16) short Ah[2048 * 8];
    __shared__ __align__(16) short Alo[2048 * 8];
    const int det = *fl;
    const int tid = threadIdx.x, l = tid & 63, w = tid >> 6;
    const int base = blockIdx.x * 64;
    {
        int row = tid >> 2, q = tid & 3;
        int n = base + row, mi = row >> 4, r = row & 15;
        const int t = (n < nrows) ? (n - (n / T_) * T_) : 0;
        #pragma unroll
        for (int i = 0; i < 8; ++i) {
            int c = q + 4 * i, kk = c >> 2, g = c & 3;
            int slot = ((mi * 8 + kk) * 4 + g) * 16 + r;
            bf16x8 hv = {0,0,0,0,0,0,0,0}, lv = {0,0,0,0,0,0,0,0};
            if (n < nrows) {
                #pragma unroll
                for (int j = 0; j < 8; ++j) {
                    float x = (c < 16) ? gldf(pos, (size_t)t * 128 + c * 8 + j, det)
                                       : hall0[(size_t)n * 128 + (c - 16) * 8 + j];
                    u16 hb = f2bf(x);
                    hv[j] = (short)hb;
                    lv[j] = (short)f2bf(x - bf2f(hb));
                }
            }
            *(bf16x8*)&Ah[slot * 8]  = hv;
            *(bf16x8*)&Alo[slot * 8] = lv;
        }
    }
    bf16x8 breg[2][8];
    #pragma unroll
    for (int t = 0; t < 2; ++t)
        #pragma unroll
        for (int kk = 0; kk < 8; ++kk)
            breg[t][kk] = *(const bf16x8*)(whi + ((size_t)((w * 2 + t) * 8 + kk) * 64 + l) * 8);
    __syncthreads();
    f32x4 acc[4][2];
    #pragma unroll
    for (int mi = 0; mi < 4; ++mi) { acc[mi][0] = (f32x4){0.f,0.f,0.f,0.f}; acc[mi][1] = (f32x4){0.f,0.f,0.f,0.f}; }
    auto pass = [&](const short* AS) {
        #pragma unroll
        for (int kk = 0; kk < 8; ++kk) {
            bf16x8 a[4];
            #pragma unroll
            for (int mi = 0; mi < 4; ++mi) a[mi] = *(const bf16x8*)&AS[((mi * 8 + kk) * 64 + l) * 8];
            #pragma unroll
            for (int mi = 0; mi < 4; ++mi) {
                acc[mi][0] = __builtin_amdgcn_mfma_f32_16x16x32_bf16(a[mi], breg[0][kk], acc[mi][0], 0, 0, 0);
                acc[mi][1] = __builtin_amdgcn_mfma_f32_16x16x32_bf16(a[mi], breg[1][kk], acc[mi][1], 0, 0, 0);
            }
        }
    };
    pass(Ah);
    pass(Alo);
    #pragma unroll
    for (int t = 0; t < 2; ++t)
        #pragma unroll
        for (int kk = 0; kk < 8; ++kk)
            breg[t][kk] = *(const bf16x8*)(wlo + ((size_t)((w * 2 + t) * 8 + kk) * 64 + l) * 8);
    pass(Ah);
    const int g = l >> 4, r = l & 15, wn0 = w * 32;
    #pragma unroll
    for (int mi = 0; mi < 4; ++mi)
        #pragma unroll
        for (int j = 0; j < 4; ++j) {
            int row = base + mi * 16 + 4 * g + j;
            if (row < nrows) {
                nh[(size_t)row * 128 + wn0 + r]      = tanhf(acc[mi][0][j]);
                nh[(size_t)row * 128 + wn0 + 16 + r] = tanhf(acc[mi][1][j]);
            }
        }
}

// beta = (sigm(nh @ glu1_w + glu1_b + g2[b]) . w2) * mask   (K=128)
__global__ __launch_bounds__(256, 2) void m_glub(
    const float* __restrict__ nh,
    const u16* __restrict__ whi, const u16* __restrict__ wlo,
    const void* __restrict__ gb, const float* __restrict__ g2,
    const void* __restrict__ w2, const int* __restrict__ mask,
    const int* __restrict__ fl, const int* __restrict__ mfok,
    float* __restrict__ beta, int nrows)
{
    if (*mfok == 0) return;
    __shared__ __align__(16) short Ah[1024 * 8];
    __shared__ __align__(16) short Alo[1024 * 8];
    __shared__ float part[4][64];
    const int det = *fl;
    const int tid = threadIdx.x, l = tid & 63, w = tid >> 6;
    const int base = blockIdx.x * 64;
    {
        int row = tid >> 2, q = tid & 3;
        int n = base + row, mi = row >> 4, r = row & 15;
        #pragma unroll
        for (int i = 0; i < 4; ++i) {
            int c = q + 4 * i, kk = c >> 2, g = c & 3;
            int slot = ((mi * 4 + kk) * 4 + g) * 16 + r;
            bf16x8 hv = {0,0,0,0,0,0,0,0}, lv = {0,0,0,0,0,0,0,0};
            if (n < nrows) {
                const float* sp = nh + (size_t)n * 128 + c * 8;
                #pragma unroll
                for (int j = 0; j < 8; ++j) {
                    float x = sp[j];
                    u16 hb = f2bf(x);
                    hv[j] = (short)hb;
                    lv[j] = (short)f2bf(x - bf2f(hb));
                }
            }
            *(bf16x8*)&Ah[slot * 8]  = hv;
            *(bf16x8*)&Alo[slot * 8] = lv;
        }
    }
    bf16x8 breg[2][4];
    #pragma unroll
    for (int t = 0; t < 2; ++t)
        #pragma unroll
        for (int kk = 0; kk < 4; ++kk)
            breg[t][kk] = *(const bf16x8*)(whi + ((size_t)((w * 2 + t) * 4 + kk) * 64 + l) * 8);
    __syncthreads();
    f32x4 acc[4][2];
    #pragma unroll
    for (int mi = 0; mi < 4; ++mi) { acc[mi][0] = (f32x4){0.f,0.f,0.f,0.f}; acc[mi][1] = (f32x4){0.f,0.f,0.f,0.f}; }
    auto pass = [&](const short* AS) {
        #pragma unroll
        for (int kk = 0; kk < 4; ++kk) {
            bf16x8 a[4];
            #pragma unroll
            for (int mi = 0; mi < 4; ++mi) a[mi] = *(const bf16x8*)&AS[((mi * 4 + kk) * 64 + l) * 8];
            #pragma unroll
            for (int mi = 0; mi < 4; ++mi) {
                acc[mi][0] = __builtin_amdgcn_mfma_f32_16x16x32_bf16(a[mi], breg[0][kk], acc[mi][0], 0, 0, 0);
                acc[mi][1] = __builtin_amdgcn_mfma_f32_16x16x32_bf16(a[mi], breg[1][kk], acc[mi][1], 0, 0, 0);
            }
        }
    };
    pass(Ah);
    pass(Alo);
    #pragma unroll
    for (int t = 0; t < 2; ++t)
        #pragma unroll
        for (int kk = 0; kk < 4; ++kk)
            breg[t][kk] = *(const bf16x8*)(wlo + ((size_t)((w * 2 + t) * 4 + kk) * 64 + l) * 8);
    pass(Ah);
    const int g = l >> 4, r = l & 15, wn0 = w * 32;
    const float gbv0 = gldf(gb, wn0 + r, det);
    const float gbv1 = gldf(gb, wn0 + 16 + r, det);
    const float w2v0 = gldf(w2, wn0 + r, det);
    const float w2v1 = gldf(w2, wn0 + 16 + r, det);
    #pragma unroll
    for (int mi = 0; mi < 4; ++mi)
        #pragma unroll
        for (int j = 0; j < 4; ++j) {
            int row = base + mi * 16 + 4 * g + j;
            int b = row / T_;
            float gv0 = (row < nrows) ? g2[(size_t)b * 128 + wn0 + r]      : 0.f;
            float gv1 = (row < nrows) ? g2[(size_t)b * 128 + wn0 + 16 + r] : 0.f;
            float v0 = sigm(acc[mi][0][j] + gbv0 + gv0);
            float v1 = sigm(acc[mi][1][j] + gbv1 + gv1);
            float pl = v0 * w2v0 + v1 * w2v1;
            #pragma unroll
            for (int m2 = 1; m2 < 16; m2 <<= 1) pl += __shfl_xor(pl, m2, 64);
            if (r == 0) part[w][mi * 16 + 4 * g + j] = pl;
        }
    __syncthreads();
    if (tid < 64) {
        int n2 = base + tid;
        if (n2 < nrows) {
            float s = part[0][tid] + part[1][tid] + part[2][tid] + part[3][tid];
            beta[n2] = s * (float)mask[n2];
        }
    }
}

// ================= tiled GEMM kernels (VALU fallback, only launched when !mf) =================
__global__ __launch_bounds__(512) void t_hi0(
    const void* __restrict__ item, const void* __restrict__ cate,
    const int* __restrict__ iid, const int* __restrict__ icate,
    const void* __restrict__ Wp, const int* __restrict__ fl,
    float* __restrict__ out, int nrows)
{
    __shared__ float Ws[8192];
    __shared__ float hrow[16][256];
    const int det = *fl;
    const int tid = threadIdx.x, c = tid & 31, slot = tid >> 5;
    for (int base = blockIdx.x * 16; base < nrows; base += gridDim.x * 16) {
        const int n = base + slot;
        if (n < nrows) {
            const int it = iid[n], ct = icate[n];
            for (int j = c; j < 128; j += 32) {
                hrow[slot][j]       = gldf(item, (size_t)it * 128 + j, det);
                hrow[slot][128 + j] = gldf(cate, (size_t)ct * 128 + j, det);
            }
        }
        float4 acc = make_float4(0.f, 0.f, 0.f, 0.f);
        for (int kb = 0; kb < 256; kb += 64) {
            __syncthreads();
            for (int i = tid; i < 8192; i += 512) Ws[i] = gldf(Wp, (size_t)kb * 128 + i, det);
            __syncthreads();
            if (n < nrows) {
                #pragma unroll 8
                for (int k = 0; k < 64; ++k) {
                    float hv = hrow[slot][kb + k];
                    float4 w = *(const float4*)&Ws[k * 128 + c * 4];
                    acc.x += hv * w.x; acc.y += hv * w.y; acc.z += hv * w.z; acc.w += hv * w.w;
                }
            }
        }
        if (n < nrows) *(float4*)&out[(size_t)n * 128 + c * 4] = acc;
        __syncthreads();
    }
}

__global__ __launch_bounds__(256) void s_hc0(
    const void* __restrict__ cate, const int* __restrict__ cid,
    const int* __restrict__ fl, float* __restrict__ out)
{
    long i = (long)blockIdx.x * 256 + threadIdx.x;
    if (i >= (long)NC_ * 128) return;
    out[i] = gldf(cate, (size_t)cid[i >> 7] * 128 + (i & 127), *fl);
}

__global__ __launch_bounds__(256) void s_initacc(
    const float* __restrict__ h, const void* __restrict__ gb, int b0off, int b1off,
    const int* __restrict__ fl, float* __restrict__ acc, long total)
{
    long i = (long)blockIdx.x * 256 + threadIdx.x;
    if (i >= total) return;
    const int det = *fl, d = (int)(i & 127);
    acc[i] = 2.f * h[i] + gldf(gb, b0off + d, det) + gldf(gb, b1off + d, det);
}

__global__ __launch_bounds__(512) void t_zgemm(
    const float* __restrict__ h, int nrows,
    const void* __restrict__ W, int woff,
    const void* __restrict__ al, int aloff,
    const void* __restrict__ ar, int aroff,
    const int* __restrict__ fl,
    __half* __restrict__ z, float* __restrict__ sl, float* __restrict__ sr)
{
    __shared__ float Ws[8192];
    __shared__ float hrow[16][128];
    const int det = *fl;
    const int tid = threadIdx.x, c = tid & 31, slot = tid >> 5;
    float4 alv, arv;
    alv.x = gldf(al, (size_t)aloff + c * 4 + 0, det); alv.y = gldf(al, (size_t)aloff + c * 4 + 1, det);
    alv.z = gldf(al, (size_t)aloff + c * 4 + 2, det); alv.w = gldf(al, (size_t)aloff + c * 4 + 3, det);
    arv.x = gldf(ar, (size_t)aroff + c * 4 + 0, det); arv.y = gldf(ar, (size_t)aroff + c * 4 + 1, det);
    arv.z = gldf(ar, (size_t)aroff + c * 4 + 2, det); arv.w = gldf(ar, (size_t)aroff + c * 4 + 3, det);
    for (int base = blockIdx.x * 16; base < nrows; base += gridDim.x * 16) {
        const int n = base + slot;
        if (n < nrows) for (int j = c; j < 128; j += 32) hrow[slot][j] = h[(size_t)n * 128 + j];
        float4 acc = make_float4(0.f, 0.f, 0.f, 0.f);
        for (int kb = 0; kb < 128; kb += 64) {
            __syncthreads();
            for (int i = tid; i < 8192; i += 512) Ws[i] = gldf(W, (size_t)woff + (size_t)kb * 128 + i, det);
            __syncthreads();
            if (n < nrows) {
                #pragma unroll 8
                for (int k = 0; k < 64; ++k) {
                    float hv = hrow[slot][kb + k];
                    float4 w = *(const float4*)&Ws[k * 128 + c * 4];
                    acc.x += hv * w.x; acc.y += hv * w.y; acc.z += hv * w.z; acc.w += hv * w.w;
                }
            }
        }
        if (n < nrows) {
            z[(size_t)n * 128 + c * 4 + 0] = __float2half_rn(acc.x);
            z[(size_t)n * 128 + c * 4 + 1] = __float2half_rn(acc.y);
            z[(size_t)n * 128 + c * 4 + 2] = __float2half_rn(acc.z);
            z[(size_t)n * 128 + c * 4 + 3] = __float2half_rn(acc.w);
            float pl = acc.x * alv.x + acc.y * alv.y + acc.z * alv.z + acc.w * alv.w;
            float pr = acc.x * arv.x + acc.y * arv.y + acc.z * arv.z + acc.w * arv.w;
            #pragma unroll
            for (int off = 16; off > 0; off >>= 1) {
                pl += __shfl_down(pl, off, 32);
                pr += __shfl_down(pr, off, 32);
            }
            if (c == 0) { sl[n] = pl; sr[n] = pr; }
        }
        __syncthreads();
    }
}

// -------- fallback atomic path --------
__global__ __launch_bounds__(256) void s_dinit(float* __restrict__ den, int n)
{
    int i = blockIdx.x * 256 + threadIdx.x;
    if (i < n) den[i] = 0.f;
}
__global__ __launch_bounds__(256) void s_edge(
    const float* __restrict__ sl, const float* __restrict__ sr,
    const int* __restrict__ src, const int* __restrict__ dst,
    float* __restrict__ e, float* __restrict__ den, int E)
{
    int j = blockIdx.x * 256 + threadIdx.x;
    if (j >= E) return;
    float ee = expf(lrelu_c(sl[src[j]] + sr[dst[j]]));
    e[j] = ee;
    atomicAdd(&den[dst[j]], ee);
}
__global__ __launch_bounds__(256) void s_scatter(
    const float* __restrict__ e, const float* __restrict__ den,
    const int* __restrict__ src, const int* __restrict__ dst,
    const __half* __restrict__ z, float* __restrict__ acc, int E)
{
    long i = (long)blockIdx.x * 256 + threadIdx.x;
    if (i >= (long)E * 128) return;
    int j = (int)(i >> 7), d = (int)(i & 127);
    int dj = dst[j];
    atomicAdd(&acc[(size_t)dj * 128 + d], (e[j] / den[dj]) * __half2float(z[(size_t)src[j] * 128 + d]));
}

__global__ __launch_bounds__(512) void t_gatefeat(
    const float* __restrict__ h0, const float* __restrict__ h1,
    const void* __restrict__ W, const void* __restrict__ bias,
    const int* __restrict__ fl,
    float* __restrict__ feat, int nrows)
{
    __shared__ float Ws[8192];
    __shared__ float hrow[16][256];
    const int det = *fl;
    const int tid = threadIdx.x, c = tid & 31, slot = tid >> 5;
    float4 bv;
    bv.x = gldf(bias, c * 4 + 0, det); bv.y = gldf(bias, c * 4 + 1, det);
    bv.z = gldf(bias, c * 4 + 2, det); bv.w = gldf(bias, c * 4 + 3, det);
    for (int base = blockIdx.x * 16; base < nrows; base += gridDim.x * 16) {
        const int n = base + slot;
        if (n < nrows) {
            for (int j = c; j < 128; j += 32) {
                hrow[slot][j]       = h0[(size_t)n * 128 + j];
                hrow[slot][128 + j] = h1[(size_t)n * 128 + j];
            }
        }
        float4 acc = make_float4(0.f, 0.f, 0.f, 0.f);
        for (int kb = 0; kb < 256; kb += 64) {
            __syncthreads();
            for (int i = tid; i < 8192; i += 512) Ws[i] = gldf(W, (size_t)kb * 128 + i, det);
            __syncthreads();
            if (n < nrows) {
                #pragma unroll 8
                for (int k = 0; k < 64; ++k) {
                    float hv = hrow[slot][kb + k];
                    float4 w = *(const float4*)&Ws[k * 128 + c * 4];
                    acc.x += hv * w.x; acc.y += hv * w.y; acc.z += hv * w.z; acc.w += hv * w.w;
                }
            }
        }
        if (n < nrows) {
            float4 a = *(const float4*)&hrow[slot][c * 4];
            float4 b = *(const float4*)&hrow[slot][128 + c * 4];
            float gx = sigm(acc.x + bv.x), gy = sigm(acc.y + bv.y);
            float gz = sigm(acc.z + bv.z), gw = sigm(acc.w + bv.w);
            float4 o;
            o.x = gx * a.x + (1.f - gx) * b.x;
            o.y = gy * a.y + (1.f - gy) * b.y;
            o.z = gz * a.z + (1.f - gz) * b.z;
            o.w = gw * a.w + (1.f - gw) * b.w;
            *(float4*)&feat[(size_t)n * 128 + c * 4] = o;
        }
        __syncthreads();
    }
}

__global__ __launch_bounds__(256) void s_hall0(
    const void* __restrict__ item, const int* __restrict__ seq,
    const int* __restrict__ alias, const int* __restrict__ mask,
    const float* __restrict__ feat, const void* __restrict__ xs,
    const int* __restrict__ fl, float* __restrict__ out)
{
    long i = (long)blockIdx.x * 256 + threadIdx.x;
    if (i >= (long)B_ * T_ * 128) return;
    const int det = *fl;
    int bt = (int)(i >> 7), d = (int)(i & 127);
    float x = gldf(xs, 0, det);
    out[i] = gldf(item, (size_t)seq[bt] * 128 + d, det) * x
           + feat[(size_t)alias[bt] * 128 + d] * (float)mask[bt];
}

// fused attn: hs->softmax->hsv->LN1 then linout+glu2 (per batch row)
__global__ __launch_bounds__(128) void t_attn12(
    const float* __restrict__ hall0, const void* __restrict__ q,
    const int* __restrict__ mask,
    const void* __restrict__ g, const void* __restrict__ bb,
    const void* __restrict__ lw, const void* __restrict__ lb,
    const void* __restrict__ gw, const int* __restrict__ fl,
    float* __restrict__ g2)
{
    __shared__ float qs[128];
    __shared__ float hs_s[T_];
    __shared__ float red[128];
    __shared__ float h1s[128];
    __shared__ float h2[128];
    const int b = blockIdx.x, tid = threadIdx.x;
    const int det = *fl;
    qs[tid] = gldf(q, tid, det);
    __syncthreads();
    if (tid < T_) {
        const float* hp = hall0 + ((size_t)b * T_ + tid) * 128;
        float a = 0.f;
        for (int d = 0; d < 128; ++d) a += hp[d] * qs[d];
        hs_s[tid] = a;
    }
    __syncthreads();
    float mx = -1e30f;
    for (int t = 0; t < T_; ++t) mx = fmaxf(mx, hs_s[t]);
    float ssum = 0.f;
    for (int t = 0; t < T_; ++t) ssum += expf(hs_s[t] - mx);
    float inv = 1.f / ssum;
    __syncthreads();
    if (tid < T_)
        hs_s[tid] = expf(hs_s[tid] - mx) * inv * (float)mask[b * T_ + tid];
    __syncthreads();
    float a = 0.f;
    for (int t = 0; t < T_; ++t) a += hs_s[t] * hall0[((size_t)b * T_ + t) * 128 + tid];
    red[tid] = a; __syncthreads();
    for (int o = 64; o > 0; o >>= 1) { if (tid < o) red[tid] += red[tid + o]; __syncthreads(); }
    float mu = red[0] * (1.f / 128.f);
    __syncthreads();
    float dv = a - mu;
    red[tid] = dv * dv; __syncthreads();
    for (int o = 64; o > 0; o >>= 1) { if (tid < o) red[tid] += red[tid + o]; __syncthreads(); }
    float rs = 1.f / sqrtf(red[0] * (1.f / 128.f) + 1e-8f);
    h1s[tid] = dv * rs * gldf(g, tid, det) + gldf(bb, tid, det);
    __syncthreads();
    // linout
    float a2 = gldf(lb, tid, det);
    for (int k = 0; k < 128; ++k)
        a2 += h1s[k] * gldf(lw, (size_t)k * 128 + tid, det);
    for (int k = 0; k < 128; ++k)
        a2 += hall0[(size_t)b * T_ * 128 + k] * gldf(lw, (size_t)(128 + k) * 128 + tid, det);
    h2[tid] = a2;
    __syncthreads();
    float g2v = 0.f;
    for (int k = 0; k < 128; ++k)
        g2v += h2[k] * gldf(gw, (size_t)k * 128 + tid, det);
    g2[(size_t)b * 128 + tid] = g2v;
}

__global__ __launch_bounds__(512) void t_nh(
    const void* __restrict__ pos, const float* __restrict__ hall0,
    const void* __restrict__ W, const int* __restrict__ fl,
    float* __restrict__ nh, int nrows)
{
    __shared__ float Ws[8192];
    __shared__ float hrow[16][256];
    const int det = *fl;
    const int tid = threadIdx.x, c = tid & 31, slot = tid >> 5;
    for (int base = blockIdx.x * 16; base < nrows; base += gridDim.x * 16) {
        const int n = base + slot;
        if (n < nrows) {
            const int t = n - (n / T_) * T_;
            for (int j = c; j < 128; j += 32) {
                hrow[slot][j]       = gldf(pos, (size_t)t * 128 + j, det);
                hrow[slot][128 + j] = hall0[(size_t)n * 128 + j];
            }
        }
        float4 acc = make_float4(0.f, 0.f, 0.f, 0.f);
        for (int kb = 0; kb < 256; kb += 64) {
            __syncthreads();
            for (int i = tid; i < 8192; i += 512) Ws[i] = gldf(W, (size_t)kb * 128 + i, det);
            __syncthreads();
            if (n < nrows) {
                #pragma unroll 8
                for (int k = 0; k < 64; ++k) {
                    float hv = hrow[slot][kb + k];
                    float4 w = *(const float4*)&Ws[k * 128 + c * 4];
                    acc.x += hv * w.x; acc.y += hv * w.y; acc.z += hv * w.z; acc.w += hv * w.w;
                }
            }
        }
        if (n < nrows) {
            float4 o;
            o.x = tanhf(acc.x); o.y = tanhf(acc.y); o.z = tanhf(acc.z); o.w = tanhf(acc.w);
            *(float4*)&nh[(size_t)n * 128 + c * 4] = o;
        }
        __syncthreads();
    }
}

__global__ __launch_bounds__(512) void t_glu_beta(
    const float* __restrict__ nh, const void* __restrict__ W, const void* __restrict__ gb,
    const float* __restrict__ g2, const void* __restrict__ w2, const int* __restrict__ mask,
    const int* __restrict__ fl, float* __restrict__ beta, int nrows)
{
    __shared__ float Ws[8192];
    __shared__ float hrow[16][128];
    const int det = *fl;
    const int tid = threadIdx.x, c = tid & 31, slot = tid >> 5;
    float4 gbv, w2v;
    gbv.x = gldf(gb, c * 4 + 0, det); gbv.y = gldf(gb, c * 4 + 1, det);
    gbv.z = gldf(gb, c * 4 + 2, det); gbv.w = gldf(gb, c * 4 + 3, det);
    w2v.x = gldf(w2, c * 4 + 0, det); w2v.y = gldf(w2, c * 4 + 1, det);
    w2v.z = gldf(w2, c * 4 + 2, det); w2v.w = gldf(w2, c * 4 + 3, det);
    for (int base = blockIdx.x * 16; base < nrows; base += gridDim.x * 16) {
        const int n = base + slot;
        if (n < nrows) for (int j = c; j < 128; j += 32) hrow[slot][j] = nh[(size_t)n * 128 + j];
        float4 acc = make_float4(0.f, 0.f, 0.f, 0.f);
        for (int kb = 0; kb < 128; kb += 64) {
            __syncthreads();
            for (int i = tid; i < 8192; i += 512) Ws[i] = gldf(W, (size_t)kb * 128 + i, det);
            __syncthreads();
            if (n < nrows) {
                #pragma unroll 8
                for (int k = 0; k < 64; ++k) {
                    float hv = hrow[slot][kb + k];
                    float4 w = *(const float4*)&Ws[k * 128 + c * 4];
                    acc.x += hv * w.x; acc.y += hv * w.y; acc.z += hv * w.z; acc.w += hv * w.w;
                }
            }
        }
        if (n < nrows) {
            const int b = n / T_;
            float4 gv = *(const float4*)&g2[(size_t)b * 128 + c * 4];
            float vx = sigm(acc.x + gbv.x + gv.x);
            float vy = sigm(acc.y + gbv.y + gv.y);
            float vz = sigm(acc.z + gbv.z + gv.z);
            float vw = sigm(acc.w + gbv.w + gv.w);
            float part = vx * w2v.x + vy * w2v.y + vz * w2v.z + vw * w2v.w;
            #pragma unroll
            for (int off = 16; off > 0; off >>= 1) part += __shfl_down(part, off, 32);
            if (c == 0) beta[n] = part * (float)mask[n];
        }
        __syncthreads();
    }
}

__global__ __launch_bounds__(128) void t_sel(
    const float* __restrict__ hall0, const float* __restrict__ beta,
    const void* __restrict__ g2, const void* __restrict__ b2,
    const float* __restrict__ feat, const int* __restrict__ lasti,
    const void* __restrict__ ys, const int* __restrict__ fl,
    float* __restrict__ hallf, float* __restrict__ fenmu, float* __restrict__ outh)
{
    __shared__ float bet[T_];
    __shared__ float red[128];
    const int b = blockIdx.x, tid = threadIdx.x;
    const int det = *fl;
    if (tid < T_) bet[tid] = beta[b * T_ + tid];
    __syncthreads();
    float acc = 0.f;
    for (int t = 0; t < T_; ++t) acc += bet[t] * hall0[((size_t)b * T_ + t) * 128 + tid];
    red[tid] = acc; __syncthreads();
    for (int off = 64; off > 0; off >>= 1) { if (tid < off) red[tid] += red[tid + off]; __syncthreads(); }
    float mu = red[0] * (1.f / 128.f);
    __syncthreads();
    float dv = acc - mu;
    red[tid] = dv * dv; __syncthreads();
    for (int off = 64; off > 0; off >>= 1) { if (tid < off) red[tid] += red[tid + off]; __syncthreads(); }
    float rs = 1.f / sqrtf(red[0] * (1.f / 128.f) + 1e-8f);
    __syncthreads();
    float h = dv * rs * gldf(g2, tid, det) + gldf(b2, tid, det)
            + feat[(size_t)lasti[b] * 128 + tid] * gldf(ys, 0, det);
    hallf[(size_t)b * 128 + tid] = h;
    outh[(size_t)b * 128 + tid] = h;
    red[tid] = h * h; __syncthreads();
    for (int off = 64; off > 0; off >>= 1) { if (tid < off) red[tid] += red[tid + off]; __syncthreads(); }
    if (tid == 0) fenmu[b] = sqrtf(red[0] + 128.f * 1e-6f);
}

__global__ __launch_bounds__(256) void t_cos(
    const float* __restrict__ hallf, const float* __restrict__ fenmu, float* __restrict__ out)
{
    __shared__ float hi[128];
    const int i = blockIdx.x, tid = threadIdx.x;
    if (tid < 128) hi[tid] = hallf[(size_t)i * 128 + tid];
    __syncthreads();
    const float fi = fenmu[i];
    for (int j = tid; j < B_; j += 256) {
        const float* hj = &hallf[(size_t)j * 128];
        float s = 0.f;
        for (int d = 0; d < 128; d += 4) {
            float4 a = *(const float4*)&hi[d];
            float4 bb = *(const float4*)&hj[d];
            s += a.x * bb.x + a.y * bb.y + a.z * bb.z + a.w * bb.w;
        }
        out[(size_t)i * B_ + j] = s / (fi * fenmu[j]);
    }
}

extern "C" void kernel_launch(void* const* d_in, const int* in_sizes, int n_in,
                              void* d_out, int out_size, void* d_ws, size_t ws_size,
                              hipStream_t stream)
{
    float* outf = (float*)d_out;
    const long OUT_N = (long)B_ * 128 + (long)B_ * B_;

    static const int EXP_SZ[41] = {
        12800000, 1280000, 25600, 32768, 131072, 1024, 1024, 1024, 32768, 128,
        32768, 128, 128, 32768, 128, 32768, 128, 16384, 128, 16384,
        128, 128, 128, 128, 1, 1, 100000, 100000, 10000, 800000,
        800000, 100000, 100000, 400000, 400000, 400000, 400000, 25600, 25600, 25600, 512 };
    float code = 0.f;
    if (n_in != 41) code = 90000.f + (float)n_in;
    else {
        for (int i = 0; i < 41; ++i)
            if (in_sizes[i] != EXP_SZ[i]) { code = 10000.f * (float)(i + 1); break; }
    }
    if (code == 0.f && out_size != (int)OUT_N) code = 95000.f;
    if (code != 0.f) {
        s_sig<<<dim3((unsigned)((OUT_N + 255) / 256)), dim3(256), 0, stream>>>(outf, OUT_N, code);
        return;
    }

    const void* item_emb = d_in[0];
    const void* cate_emb = d_in[1];
    const void* pos_emb  = d_in[2];
    const void* W_pos    = d_in[3];
    const void* gat_W    = d_in[4];
    const void* gat_al   = d_in[5];
    const void* gat_ar   = d_in[6];
    const void* gat_b    = d_in[7];
    const void* Wg1_w    = d_in[8];
    const void* Wg1_b    = d_in[9];
    const void* q        = d_in[12];
    const void* lin_w    = d_in[13];
    const void* lin_b    = d_in[14];
    const void* w_1      = d_in[15];
    const void* w_2      = d_in[16];
    const void* glu1_w   = d_in[17];
    const void* glu1_b   = d_in[18];
    const void* glu2_w   = d_in[19];
    const void* ln1_g    = d_in[20];
    const void* ln1_b    = d_in[21];
    const void* ln2_g    = d_in[22];
    const void* ln2_b    = d_in[23];
    const void* x_s      = d_in[24];
    const void* y_s      = d_in[25];
    const int* iid    = (const int*)d_in[26];
    const int* icate  = (const int*)d_in[27];
    const int* cid    = (const int*)d_in[28];
    const int* src_ii = (const int*)d_in[29];
    const int* dst_ii = (const int*)d_in[30];
    const int* src_cc = (const int*)d_in[31];
    const int* dst_cc = (const int*)d_in[32];
    const int* src_ci = (const int*)d_in[33];
    const int* dst_ci = (const int*)d_in[34];
    const int* src_ic = (const int*)d_in[35];
    const int* dst_ic = (const int*)d_in[36];
    const int* alias  = (const int*)d_in[37];
    const int* seq    = (const int*)d_in[38];
    const int* mask   = (const int*)d_in[39];
    const int* lasti  = (const int*)d_in[40];

    const size_t NEED_BASE = 64 + ((size_t)4 * NI_ + 3 * NC_) * 128 * 4
                                + ((size_t)3 * NI_ + 2 * NC_ + EII_) * 4;
    const size_t CSR_EXTRA = ((size_t)2 * (NI_ + 1) + 2 * (NC_ + 1)
                                + ECI_ + ECC_ + EIC_ + NI_) * 4;
    const size_t NEED_CSR = NEED_BASE + CSR_EXTRA;
    if (ws_size < NEED_BASE) {
        s_sig<<<dim3((unsigned)((OUT_N + 255) / 256)), dim3(256), 0, stream>>>(outf, OUT_N, 80000.f);
        return;
    }
    const bool useCSR = (ws_size >= NEED_CSR);
    const int mf = useCSR ? 1 : 0;

    int* flagp = (int*)d_ws;
    char* basep = (char*)d_ws;
    size_t off = 64;
    auto AL = [&](size_t nfl) { float* p = (float*)(basep + off); off += nfl * 4; return p; };
    float* hi0 = AL((size_t)NI_ * 128);
    float* HiA = AL((size_t)NI_ * 128);
    float* HiB = AL((size_t)NI_ * 128);   // binned edges during build | score scratch | L1 acc
    float* zA  = AL((size_t)NI_ * 128);   // two fp16 z's | feat fp32 later
    float* hc0 = AL((size_t)NC_ * 128);
    float* HcA = AL((size_t)NC_ * 128);
    float* zC  = AL((size_t)NC_ * 128);   // two fp16 z's
    float* sAl = AL(NI_); float* sAr = AL(NI_);
    float* sCl = AL(NC_); float* sCr = AL(NC_);
    float* denF = AL(NI_);          // fallback den | CSR: bsum[0,4KB) wars gcur wt_lo[17408,..)
    float* eF   = AL(EII_);         // fallback e   | CSR: colsrc_ii
    int* rpII = (int*)AL(NI_ + 1);
    int* rpCI = (int*)AL(NI_ + 1);
    int* rpCC = (int*)AL(NC_ + 1);
    int* rpIC = (int*)AL(NC_ + 1);
    int* csCI = (int*)AL(ECI_);
    int* csCC = (int*)AL(ECC_);
    int* csIC = (int*)AL(EIC_);
    int* wtregion = (int*)AL(NI_);  // wt_hi (320 KB)
    int* csII = (int*)eF;
    int* bsum = (int*)denF;                         // ints [0,1024)
    float* wars = denF + 1024;                      // 3x128 floats
    int* gcur = ((int*)denF) + 1408;                // 108 ints
    u16* wt_hi = (u16*)wtregion;                    // 20480 slots * 16 B
    u16* wt_lo = (u16*)((char*)denF + 17408);
    __half* zAh  = (__half*)zA;
    __half* zA2h = zAh + (size_t)NI_ * 128;
    __half* zCh  = (__half*)zC;
    __half* zC2h = zCh + (size_t)NC_ * 128;
    // binned edge arrays (build-time) live in HiB
    u32* binII = (u32*)HiB;
    u32* binCI = binII + EII_;
    u32* binCC = binCI + ECI_;
    u32* binIC = binCC + ECC_;
    // layer-0 score scratch (after build) also in HiB
    float* sl03p = HiB;
    float* sr03s = HiB + NI_;
    float* sl02p = HiB + 2 * (size_t)NI_;
    float* sr02s = sl02p + NC_;
    // attention-phase packed weights (w_1 + glu1_w = 6144 slots) live in dead HiA
    u16* wt2_hi = (u16*)HiA;
    u16* wt2_lo = wt2_hi + (size_t)6144 * 8;

    auto WTS = [&](int l, int k) {                  // slot base (u16 units) for gat_W (l,k)
        int midx = (l == 0) ? k : ((k == 0) ? 4 : 5);
        return (size_t)(8192 + midx * 2048) * 8;
    };

    float* feat = zA;
    float* hall0 = hi0;
    float* nh    = hall0 + (size_t)B_ * T_ * 128;
    float* vbuf  = nh    + (size_t)B_ * T_ * 128;
    float* hsb   = vbuf  + (size_t)B_ * T_ * 128;
    float* hsv   = hsb   + (size_t)B_ * T_;
    float* hsvn  = hsv   + (size_t)B_ * 128;
    float* hsv2  = hsvn  + (size_t)B_ * 128;
    float* g2b   = hsv2  + (size_t)B_ * 128;
    float* betab = g2b   + (size_t)B_ * 128;
    float* hallf = betab + (size_t)B_ * T_;
    float* fenmu = hallf + (size_t)B_ * 128;

    #define GRL(n) dim3((unsigned)(((long)(n) + 255) / 256))
    auto WOFF = [](int l, int k) { return (l * 4 + k) * 16384; };
    auto VOFF = [](int l, int k) { return (l * 4 + k) * 128; };

    auto seg = [&](const float* sl, const float* sr, const int* s, const int* d,
                   int E, int ndst, const __half* z, float* acc) {
        s_dinit<<<GRL(ndst), dim3(256), 0, stream>>>(denF, ndst);
        s_edge<<<GRL(E), dim3(256), 0, stream>>>(sl, sr, s, d, eF, denF, E);
        s_scatter<<<GRL((long)E * 128), dim3(256), 0, stream>>>(eF, denF, s, d, z, acc, E);
    };

    k_init<<<dim3(1), dim3(128), 0, stream>>>(item_emb, flagp);

    if (useCSR) {
        int* cu0 = (int*)sAr; int* cu1 = (int*)sAl; int* cu2 = (int*)sCl; int* cu3 = (int*)sCr;
        const int ET = EII_ + ECI_ + ECC_ + EIC_;
        const int NB4 = ((NI_ + 1023) >> 10) * 2 + ((NC_ + 1023) >> 10) * 2;
        k_pre<<<dim3(5943), dim3(256), 0, stream>>>(
            cate_emb, cid, hc0, cu0, cu1, cu2, cu3,
            W_pos, Wg1_w, gat_W, wt_hi, wt_lo, gat_ar, wars, flagp);
        k_hist4<<<GRL(ET), dim3(256), 0, stream>>>(dst_ii, EII_, dst_ci, ECI_, dst_cc, ECC_, dst_ic, EIC_,
                                                   cu0, cu1, cu2, cu3);
        k_bsum4<<<dim3(NB4), dim3(256), 0, stream>>>(cu0, NI_, cu1, NI_, cu2, NC_, cu3, NC_, bsum);
        k_scanb4<<<dim3(4), dim3(1), 0, stream>>>(bsum, NI_, NI_, NC_, NC_, rpII, rpCI, rpCC, rpIC);
        k_scanfinal4<<<dim3(NB4), dim3(256), 0, stream>>>(cu0, NI_, cu1, NI_, cu2, NC_, cu3, NC_,
                                                          bsum, rpII, rpCI, rpCC, rpIC);
        k_gcur<<<dim3(1), dim3(128), 0, stream>>>(rpII, rpCI, rpCC, rpIC, gcur);
        k_binA<<<dim3((ET + ECH_ - 1) / ECH_), dim3(256), 0, stream>>>(
            src_ii, dst_ii, src_ci, dst_ci, src_cc, dst_cc, src_ic, dst_ic,
            gcur, binII, binCI, binCC, binIC);
        k_binB<<<dim3(NBK_), dim3(256), 0, stream>>>(
            rpII, rpCI, rpCC, rpIC, binII, binCI, binCC, binIC,
            csII, csCI, csCC, csIC);
        m_hi0<<<dim3((NI_ + 63) / 64), dim3(256), 0, stream>>>(
            item_emb, cate_emb, iid, icate, wt_hi, wt_lo, flagp, flagp + 1, hi0, NI_);
        // ---- layer 0 z-gemms (dual-weight)
        m_zgemm2<<<dim3((NI_ + 63) / 64), dim3(256), 0, stream>>>(
            hi0, NI_,
            wt_hi + WTS(0, 0), wt_lo + WTS(0, 0), VOFF(0, 0), VOFF(0, 0), zAh,  sAl,   sAr,
            wt_hi + WTS(0, 3), wt_lo + WTS(0, 3), VOFF(0, 3), VOFF(0, 3), zA2h, sl03p, sr03s,
            gat_al, gat_ar, flagp, flagp + 1);
        m_zgemm2<<<dim3((NC_ + 63) / 64), dim3(256), 0, stream>>>(
            hc0, NC_,
            wt_hi + WTS(0, 1), wt_lo + WTS(0, 1), VOFF(0, 1), VOFF(0, 1), zC2h, sCl,   sCr,
            wt_hi + WTS(0, 2), wt_lo + WTS(0, 2), VOFF(0, 2), VOFF(0, 2), zCh,  sl02p, sr02s,
            gat_al, gat_ar, flagp, flagp + 1);
        // ---- layer 0 aggs
        t_gat_fused<<<dim3((NI_ + 3) / 4), dim3(256), 0, stream>>>(
            rpII, csII, sAl, sAr, (const __half2*)zAh,
            rpCI, csCI, sl02p, wars + 0, (const __half2*)zCh,
            hi0, gat_b, VOFF(0, 0), VOFF(0, 2), flagp, HiA, NI_);
        t_gat_fused<<<dim3((NC_ + 3) / 4), dim3(256), 0, stream>>>(
            rpCC, csCC, sCl, sCr, (const __half2*)zC2h,
            rpIC, csIC, sl03p, wars + 128, (const __half2*)zA2h,
            hc0, gat_b, VOFF(0, 1), VOFF(0, 3), flagp, HcA, NC_);
        // ---- layer 1
        m_zgemm<<<dim3((NI_ + 63) / 64), dim3(256), 0, stream>>>(
            HiA, NI_, wt_hi + WTS(1, 0), wt_lo + WTS(1, 0),
            gat_al, VOFF(1, 0), gat_ar, VOFF(1, 0), flagp, flagp + 1, zAh, sAl, sAr);
        m_zgemm<<<dim3((NC_ + 63) / 64), dim3(256), 0, stream>>>(
            HcA, NC_, wt_hi + WTS(1, 2), wt_lo + WTS(1, 2),
            gat_al, VOFF(1, 2), gat_ar, VOFF(1, 2), flagp, flagp + 1, zCh, sCl, sCr);
        t_gat_fused<<<dim3((NI_ + 3) / 4), dim3(256), 0, stream>>>(
            rpII, csII, sAl, sAr, (const __half2*)zAh,
            rpCI, csCI, sCl, wars + 256, (const __half2*)zCh,
            HiA, gat_b, VOFF(1, 0), VOFF(1, 2), flagp, HiB, NI_);
        // HiA now dead: pack attention-phase weights into it
        k_prepw3<<<dim3(24), dim3(256), 0, stream>>>(w_1, glu1_w, flagp, wt2_hi, wt2_lo);
        m_gatefeat<<<dim3((NI_ + 63) / 64), dim3(256), 0, stream>>>(
            hi0, HiB, wt_hi + (size_t)4096 * 8, wt_lo + (size_t)4096 * 8, Wg1_b, flagp, flagp + 1, feat, NI_);
    } else {
        s_hc0<<<GRL((long)NC_ * 128), dim3(256), 0, stream>>>(cate_emb, cid, flagp, hc0);
        t_hi0<<<dim3(768), dim3(512), 0, stream>>>(item_emb, cate_emb, iid, icate, W_pos, flagp, hi0, NI_);
        s_initacc<<<GRL((long)NI_ * 128), dim3(256), 0, stream>>>(hi0, gat_b, VOFF(0, 0), VOFF(0, 2), flagp, HiA, (long)NI_ * 128);
        s_initacc<<<GRL((long)NC_ * 128), dim3(256), 0, stream>>>(hc0, gat_b, VOFF(0, 1), VOFF(0, 3), flagp, HcA, (long)NC_ * 128);
        t_zgemm<<<dim3(1024), dim3(512), 0, stream>>>(hi0, NI_, gat_W, WOFF(0, 0), gat_al, VOFF(0, 0), gat_ar, VOFF(0, 0), flagp, zAh, sAl, sAr);
        seg(sAl, sAr, src_ii, dst_ii, EII_, NI_, zAh, HiA);
        t_zgemm<<<dim3(625), dim3(512), 0, stream>>>(hc0, NC_, gat_W, WOFF(0, 2), gat_al, VOFF(0, 2), gat_ar, VOFF(0, 2), flagp, zCh, sCl, sCr);
        t_zgemm<<<dim3(1024), dim3(512), 0, stream>>>(hi0, NI_, gat_W, WOFF(0, 2), gat_al, VOFF(0, 2), gat_ar, VOFF(0, 2), flagp, zAh, sAl, sAr);
        seg(sCl, sAr, src_ci, dst_ci, ECI_, NI_, zCh, HiA);
        t_zgemm<<<dim3(625), dim3(512), 0, stream>>>(hc0, NC_, gat_W, WOFF(0, 1), gat_al, VOFF(0, 1), gat_ar, VOFF(0, 1), flagp, zCh, sCl, sCr);
        seg(sCl, sCr, src_cc, dst_cc, ECC_, NC_, zCh, HcA);
        t_zgemm<<<dim3(1024), dim3(512), 0, stream>>>(hi0, NI_, gat_W, WOFF(0, 3), gat_al, VOFF(0, 3), gat_ar, VOFF(0, 3), flagp, zAh, sAl, sAr);
        t_zgemm<<<dim3(625), dim3(512), 0, stream>>>(hc0, NC_, gat_W, WOFF(0, 3), gat_al, VOFF(0, 3), gat_ar, VOFF(0, 3), flagp, zCh, sCl, sCr);
        seg(sAl, sCr, src_ic, dst_ic, EIC_, NC_, zAh, HcA);
        s_initacc<<<GRL((long)NI_ * 128), dim3(256), 0, stream>>>(HiA, gat_b, VOFF(1, 0), VOFF(1, 2), flagp, HiB, (long)NI_ * 128);
        t_zgemm<<<dim3(1024), dim3(512), 0, stream>>>(HiA, NI_, gat_W, WOFF(1, 0), gat_al, VOFF(1, 0), gat_ar, VOFF(1, 0), flagp, zAh, sAl, sAr);
        seg(sAl, sAr, src_ii, dst_ii, EII_, NI_, zAh, HiB);
        t_zgemm<<<dim3(625), dim3(512), 0, stream>>>(HcA, NC_, gat_W, WOFF(1, 2), gat_al, VOFF(1, 2), gat_ar, VOFF(1, 2), flagp, zCh, sCl, sCr);
        t_zgemm<<<dim3(1024), dim3(512), 0, stream>>>(HiA, NI_, gat_W, WOFF(1, 2), gat_al, VOFF(1, 2), gat_ar, VOFF(1, 2), flagp, zAh, sAl, sAr);
        seg(sCl, sAr, src_ci, dst_ci, ECI_, NI_, zCh, HiB);
        t_gatefeat<<<dim3(768), dim3(512), 0, stream>>>(hi0, HiB, Wg1_w, Wg1_b, flagp, feat, NI_);
    }

    s_hall0<<<GRL((long)B_ * T_ * 128), dim3(256), 0, stream>>>(item_emb, seq, alias, mask, feat, x_s, flagp, hall0);
    t_attn12<<<dim3(B_), dim3(128), 0, stream>>>(hall0, q, mask, ln1_g, ln1_b, lin_w, lin_b, glu2_w, flagp, g2b);
    if (mf) {
        m_nh<<<dim3((B_ * T_ + 63) / 64), dim3(256), 0, stream>>>(
            pos_emb, hall0, wt2_hi, wt2_lo, flagp, flagp + 1, nh, B_ * T_);
        m_glub<<<dim3((B_ * T_ + 63) / 64), dim3(256), 0, stream>>>(
            nh, wt2_hi + (size_t)4096 * 8, wt2_lo + (size_t)4096 * 8,
            glu1_b, g2b, w_2, mask, flagp, flagp + 1, betab, B_ * T_);
    } else {
        int grid = (B_ * T_ + 15) / 16; if (grid > 1024) grid = 1024;
        t_nh<<<dim3(grid), dim3(512), 0, stream>>>(pos_emb, hall0, w_1, flagp, nh, B_ * T_);
        t_glu_beta<<<dim3(grid), dim3(512), 0, stream>>>(nh, glu1_w, glu1_b, g2b, w_2, mask, flagp, betab, B_ * T_);
    }
    t_sel<<<dim3(B_), dim3(128), 0, stream>>>(hall0, betab, ln2_g, ln2_b, feat, lasti, y_s, flagp, hallf, fenmu, outf);
    t_cos<<<dim3(B_), dim3(256), 0, stream>>>(hallf, fenmu, outf + (size_t)B_ * 128);
}

// Round 8
// 932.013 us; speedup vs baseline: 1.0972x; 1.0972x over previous
//
#include <hip/hip_runtime.h>
#include <hip/hip_fp16.h>

typedef unsigned short u16;
typedef unsigned int u32;
typedef unsigned long long u64;
typedef __attribute__((ext_vector_type(8))) short bf16x8;   // 8 bf16 = 4 VGPRs
typedef __attribute__((ext_vector_type(4))) float f32x4;    // MFMA 16x16 accumulator

#define NI_ 100000
#define NC_ 10000
#define EII_ 800000
#define ECC_ 100000
#define ECI_ 400000
#define EIC_ 400000
#define B_ 512
#define T_ 50
#define BSH_ 9            // 512-dst buckets
#define NBII_ 196         // ceil(100000/512)
#define NBNC_ 20          // ceil(10000/512)
#define NBK_ 432          // 196 II + 196 CI + 20 CC + 20 IC
#define ECH_ 4096         // edges per binning chunk

__device__ __forceinline__ float bf2f(u16 u) { return __uint_as_float(((u32)u) << 16); }
__device__ __forceinline__ u16 f2bf(float x) {
    u32 u = __float_as_uint(x);
    return (u16)((u + 0x7FFFu + ((u >> 16) & 1u)) >> 16);   // RNE
}
__device__ __forceinline__ float sigm(float x) { return 1.f / (1.f + expf(-x)); }
__device__ __forceinline__ float gldf(const void* p, size_t i, int isf) {
    return isf ? ((const float*)p)[i] : bf2f(((const u16*)p)[i]);
}
__device__ __forceinline__ float lrelu_c(float v) {
    v = (v >= 0.f) ? v : 0.2f * v;
    return fminf(fmaxf(v, -60.f), 60.f);
}

// init: dtype detect + MFMA layout self-check
__global__ void k_init(const void* __restrict__ item, int* __restrict__ flag)
{
    const int tid = threadIdx.x;
    if (tid < 64) {
        const int l = tid;
        bf16x8 a, b;
        #pragma unroll
        for (int j = 0; j < 8; ++j) {
            int ka = (l >> 4) * 8 + j;
            float av = (float)((((l & 15) * 5 + ka * 3) & 15) - 7);
            float bv = (float)(((ka * 7 + (l & 15) * 11) & 15) - 8);
            a[j] = (short)f2bf(av);
            b[j] = (short)f2bf(bv);
        }
        f32x4 d = {0.f, 0.f, 0.f, 0.f};
        d = __builtin_amdgcn_mfma_f32_16x16x32_bf16(a, b, d, 0, 0, 0);
        bool ok = true;
        #pragma unroll
        for (int j = 0; j < 4; ++j) {
            int row = (l >> 4) * 4 + j, col = l & 15;
            float ref = 0.f;
            for (int k = 0; k < 32; ++k)
                ref += (float)(((row * 5 + k * 3) & 15) - 7) * (float)(((k * 7 + col * 11) & 15) - 8);
            ok = ok && (d[j] == ref);
        }
        unsigned long long vote = __ballot(ok);
        if (l == 0) flag[1] = (vote == ~0ull) ? 1 : 0;
    } else if (tid == 64) {
        const u16* p = (const u16*)item;
        int cnt = 0;
        for (int i = 0; i < 128; ++i) {
            float v = bf2f(p[i]);
            if (fabsf(v) <= 0.0886f) ++cnt;
        }
        flag[0] = (cnt >= 120) ? 0 : 1;
    }
}

__global__ void s_sig(float* __restrict__ out, long n, float code)
{
    long i = (long)blockIdx.x * 256 + threadIdx.x;
    if (i < n) out[i] = (i == 0) ? code : 0.f;
}

// ============ merged pre-pass: hc0 gather | cursor zero | weight pack | war vecs ============
// roles by block range: [0,5000) hc0, [5000,5860) zero, [5860,5940) prepw2, [5940,5943) wvec3
__global__ __launch_bounds__(256) void k_pre(
    const void* __restrict__ cate, const int* __restrict__ cid, float* __restrict__ hc0,
    int* __restrict__ cu0, int* __restrict__ cu1, int* __restrict__ cu2, int* __restrict__ cu3,
    const void* __restrict__ Wp, const void* __restrict__ Wg1, const void* __restrict__ gW,
    u16* __restrict__ whi, u16* __restrict__ wlo,
    const void* __restrict__ ar, float* __restrict__ wars,
    const int* __restrict__ fl)
{
    const int det = fl[0];
    int bid = blockIdx.x, tid = threadIdx.x;
    if (bid < 5000) {
        long i = (long)bid * 256 + tid;
        if (i < (long)NC_ * 128)
            hc0[i] = gldf(cate, (size_t)cid[i >> 7] * 128 + (i & 127), det);
        return;
    }
    bid -= 5000;
    if (bid < 860) {
        int i = bid * 256 + tid;
        if (i < NI_) { cu0[i] = 0; return; } i -= NI_;
        if (i < NI_) { cu1[i] = 0; return; } i -= NI_;
        if (i < NC_) { cu2[i] = 0; return; } i -= NC_;
        if (i < NC_) cu3[i] = 0;
        return;
    }
    bid -= 860;
    if (bid < 80) {
        int s = bid * 256 + tid;
        if (s >= 20480) return;
        const void* src; int K, local; size_t soff;
        if (s < 4096)       { src = Wp;  K = 256; local = s;        soff = 0; }
        else if (s < 8192)  { src = Wg1; K = 256; local = s - 4096; soff = 0; }
        else {
            int t = s - 8192; int m = t >> 11; local = t & 2047; K = 128;
            const int MK[6] = {0, 1, 2, 3, 4, 6};
            src = gW; soff = (size_t)MK[m] * 16384;
        }
        const int KK = K >> 5;
        int r = local & 15, g = (local >> 4) & 3, q2 = local >> 6;
        int kk = q2 % KK, ni = q2 / KK;
        bf16x8 hv, lv;
        #pragma unroll
        for (int j = 0; j < 8; ++j) {
            float x = gldf(src, soff + (size_t)(kk * 32 + 8 * g + j) * 128 + ni * 16 + r, det);
            u16 hb = f2bf(x);
            hv[j] = (short)hb;
            lv[j] = (short)f2bf(x - bf2f(hb));
        }
        *(bf16x8*)(whi + (size_t)s * 8) = hv;
        *(bf16x8*)(wlo + (size_t)s * 8) = lv;
        return;
    }
    bid -= 80;
    if (tid < 128) {
        // wars: g=0 -> (0,2), g=1 -> (0,3), g=2 -> (1,2)
        const int WO[3] = {2 * 16384, 3 * 16384, 6 * 16384};
        const int AO[3] = {2 * 128, 3 * 128, 6 * 128};
        int g = bid, k = tid;
        float a = 0.f;
        for (int c = 0; c < 128; ++c)
            a += gldf(gW, (size_t)WO[g] + (size_t)k * 128 + c, det) * gldf(ar, AO[g] + c, det);
        wars[g * 128 + k] = a;
    }
}

// ================= batched CSR build =================
__global__ __launch_bounds__(256) void k_hist4(
    const int* d0, int E0, const int* d1, int E1,
    const int* d2, int E2, const int* d3, int E3,
    int* c0, int* c1, int* c2, int* c3)
{
    int i = blockIdx.x * 256 + threadIdx.x;
    if (i < E0) { atomicAdd(&c0[d0[i]], 1); return; } i -= E0;
    if (i < E1) { atomicAdd(&c1[d1[i]], 1); return; } i -= E1;
    if (i < E2) { atomicAdd(&c2[d2[i]], 1); return; } i -= E2;
    if (i < E3) atomicAdd(&c3[d3[i]], 1);
}

__device__ __forceinline__ void map4(
    int b, int n0, int n1, int n2, int n3, int& g, int& lb)
{
    int nB0 = (n0 + 1023) >> 10, nB1 = (n1 + 1023) >> 10;
    int nB2 = (n2 + 1023) >> 10;
    if (b < nB0) { g = 0; lb = b; return; } b -= nB0;
    if (b < nB1) { g = 1; lb = b; return; } b -= nB1;
    if (b < nB2) { g = 2; lb = b; return; } b -= nB2;
    g = 3; lb = b;
}

__global__ __launch_bounds__(256) void k_bsum4(
    const int* c0, int n0, const int* c1, int n1,
    const int* c2, int n2, const int* c3, int n3, int* bsum)
{
    int g, lb;
    map4(blockIdx.x, n0, n1, n2, n3, g, lb);
    const int* cnt = (g == 0) ? c0 : (g == 1) ? c1 : (g == 2) ? c2 : c3;
    const int n = (g == 0) ? n0 : (g == 1) ? n1 : (g == 2) ? n2 : n3;
    __shared__ int sh[256];
    int t = threadIdx.x, base = lb * 1024 + t * 4;
    int s = 0;
    #pragma unroll
    for (int j = 0; j < 4; ++j) if (base + j < n) s += cnt[base + j];
    sh[t] = s; __syncthreads();
    for (int o = 128; o > 0; o >>= 1) { if (t < o) sh[t] += sh[t + o]; __syncthreads(); }
    if (t == 0) bsum[g * 256 + lb] = sh[0];
}

__global__ void k_scanb4(
    int* bsum, int n0, int n1, int n2, int n3,
    int* r0, int* r1, int* r2, int* r3)
{
    if (threadIdx.x != 0) return;
    int g = blockIdx.x;
    int n = (g == 0) ? n0 : (g == 1) ? n1 : (g == 2) ? n2 : n3;
    int* rp = (g == 0) ? r0 : (g == 1) ? r1 : (g == 2) ? r2 : r3;
    int nB = (n + 1023) >> 10;
    int run = 0;
    for (int i = 0; i < nB; ++i) { int v = bsum[g * 256 + i]; bsum[g * 256 + i] = run; run += v; }
    rp[n] = run;
}

__global__ __launch_bounds__(256) void k_scanfinal4(
    int* c0, int n0, int* c1, int n1, int* c2, int n2, int* c3, int n3,
    const int* bsum, int* r0, int* r1, int* r2, int* r3)
{
    int g, lb;
    map4(blockIdx.x, n0, n1, n2, n3, g, lb);
    int* cnt = (g == 0) ? c0 : (g == 1) ? c1 : (g == 2) ? c2 : c3;
    const int n = (g == 0) ? n0 : (g == 1) ? n1 : (g == 2) ? n2 : n3;
    int* rowptr = (g == 0) ? r0 : (g == 1) ? r1 : (g == 2) ? r2 : r3;
    __shared__ int sh[256];
    int t = threadIdx.x, base = lb * 1024 + t * 4;
    int c0v = (base + 0 < n) ? cnt[base + 0] : 0;
    int c1v = (base + 1 < n) ? cnt[base + 1] : 0;
    int c2v = (base + 2 < n) ? cnt[base + 2] : 0;
    int c3v = (base + 3 < n) ? cnt[base + 3] : 0;
    int tsum = c0v + c1v + c2v + c3v;
    sh[t] = tsum; __syncthreads();
    for (int s = 1; s < 256; s <<= 1) {
        int v = (t >= s) ? sh[t - s] : 0;
        __syncthreads();
        sh[t] += v;
        __syncthreads();
    }
    int off = bsum[g * 256 + lb] + sh[t] - tsum;
    if (base + 0 < n) { rowptr[base + 0] = off; off += c0v; }
    if (base + 1 < n) { rowptr[base + 1] = off; off += c1v; }
    if (base + 2 < n) { rowptr[base + 2] = off; off += c2v; }
    if (base + 3 < n) { rowptr[base + 3] = off; off += c3v; }
}

// bucket cursors (432) seeded from rowptr at 512-dst boundaries
__global__ void k_gcur(
    const int* rpII, const int* rpCI, const int* rpCC, const int* rpIC, int* gcur)
{
    int t = threadIdx.x;
    if (t < NBII_)                gcur[t] = rpII[t << BSH_];
    else if (t < 2 * NBII_)       gcur[t] = rpCI[(t - NBII_) << BSH_];
    else if (t < 2 * NBII_ + NBNC_)        gcur[t] = rpCC[(t - 2 * NBII_) << BSH_];
    else if (t < NBK_)            gcur[t] = rpIC[(t - 2 * NBII_ - NBNC_) << BSH_];
}

// phase A: bin edges by 512-dst bucket; LDS-compact, burst-write (src<<BSH|dstlocal)
__global__ __launch_bounds__(256) void k_binA(
    const int* s0, const int* d0, const int* s1, const int* d1,
    const int* s2, const int* d2, const int* s3, const int* d3,
    int* __restrict__ gcur,
    u32* __restrict__ b0, u32* __restrict__ b1,
    u32* __restrict__ b2, u32* __restrict__ b3)
{
    __shared__ u32 stag[ECH_];
    __shared__ int cnt[NBK_], base_l[NBK_ + 1], gbase[NBK_], cur_l[NBK_];
    const int tid = threadIdx.x;
    const long estart = (long)blockIdx.x * ECH_;
    const long ET = (long)EII_ + ECI_ + ECC_ + EIC_;
    for (int b = tid; b < NBK_; b += 256) cnt[b] = 0;
    __syncthreads();
    int gidv[16]; u32 pk[16];
    #pragma unroll
    for (int j = 0; j < 16; ++j) {
        long i = estart + j * 256 + tid;
        gidv[j] = -1;
        if (i < ET) {
            int src, dst, boff;
            long ii = i;
            if (ii < EII_) { src = s0[ii]; dst = d0[ii]; boff = 0; }
            else { ii -= EII_;
            if (ii < ECI_) { src = s1[ii]; dst = d1[ii]; boff = NBII_; }
            else { ii -= ECI_;
            if (ii < ECC_) { src = s2[ii]; dst = d2[ii]; boff = 2 * NBII_; }
            else { ii -= ECC_; src = s3[ii]; dst = d3[ii]; boff = 2 * NBII_ + NBNC_; } } }
            int gid = boff + (dst >> BSH_);
            gidv[j] = gid;
            pk[j] = ((u32)src << BSH_) | (u32)(dst & ((1 << BSH_) - 1));
            atomicAdd(&cnt[gid], 1);
        }
    }
    __syncthreads();
    if (tid == 0) {
        int run = 0;
        for (int b = 0; b < NBK_; ++b) { base_l[b] = run; run += cnt[b]; }
        base_l[NBK_] = run;
    }
    __syncthreads();
    for (int b = tid; b < NBK_; b += 256) {
        gbase[b] = cnt[b] ? atomicAdd(&gcur[b], cnt[b]) : 0;
        cur_l[b] = base_l[b];
    }
    __syncthreads();
    #pragma unroll
    for (int j = 0; j < 16; ++j)
        if (gidv[j] >= 0) {
            int l = atomicAdd(&cur_l[gidv[j]], 1);
            stag[l] = pk[j];
        }
    __syncthreads();
    const int total = base_l[NBK_];
    for (int t = tid; t < total; t += 256) {
        int lo = 0, hi = NBK_ - 1;
        while (lo < hi) { int mid = (lo + hi + 1) >> 1; if (base_l[mid] <= t) lo = mid; else hi = mid - 1; }
        int pos = gbase[lo] + (t - base_l[lo]);
        u32* bp = (lo < NBII_) ? b0 : (lo < 2 * NBII_) ? b1 : (lo < 2 * NBII_ + NBNC_) ? b2 : b3;
        bp[pos] = stag[t];
    }
}

// phase B: per-bucket fine fill — scattered writes confined to one block's 2KB window
__global__ __launch_bounds__(256) void k_binB(
    const int* rpII, const int* rpCI, const int* rpCC, const int* rpIC,
    const u32* b0, const u32* b1, const u32* b2, const u32* b3,
    int* csII, int* csCI, int* csCC, int* csIC)
{
    __shared__ int cur[1 << BSH_];
    const int gid = blockIdx.x, tid = threadIdx.x;
    const int* rp; const u32* bp; int* cs; int b, n;
    if (gid < NBII_)                 { rp = rpII; bp = b0; cs = csII; b = gid;                    n = NI_; }
    else if (gid < 2 * NBII_)        { rp = rpCI; bp = b1; cs = csCI; b = gid - NBII_;            n = NI_; }
    else if (gid < 2 * NBII_ + NBNC_){ rp = rpCC; bp = b2; cs = csCC; b = gid - 2 * NBII_;        n = NC_; }
    else                             { rp = rpIC; bp = b3; cs = csIC; b = gid - 2 * NBII_ - NBNC_; n = NC_; }
    const int dz = b << BSH_;
    const int d1v = (dz + (1 << BSH_) < n) ? dz + (1 << BSH_) : n;
    const int ndl = d1v - dz;
    for (int dl = tid; dl < ndl; dl += 256) cur[dl] = rp[dz + dl];
    __syncthreads();
    const int e0 = rp[dz], e1 = rp[d1v];
    for (int e = e0 + tid; e < e1; e += 256) {
        u32 p = bp[e];
        int dl = (int)(p & ((1 << BSH_) - 1));
        int pos = atomicAdd(&cur[dl], 1);
        cs[pos] = (int)(p >> BSH_);
    }
}

// ========== GAT aggregation (fused, shuffle-cached alphas, fp16 z, 8-wide ILP) ==========
__device__ __forceinline__ void gat_gather(
    const int* __restrict__ rp, const int* __restrict__ cs,
    const float* __restrict__ sl, float srd, const __half2* __restrict__ z,
    int w, int lane, float& a0, float& a1)
{
    const int start = rp[w], end = rp[w + 1];
    if (end <= start) return;
    const int cnt = end - start;
    int   sE = 0; float eE = 0.f;
    if (lane < cnt) {
        sE = cs[start + lane];
        eE = expf(lrelu_c(sl[sE] + srd));
    }
    float local = eE;
    for (int k = start + 64 + lane; k < end; k += 64)
        local += expf(lrelu_c(sl[cs[k]] + srd));
    #pragma unroll
    for (int o = 32; o > 0; o >>= 1) local += __shfl_xor(local, o, 64);
    const float inv = 1.f / local;
    const int m = (cnt < 64) ? cnt : 64;
    int k = 0;
    for (; k + 8 <= m; k += 8) {
        int   s[8]; float lw[8]; float2 f[8];
        #pragma unroll
        for (int u = 0; u < 8; ++u) {
            s[u]  = __shfl(sE, k + u, 64);
            lw[u] = __shfl(eE, k + u, 64) * inv;
        }
        #pragma unroll
        for (int u = 0; u < 8; ++u) f[u] = __half22float2(z[(size_t)s[u] * 64 + lane]);
        #pragma unroll
        for (int u = 0; u < 8; ++u) { a0 += lw[u] * f[u].x; a1 += lw[u] * f[u].y; }
    }
    for (; k + 4 <= m; k += 4) {
        int s0 = __shfl(sE, k, 64),     s1 = __shfl(sE, k + 1, 64);
        int s2 = __shfl(sE, k + 2, 64), s3 = __shfl(sE, k + 3, 64);
        float l0 = __shfl(eE, k, 64) * inv,     l1 = __shfl(eE, k + 1, 64) * inv;
        float l2 = __shfl(eE, k + 2, 64) * inv, l3 = __shfl(eE, k + 3, 64) * inv;
        float2 f0 = __half22float2(z[(size_t)s0 * 64 + lane]);
        float2 f1 = __half22float2(z[(size_t)s1 * 64 + lane]);
        float2 f2 = __half22float2(z[(size_t)s2 * 64 + lane]);
        float2 f3 = __half22float2(z[(size_t)s3 * 64 + lane]);
        a0 += l0 * f0.x + l1 * f1.x + l2 * f2.x + l3 * f3.x;
        a1 += l0 * f0.y + l1 * f1.y + l2 * f2.y + l3 * f3.y;
    }
    for (; k < m; ++k) {
        int s = __shfl(sE, k, 64);
        float al = __shfl(eE, k, 64) * inv;
        float2 f = __half22float2(z[(size_t)s * 64 + lane]);
        a0 += al * f.x;
        a1 += al * f.y;
    }
    for (int kk = start + 64; kk < end; ++kk) {   // rare: degree > 64
        int s = cs[kk];
        float al = expf(lrelu_c(sl[s] + srd)) * inv;
        float2 f = __half22float2(z[(size_t)s * 64 + lane]);
        a0 += al * f.x;
        a1 += al * f.y;
    }
}

// acc = 2*h0 + gb[b0] + gb[b1] + sum_A(alpha*zA[src]) + sum_B(alpha*zB[src])
__global__ __launch_bounds__(256) void t_gat_fused(
    const int* __restrict__ rpA, const int* __restrict__ csA,
    const float* __restrict__ slA, const float* __restrict__ srA, const __half2* __restrict__ zA_,
    const int* __restrict__ rpB, const int* __restrict__ csB,
    const float* __restrict__ slB, const float* __restrict__ war, const __half2* __restrict__ zB_,
    const float* __restrict__ h0, const void* __restrict__ gb, int b0off, int b1off,
    const int* __restrict__ fl, float* __restrict__ acc, int ndst)
{
    int w = blockIdx.x * 4 + (threadIdx.x >> 6);
    int lane = threadIdx.x & 63;
    if (w >= ndst) return;
    const int det = *fl;
    const int d0 = 2 * lane, d1 = 2 * lane + 1;
    float2 h0v = *(const float2*)(h0 + (size_t)w * 128 + d0);
    float2 wv  = *(const float2*)(war + d0);
    float srB = h0v.x * wv.x + h0v.y * wv.y;
    #pragma unroll
    for (int off = 32; off > 0; off >>= 1) srB += __shfl_xor(srB, off, 64);
    float a0 = 2.f * h0v.x + gldf(gb, b0off + d0, det) + gldf(gb, b1off + d0, det);
    float a1 = 2.f * h0v.y + gldf(gb, b0off + d1, det) + gldf(gb, b1off + d1, det);
    gat_gather(rpA, csA, slA, srA[w], zA_, w, lane, a0, a1);
    gat_gather(rpB, csB, slB, srB,    zB_, w, lane, a0, a1);
    *(float2*)(acc + (size_t)w * 128 + d0) = make_float2(a0, a1);
}

// attention-phase weight pack (w_1 + glu1_w), re-done each iter (wt2 overlays HiA)
__global__ __launch_bounds__(256) void k_prepw3(
    const void* __restrict__ w1, const void* __restrict__ g1w,
    const int* __restrict__ fl, u16* __restrict__ whi, u16* __restrict__ wlo)
{
    int s = blockIdx.x * 256 + threadIdx.x;
    if (s >= 6144) return;
    const int det = *fl;
    const void* src; int K, local;
    if (s < 4096) { src = w1;  K = 256; local = s; }
    else          { src = g1w; K = 128; local = s - 4096; }
    const int KK = K >> 5;
    int r = local & 15, g = (local >> 4) & 3, q2 = local >> 6;
    int kk = q2 % KK, ni = q2 / KK;
    bf16x8 hv, lv;
    #pragma unroll
    for (int j = 0; j < 8; ++j) {
        float x = gldf(src, (size_t)(kk * 32 + 8 * g + j) * 128 + ni * 16 + r, det);
        u16 hb = f2bf(x);
        hv[j] = (short)hb;
        lv[j] = (short)f2bf(x - bf2f(hb));
    }
    *(bf16x8*)(whi + (size_t)s * 8) = hv;
    *(bf16x8*)(wlo + (size_t)s * 8) = lv;
}

// hi0 = [item[iid] | cate[icate]] @ W_pos   (K=256)
__global__ __launch_bounds__(256, 2) void m_hi0(
    const void* __restrict__ item, const void* __restrict__ cate,
    const int* __restrict__ iid, const int* __restrict__ icate,
    const u16* __restrict__ whi, const u16* __restrict__ wlo,
    const int* __restrict__ fl, const int* __restrict__ mfok,
    float* __restrict__ out, int nrows)
{
    if (*mfok == 0) return;
    __shared__ __align__(16) short Ah[2048 * 8];   // 32 KB
    __shared__ __align__(16) short Alo[2048 * 8];  // 32 KB
    const int det = *fl;
    const int tid = threadIdx.x, l = tid & 63, w = tid >> 6;
    const int base = blockIdx.x * 64;
    {
        int row = tid >> 2, q = tid & 3;
        int n = base + row, mi = row >> 4, r = row & 15;
        const int it = (n < nrows) ? iid[n] : 0;
        const int ct = (n < nrows) ? icate[n] : 0;
        #pragma unroll
        for (int i = 0; i < 8; ++i) {
            int c = q + 4 * i, kk = c >> 2, g = c & 3;
            int slot = ((mi * 8 + kk) * 4 + g) * 16 + r;
            bf16x8 hv = {0,0,0,0,0,0,0,0}, lv = {0,0,0,0,0,0,0,0};
            if (n < nrows) {
                #pragma unroll
                for (int j = 0; j < 8; ++j) {
                    float x = (c < 16) ? gldf(item, (size_t)it * 128 + c * 8 + j, det)
                                       : gldf(cate, (size_t)ct * 128 + (c - 16) * 8 + j, det);
                    u16 hb2 = f2bf(x);
                    hv[j] = (short)hb2;
                    lv[j] = (short)f2bf(x - bf2f(hb2));
                }
            }
            *(bf16x8*)&Ah[slot * 8]  = hv;
            *(bf16x8*)&Alo[slot * 8] = lv;
        }
    }
    bf16x8 breg[2][8];
    #pragma unroll
    for (int t = 0; t < 2; ++t)
        #pragma unroll
        for (int kk = 0; kk < 8; ++kk)
            breg[t][kk] = *(const bf16x8*)(whi + ((size_t)((w * 2 + t) * 8 + kk) * 64 + l) * 8);
    __syncthreads();
    f32x4 acc[4][2];
    #pragma unroll
    for (int mi = 0; mi < 4; ++mi) { acc[mi][0] = (f32x4){0.f,0.f,0.f,0.f}; acc[mi][1] = (f32x4){0.f,0.f,0.f,0.f}; }
    auto pass = [&](const short* AS) {
        #pragma unroll
        for (int kk = 0; kk < 8; ++kk) {
            bf16x8 a[4];
            #pragma unroll
            for (int mi = 0; mi < 4; ++mi) a[mi] = *(const bf16x8*)&AS[((mi * 8 + kk) * 64 + l) * 8];
            #pragma unroll
            for (int mi = 0; mi < 4; ++mi) {
                acc[mi][0] = __builtin_amdgcn_mfma_f32_16x16x32_bf16(a[mi], breg[0][kk], acc[mi][0], 0, 0, 0);
                acc[mi][1] = __builtin_amdgcn_mfma_f32_16x16x32_bf16(a[mi], breg[1][kk], acc[mi][1], 0, 0, 0);
            }
        }
    };
    pass(Ah);
    pass(Alo);
    #pragma unroll
    for (int t = 0; t < 2; ++t)
        #pragma unroll
        for (int kk = 0; kk < 8; ++kk)
            breg[t][kk] = *(const bf16x8*)(wlo + ((size_t)((w * 2 + t) * 8 + kk) * 64 + l) * 8);
    pass(Ah);
    const int g = l >> 4, r = l & 15, wn0 = w * 32;
    #pragma unroll
    for (int mi = 0; mi < 4; ++mi)
        #pragma unroll
        for (int j = 0; j < 4; ++j) {
            int row = base + mi * 16 + 4 * g + j;
            if (row < nrows) {
                out[(size_t)row * 128 + wn0 + r]      = acc[mi][0][j];
                out[(size_t)row * 128 + wn0 + 16 + r] = acc[mi][1][j];
            }
        }
}

// z = h @ W (K=128, fp32 h) -> fp16 z + fused sl = z@al, sr = z@ar
__global__ __launch_bounds__(256, 2) void m_zgemm(
    const float* __restrict__ h, int nrows,
    const u16* __restrict__ whi, const u16* __restrict__ wlo,
    const void* __restrict__ al, int aloff, const void* __restrict__ ar, int aroff,
    const int* __restrict__ fl, const int* __restrict__ mfok,
    __half* __restrict__ z, float* __restrict__ sl, float* __restrict__ sr)
{
    if (*mfok == 0) return;
    __shared__ __align__(16) short Ah[1024 * 8];   // 16 KB
    __shared__ __align__(16) short Alo[1024 * 8];  // 16 KB
    __shared__ float part[2][4][64];               // 2 KB
    const int det = *fl;
    const int tid = threadIdx.x, l = tid & 63, w = tid >> 6;
    const int base = blockIdx.x * 64;
    {
        int row = tid >> 2, q = tid & 3;
        int n = base + row, mi = row >> 4, r = row & 15;
        #pragma unroll
        for (int i = 0; i < 4; ++i) {
            int c = q + 4 * i, kk = c >> 2, g = c & 3;
            int slot = ((mi * 4 + kk) * 4 + g) * 16 + r;
            bf16x8 hv = {0,0,0,0,0,0,0,0}, lv = {0,0,0,0,0,0,0,0};
            if (n < nrows) {
                const float* sp = h + (size_t)n * 128 + c * 8;
                #pragma unroll
                for (int j = 0; j < 8; ++j) {
                    float x = sp[j];
                    u16 hb = f2bf(x);
                    hv[j] = (short)hb;
                    lv[j] = (short)f2bf(x - bf2f(hb));
                }
            }
            *(bf16x8*)&Ah[slot * 8]  = hv;
            *(bf16x8*)&Alo[slot * 8] = lv;
        }
    }
    bf16x8 breg[2][4];
    #pragma unroll
    for (int t = 0; t < 2; ++t)
        #pragma unroll
        for (int kk = 0; kk < 4; ++kk)
            breg[t][kk] = *(const bf16x8*)(whi + ((size_t)((w * 2 + t) * 4 + kk) * 64 + l) * 8);
    __syncthreads();
    f32x4 acc[4][2];
    #pragma unroll
    for (int mi = 0; mi < 4; ++mi) { acc[mi][0] = (f32x4){0.f,0.f,0.f,0.f}; acc[mi][1] = (f32x4){0.f,0.f,0.f,0.f}; }
    auto pass = [&](const short* AS) {
        #pragma unroll
        for (int kk = 0; kk < 4; ++kk) {
            bf16x8 a[4];
            #pragma unroll
            for (int mi = 0; mi < 4; ++mi) a[mi] = *(const bf16x8*)&AS[((mi * 4 + kk) * 64 + l) * 8];
            #pragma unroll
            for (int mi = 0; mi < 4; ++mi) {
                acc[mi][0] = __builtin_amdgcn_mfma_f32_16x16x32_bf16(a[mi], breg[0][kk], acc[mi][0], 0, 0, 0);
                acc[mi][1] = __builtin_amdgcn_mfma_f32_16x16x32_bf16(a[mi], breg[1][kk], acc[mi][1], 0, 0, 0);
            }
        }
    };
    pass(Ah);
    pass(Alo);
    #pragma unroll
    for (int t = 0; t < 2; ++t)
        #pragma unroll
        for (int kk = 0; kk < 4; ++kk)
            breg[t][kk] = *(const bf16x8*)(wlo + ((size_t)((w * 2 + t) * 4 + kk) * 64 + l) * 8);
    pass(Ah);
    const int g = l >> 4, r = l & 15, wn0 = w * 32;
    const float alv0 = gldf(al, (size_t)aloff + wn0 + r, det);
    const float alv1 = gldf(al, (size_t)aloff + wn0 + 16 + r, det);
    const float arv0 = gldf(ar, (size_t)aroff + wn0 + r, det);
    const float arv1 = gldf(ar, (size_t)aroff + wn0 + 16 + r, det);
    #pragma unroll
    for (int mi = 0; mi < 4; ++mi)
        #pragma unroll
        for (int j = 0; j < 4; ++j) {
            int row = base + mi * 16 + 4 * g + j;
            float d0 = acc[mi][0][j], d1 = acc[mi][1][j];
            if (row < nrows) {
                z[(size_t)row * 128 + wn0 + r]      = __float2half_rn(d0);
                z[(size_t)row * 128 + wn0 + 16 + r] = __float2half_rn(d1);
            }
            float pl = d0 * alv0 + d1 * alv1;
            float pr = d0 * arv0 + d1 * arv1;
            #pragma unroll
            for (int m2 = 1; m2 < 16; m2 <<= 1) {
                pl += __shfl_xor(pl, m2, 64);
                pr += __shfl_xor(pr, m2, 64);
            }
            if (r == 0) {
                part[0][w][mi * 16 + 4 * g + j] = pl;
                part[1][w][mi * 16 + 4 * g + j] = pr;
            }
        }
    __syncthreads();
    if (tid < 128) {
        int which = tid >> 6, t = tid & 63;
        int n2 = base + t;
        if (n2 < nrows) {
            float s = part[which][0][t] + part[which][1][t] + part[which][2][t] + part[which][3][t];
            (which ? sr : sl)[n2] = s;
        }
    }
}

// dual-weight z-gemm
__global__ __launch_bounds__(256, 2) void m_zgemm2(
    const float* __restrict__ h, int nrows,
    const u16* __restrict__ whi1, const u16* __restrict__ wlo1,
    int alo1, int aro1, __half* __restrict__ z1,
    float* __restrict__ sl1, float* __restrict__ sr1,
    const u16* __restrict__ whi2, const u16* __restrict__ wlo2,
    int alo2, int aro2, __half* __restrict__ z2,
    float* __restrict__ sl2, float* __restrict__ sr2,
    const void* __restrict__ al, const void* __restrict__ ar,
    const int* __restrict__ fl, const int* __restrict__ mfok)
{
    if (*mfok == 0) return;
    __shared__ __align__(16) short Ah[1024 * 8];   // 16 KB
    __shared__ __align__(16) short Alo[1024 * 8];  // 16 KB
    __shared__ float part[2][4][64];               // 2 KB
    const int det = *fl;
    const int tid = threadIdx.x, l = tid & 63, w = tid >> 6;
    const int base = blockIdx.x * 64;
    {
        int row = tid >> 2, q = tid & 3;
        int n = base + row, mi = row >> 4, r = row & 15;
        #pragma unroll
        for (int i = 0; i < 4; ++i) {
            int c = q + 4 * i, kk = c >> 2, g = c & 3;
            int slot = ((mi * 4 + kk) * 4 + g) * 16 + r;
            bf16x8 hv = {0,0,0,0,0,0,0,0}, lv = {0,0,0,0,0,0,0,0};
            if (n < nrows) {
                const float* sp = h + (size_t)n * 128 + c * 8;
                #pragma unroll
                for (int j = 0; j < 8; ++j) {
                    float x = sp[j];
                    u16 hb = f2bf(x);
                    hv[j] = (short)hb;
                    lv[j] = (short)f2bf(x - bf2f(hb));
                }
            }
            *(bf16x8*)&Ah[slot * 8]  = hv;
            *(bf16x8*)&Alo[slot * 8] = lv;
        }
    }
    __syncthreads();
    const int g = l >> 4, r = l & 15, wn0 = w * 32;
    auto doSet = [&](const u16* whi, const u16* wlo, int aloff, int aroff,
                     __half* z, float* sl, float* sr) {
        bf16x8 breg[2][4];
        #pragma unroll
        for (int t = 0; t < 2; ++t)
            #pragma unroll
            for (int kk = 0; kk < 4; ++kk)
                breg[t][kk] = *(const bf16x8*)(whi + ((size_t)((w * 2 + t) * 4 + kk) * 64 + l) * 8);
        f32x4 acc[4][2];
        #pragma unroll
        for (int mi = 0; mi < 4; ++mi) { acc[mi][0] = (f32x4){0.f,0.f,0.f,0.f}; acc[mi][1] = (f32x4){0.f,0.f,0.f,0.f}; }
        auto pass = [&](const short* AS) {
            #pragma unroll
            for (int kk = 0; kk < 4; ++kk) {
                bf16x8 a[4];
                #pragma unroll
                for (int mi = 0; mi < 4; ++mi) a[mi] = *(const bf16x8*)&AS[((mi * 4 + kk) * 64 + l) * 8];
                #pragma unroll
                for (int mi = 0; mi < 4; ++mi) {
                    acc[mi][0] = __builtin_amdgcn_mfma_f32_16x16x32_bf16(a[mi], breg[0][kk], acc[mi][0], 0, 0, 0);
                    acc[mi][1] = __builtin_amdgcn_mfma_f32_16x16x32_bf16(a[mi], breg[1][kk], acc[mi][1], 0, 0, 0);
                }
            }
        };
        pass(Ah);
        pass(Alo);
        #pragma unroll
        for (int t = 0; t < 2; ++t)
            #pragma unroll
            for (int kk = 0; kk < 4; ++kk)
                breg[t][kk] = *(const bf16x8*)(wlo + ((size_t)((w * 2 + t) * 4 + kk) * 64 + l) * 8);
        pass(Ah);
        const float alv0 = gldf(al, (size_t)aloff + wn0 + r, det);
        const float alv1 = gldf(al, (size_t)aloff + wn0 + 16 + r, det);
        const float arv0 = gldf(ar, (size_t)aroff + wn0 + r, det);
        const float arv1 = gldf(ar, (size_t)aroff + wn0 + 16 + r, det);
        #pragma unroll
        for (int mi = 0; mi < 4; ++mi)
            #pragma unroll
            for (int j = 0; j < 4; ++j) {
                int row = base + mi * 16 + 4 * g + j;
                float d0 = acc[mi][0][j], d1 = acc[mi][1][j];
                if (row < nrows) {
                    z[(size_t)row * 128 + wn0 + r]      = __float2half_rn(d0);
                    z[(size_t)row * 128 + wn0 + 16 + r] = __float2half_rn(d1);
                }
                float pl = d0 * alv0 + d1 * alv1;
                float pr = d0 * arv0 + d1 * arv1;
                #pragma unroll
                for (int m2 = 1; m2 < 16; m2 <<= 1) {
                    pl += __shfl_xor(pl, m2, 64);
                    pr += __shfl_xor(pr, m2, 64);
                }
                if (r == 0) {
                    part[0][w][mi * 16 + 4 * g + j] = pl;
                    part[1][w][mi * 16 + 4 * g + j] = pr;
                }
            }
        __syncthreads();
        if (tid < 128) {
            int which = tid >> 6, t = tid & 63;
            int n2 = base + t;
            if (n2 < nrows) {
                float s = part[which][0][t] + part[which][1][t] + part[which][2][t] + part[which][3][t];
                (which ? sr : sl)[n2] = s;
            }
        }
        __syncthreads();
    };
    doSet(whi1, wlo1, alo1, aro1, z1, sl1, sr1);
    doSet(whi2, wlo2, alo2, aro2, z2, sl2, sr2);
}

// feat = g*h0 + (1-g)*h1, g = sigm([h0|h1] @ W + b)   (K=256)
__global__ __launch_bounds__(256, 2) void m_gatefeat(
    const float* __restrict__ h0, const float* __restrict__ h1,
    const u16* __restrict__ whi, const u16* __restrict__ wlo,
    const void* __restrict__ bias,
    const int* __restrict__ fl, const int* __restrict__ mfok,
    float* __restrict__ feat, int nrows)
{
    if (*mfok == 0) return;
    __shared__ __align__(16) short Ah[2048 * 8];   // 32 KB
    __shared__ __align__(16) short Alo[2048 * 8];  // 32 KB
    const int det = *fl;
    const int tid = threadIdx.x, l = tid & 63, w = tid >> 6;
    const int base = blockIdx.x * 64;
    {
        int row = tid >> 2, q = tid & 3;
        int n = base + row, mi = row >> 4, r = row & 15;
        #pragma unroll
        for (int i = 0; i < 8; ++i) {
            int c = q + 4 * i, kk = c >> 2, g = c & 3;
            int slot = ((mi * 8 + kk) * 4 + g) * 16 + r;
            bf16x8 hv = {0,0,0,0,0,0,0,0}, lv = {0,0,0,0,0,0,0,0};
            if (n < nrows) {
                const float* sp = ((c < 16) ? h0 : h1) + (size_t)n * 128 + (c & 15) * 8;
                #pragma unroll
                for (int j = 0; j < 8; ++j) {
                    float x = sp[j];
                    u16 hb = f2bf(x);
                    hv[j] = (short)hb;
                    lv[j] = (short)f2bf(x - bf2f(hb));
                }
            }
            *(bf16x8*)&Ah[slot * 8]  = hv;
            *(bf16x8*)&Alo[slot * 8] = lv;
        }
    }
    bf16x8 breg[2][8];
    #pragma unroll
    for (int t = 0; t < 2; ++t)
        #pragma unroll
        for (int kk = 0; kk < 8; ++kk)
            breg[t][kk] = *(const bf16x8*)(whi + ((size_t)((w * 2 + t) * 8 + kk) * 64 + l) * 8);
    __syncthreads();
    f32x4 acc[4][2];
    #pragma unroll
    for (int mi = 0; mi < 4; ++mi) { acc[mi][0] = (f32x4){0.f,0.f,0.f,0.f}; acc[mi][1] = (f32x4){0.f,0.f,0.f,0.f}; }
    auto pass = [&](const short* AS) {
        #pragma unroll
        for (int kk = 0; kk < 8; ++kk) {
            bf16x8 a[4];
            #pragma unroll
            for (int mi = 0; mi < 4; ++mi) a[mi] = *(const bf16x8*)&AS[((mi * 8 + kk) * 64 + l) * 8];
            #pragma unroll
            for (int mi = 0; mi < 4; ++mi) {
                acc[mi][0] = __builtin_amdgcn_mfma_f32_16x16x32_bf16(a[mi], breg[0][kk], acc[mi][0], 0, 0, 0);
                acc[mi][1] = __builtin_amdgcn_mfma_f32_16x16x32_bf16(a[mi], breg[1][kk], acc[mi][1], 0, 0, 0);
            }
        }
    };
    pass(Ah);
    pass(Alo);
    #pragma unroll
    for (int t = 0; t < 2; ++t)
        #pragma unroll
        for (int kk = 0; kk < 8; ++kk)
            breg[t][kk] = *(const bf16x8*)(wlo + ((size_t)((w * 2 + t) * 8 + kk) * 64 + l) * 8);
    pass(Ah);
    const int g = l >> 4, r = l & 15, wn0 = w * 32;
    const float bv0 = gldf(bias, wn0 + r, det);
    const float bv1 = gldf(bias, wn0 + 16 + r, det);
    #pragma unroll
    for (int mi = 0; mi < 4; ++mi)
        #pragma unroll
        for (int j = 0; j < 4; ++j) {
            int row = base + mi * 16 + 4 * g + j;
            if (row < nrows) {
                size_t o0 = (size_t)row * 128 + wn0 + r;
                size_t o1 = o0 + 16;
                float ga  = sigm(acc[mi][0][j] + bv0);
                float gb2 = sigm(acc[mi][1][j] + bv1);
                feat[o0] = ga  * h0[o0] + (1.f - ga)  * h1[o0];
                feat[o1] = gb2 * h0[o1] + (1.f - gb2) * h1[o1];
            }
        }
}

// nh = tanh([pos(t) | hall0] @ w_1)   (K=256)
__global__ __launch_bounds__(256, 2) void m_nh(
    const void* __restrict__ pos, const float* __restrict__ hall0,
    const u16* __restrict__ whi, const u16* __restrict__ wlo,
    const int* __restrict__ fl, const int* __restrict__ mfok,
    float* __restrict__ nh, int nrows)
{
    if (*mfok == 0) return;
    __shared__ __align__(16) short Ah[2048 * 8];
    __shared__ __align__(16) short Alo[2048 * 8];
    const int det = *fl;
    const int tid = threadIdx.x, l = tid & 63, w = tid >> 6;
    const int base = blockIdx.x * 64;
    {
        int row = tid >> 2, q = tid & 3;
        int n = base + row, mi = row >> 4, r = row & 15;
        const int t = (n < nrows) ? (n - (n / T_) * T_) : 0;
        #pragma unroll
        for (int i = 0; i < 8; ++i) {
            int c = q + 4 * i, kk = c >> 2, g = c & 3;
            int slot = ((mi * 8 + kk) * 4 + g) * 16 + r;
            bf16x8 hv = {0,0,0,0,0,0,0,0}, lv = {0,0,0,0,0,0,0,0};
            if (n < nrows) {
                #pragma unroll
                for (int j = 0; j < 8; ++j) {
                    float x = (c < 16) ? gldf(pos, (size_t)t * 128 + c * 8 + j, det)
                                       : hall0[(size_t)n * 128 + (c - 16) * 8 + j];
                    u16 hb = f2bf(x);
                    hv[j] = (short)hb;
                    lv[j] = (short)f2bf(x - bf2f(hb));
                }
            }
            *(bf16x8*)&Ah[slot * 8]  = hv;
            *(bf16x8*)&Alo[slot * 8] = lv;
        }
    }
    bf16x8 breg[2][8];
    #pragma unroll
    for (int t = 0; t < 2; ++t)
        #pragma unroll
        for (int kk = 0; kk < 8; ++kk)
            breg[t][kk] = *(const bf16x8*)(whi + ((size_t)((w * 2 + t) * 8 + kk) * 64 + l) * 8);
    __syncthreads();
    f32x4 acc[4][2];
    #pragma unroll
    for (int mi = 0; mi < 4; ++mi) { acc[mi][0] = (f32x4){0.f,0.f,0.f,0.f}; acc[mi][1] = (f32x4){0.f,0.f,0.f,0.f}; }
    auto pass = [&](const short* AS) {
        #pragma unroll
        for (int kk = 0; kk < 8; ++kk) {
            bf16x8 a[4];
            #pragma unroll
            for (int mi = 0; mi < 4; ++mi) a[mi] = *(const bf16x8*)&AS[((mi * 8 + kk) * 64 + l) * 8];
            #pragma unroll
            for (int mi = 0; mi < 4; ++mi) {
                acc[mi][0] = __builtin_amdgcn_mfma_f32_16x16x32_bf16(a[mi], breg[0][kk], acc[mi][0], 0, 0, 0);
                acc[mi][1] = __builtin_amdgcn_mfma_f32_16x16x32_bf16(a[mi], breg[1][kk], acc[mi][1], 0, 0, 0);
            }
        }
    };
    pass(Ah);
    pass(Alo);
    #pragma unroll
    for (int t = 0; t < 2; ++t)
        #pragma unroll
        for (int kk = 0; kk < 8; ++kk)
            breg[t][kk] = *(const bf16x8*)(wlo + ((size_t)((w * 2 + t) * 8 + kk) * 64 + l) * 8);
    pass(Ah);
    const int g = l >> 4, r = l & 15, wn0 = w * 32;
    #pragma unroll
    for (int mi = 0; mi < 4; ++mi)
        #pragma unroll
        for (int j = 0; j < 4; ++j) {
            int row = base + mi * 16 + 4 * g + j;
            if (row < nrows) {
                nh[(size_t)row * 128 + wn0 + r]      = tanhf(acc[mi][0][j]);
                nh[(size_t)row * 128 + wn0 + 16 + r] = tanhf(acc[mi][1][j]);
            }
        }
}

// beta = (sigm(nh @ glu1_w + glu1_b + g2[b]) . w2) * mask   (K=128)
__global__ __launch_bounds__(256, 2) void m_glub(
    const float* __restrict__ nh,
    const u16* __restrict__ whi, const u16* __restrict__ wlo,
    const void* __restrict__ gb, const float* __restrict__ g2,
    const void* __restrict__ w2, const int* __restrict__ mask,
    const int* __restrict__ fl, const int* __restrict__ mfok,
    float* __restrict__ beta, int nrows)
{
    if (*mfok == 0) return;
    __shared__ __align__(16) short Ah[1024 * 8];
    __shared__ __align__(16) short Alo[1024 * 8];
    __shared__ float part[4][64];
    const int det = *fl;
    const int tid = threadIdx.x, l = tid & 63, w = tid >> 6;
    const int base = blockIdx.x * 64;
    {
        int row = tid >> 2, q = tid & 3;
        int n = base + row, mi = row >> 4, r = row & 15;
        #pragma unroll
        for (int i = 0; i < 4; ++i) {
            int c = q + 4 * i, kk = c >> 2, g = c & 3;
            int slot = ((mi * 4 + kk) * 4 + g) * 16 + r;
            bf16x8 hv = {0,0,0,0,0,0,0,0}, lv = {0,0,0,0,0,0,0,0};
            if (n < nrows) {
                const float* sp = nh + (size_t)n * 128 + c * 8;
                #pragma unroll
                for (int j = 0; j < 8; ++j) {
                    float x = sp[j];
                    u16 hb = f2bf(x);
                    hv[j] = (short)hb;
                    lv[j] = (short)f2bf(x - bf2f(hb));
                }
            }
            *(bf16x8*)&Ah[slot * 8]  = hv;
            *(bf16x8*)&Alo[slot * 8] = lv;
        }
    }
    bf16x8 breg[2][4];
    #pragma unroll
    for (int t = 0; t < 2; ++t)
        #pragma unroll
        for (int kk = 0; kk < 4; ++kk)
            breg[t][kk] = *(const bf16x8*)(whi + ((size_t)((w * 2 + t) * 4 + kk) * 64 + l) * 8);
    __syncthreads();
    f32x4 acc[4][2];
    #pragma unroll
    for (int mi = 0; mi < 4; ++mi) { acc[mi][0] = (f32x4){0.f,0.f,0.f,0.f}; acc[mi][1] = (f32x4){0.f,0.f,0.f,0.f}; }
    auto pass = [&](const short* AS) {
        #pragma unroll
        for (int kk = 0; kk < 4; ++kk) {
            bf16x8 a[4];
            #pragma unroll
            for (int mi = 0; mi < 4; ++mi) a[mi] = *(const bf16x8*)&AS[((mi * 4 + kk) * 64 + l) * 8];
            #pragma unroll
            for (int mi = 0; mi < 4; ++mi) {
                acc[mi][0] = __builtin_amdgcn_mfma_f32_16x16x32_bf16(a[mi], breg[0][kk], acc[mi][0], 0, 0, 0);
                acc[mi][1] = __builtin_amdgcn_mfma_f32_16x16x32_bf16(a[mi], breg[1][kk], acc[mi][1], 0, 0, 0);
            }
        }
    };
    pass(Ah);
    pass(Alo);
    #pragma unroll
    for (int t = 0; t < 2; ++t)
        #pragma unroll
        for (int kk = 0; kk < 4; ++kk)
            breg[t][kk] = *(const bf16x8*)(wlo + ((size_t)((w * 2 + t) * 4 + kk) * 64 + l) * 8);
    pass(Ah);
    const int g = l >> 4, r = l & 15, wn0 = w * 32;
    const float gbv0 = gldf(gb, wn0 + r, det);
    const float gbv1 = gldf(gb, wn0 + 16 + r, det);
    const float w2v0 = gldf(w2, wn0 + r, det);
    const float w2v1 = gldf(w2, wn0 + 16 + r, det);
    #pragma unroll
    for (int mi = 0; mi < 4; ++mi)
        #pragma unroll
        for (int j = 0; j < 4; ++j) {
            int row = base + mi * 16 + 4 * g + j;
            int b = row / T_;
            float gv0 = (row < nrows) ? g2[(size_t)b * 128 + wn0 + r]      : 0.f;
            float gv1 = (row < nrows) ? g2[(size_t)b * 128 + wn0 + 16 + r] : 0.f;
            float v0 = sigm(acc[mi][0][j] + gbv0 + gv0);
            float v1 = sigm(acc[mi][1][j] + gbv1 + gv1);
            float pl = v0 * w2v0 + v1 * w2v1;
            #pragma unroll
            for (int m2 = 1; m2 < 16; m2 <<= 1) pl += __shfl_xor(pl, m2, 64);
            if (r == 0) part[w][mi * 16 + 4 * g + j] = pl;
        }
    __syncthreads();
    if (tid < 64) {
        int n2 = base + tid;
        if (n2 < nrows) {
            float s = part[0][tid] + part[1][tid] + part[2][tid] + part[3][tid];
            beta[n2] = s * (float)mask[n2];
        }
    }
}

// ================= tiled GEMM kernels (VALU fallback, only launched when !mf) =================
__global__ __launch_bounds__(512) void t_hi0(
    const void* __restrict__ item, const void* __restrict__ cate,
    const int* __restrict__ iid, const int* __restrict__ icate,
    const void* __restrict__ Wp, const int* __restrict__ fl,
    float* __restrict__ out, int nrows)
{
    __shared__ float Ws[8192];
    __shared__ float hrow[16][256];
    const int det = *fl;
    const int tid = threadIdx.x, c = tid & 31, slot = tid >> 5;
    for (int base = blockIdx.x * 16; base < nrows; base += gridDim.x * 16) {
        const int n = base + slot;
        if (n < nrows) {
            const int it = iid[n], ct = icate[n];
            for (int j = c; j < 128; j += 32) {
                hrow[slot][j]       = gldf(item, (size_t)it * 128 + j, det);
                hrow[slot][128 + j] = gldf(cate, (size_t)ct * 128 + j, det);
            }
        }
        float4 acc = make_float4(0.f, 0.f, 0.f, 0.f);
        for (int kb = 0; kb < 256; kb += 64) {
            __syncthreads();
            for (int i = tid; i < 8192; i += 512) Ws[i] = gldf(Wp, (size_t)kb * 128 + i, det);
            __syncthreads();
            if (n < nrows) {
                #pragma unroll 8
                for (int k = 0; k < 64; ++k) {
                    float hv = hrow[slot][kb + k];
                    float4 w = *(const float4*)&Ws[k * 128 + c * 4];
                    acc.x += hv * w.x; acc.y += hv * w.y; acc.z += hv * w.z; acc.w += hv * w.w;
                }
            }
        }
        if (n < nrows) *(float4*)&out[(size_t)n * 128 + c * 4] = acc;
        __syncthreads();
    }
}

__global__ __launch_bounds__(256) void s_hc0(
    const void* __restrict__ cate, const int* __restrict__ cid,
    const int* __restrict__ fl, float* __restrict__ out)
{
    long i = (long)blockIdx.x * 256 + threadIdx.x;
    if (i >= (long)NC_ * 128) return;
    out[i] = gldf(cate, (size_t)cid[i >> 7] * 128 + (i & 127), *fl);
}

__global__ __launch_bounds__(256) void s_initacc(
    const float* __restrict__ h, const void* __restrict__ gb, int b0off, int b1off,
    const int* __restrict__ fl, float* __restrict__ acc, long total)
{
    long i = (long)blockIdx.x * 256 + threadIdx.x;
    if (i >= total) return;
    const int det = *fl, d = (int)(i & 127);
    acc[i] = 2.f * h[i] + gldf(gb, b0off + d, det) + gldf(gb, b1off + d, det);
}

__global__ __launch_bounds__(512) void t_zgemm(
    const float* __restrict__ h, int nrows,
    const void* __restrict__ W, int woff,
    const void* __restrict__ al, int aloff,
    const void* __restrict__ ar, int aroff,
    const int* __restrict__ fl,
    __half* __restrict__ z, float* __restrict__ sl, float* __restrict__ sr)
{
    __shared__ float Ws[8192];
    __shared__ float hrow[16][128];
    const int det = *fl;
    const int tid = threadIdx.x, c = tid & 31, slot = tid >> 5;
    float4 alv, arv;
    alv.x = gldf(al, (size_t)aloff + c * 4 + 0, det); alv.y = gldf(al, (size_t)aloff + c * 4 + 1, det);
    alv.z = gldf(al, (size_t)aloff + c * 4 + 2, det); alv.w = gldf(al, (size_t)aloff + c * 4 + 3, det);
    arv.x = gldf(ar, (size_t)aroff + c * 4 + 0, det); arv.y = gldf(ar, (size_t)aroff + c * 4 + 1, det);
    arv.z = gldf(ar, (size_t)aroff + c * 4 + 2, det); arv.w = gldf(ar, (size_t)aroff + c * 4 + 3, det);
    for (int base = blockIdx.x * 16; base < nrows; base += gridDim.x * 16) {
        const int n = base + slot;
        if (n < nrows) for (int j = c; j < 128; j += 32) hrow[slot][j] = h[(size_t)n * 128 + j];
        float4 acc = make_float4(0.f, 0.f, 0.f, 0.f);
        for (int kb = 0; kb < 128; kb += 64) {
            __syncthreads();
            for (int i = tid; i < 8192; i += 512) Ws[i] = gldf(W, (size_t)woff + (size_t)kb * 128 + i, det);
            __syncthreads();
            if (n < nrows) {
                #pragma unroll 8
                for (int k = 0; k < 64; ++k) {
                    float hv = hrow[slot][kb + k];
                    float4 w = *(const float4*)&Ws[k * 128 + c * 4];
                    acc.x += hv * w.x; acc.y += hv * w.y; acc.z += hv * w.z; acc.w += hv * w.w;
                }
            }
        }
        if (n < nrows) {
            z[(size_t)n * 128 + c * 4 + 0] = __float2half_rn(acc.x);
            z[(size_t)n * 128 + c * 4 + 1] = __float2half_rn(acc.y);
            z[(size_t)n * 128 + c * 4 + 2] = __float2half_rn(acc.z);
            z[(size_t)n * 128 + c * 4 + 3] = __float2half_rn(acc.w);
            float pl = acc.x * alv.x + acc.y * alv.y + acc.z * alv.z + acc.w * alv.w;
            float pr = acc.x * arv.x + acc.y * arv.y + acc.z * arv.z + acc.w * arv.w;
            #pragma unroll
            for (int off = 16; off > 0; off >>= 1) {
                pl += __shfl_down(pl, off, 32);
                pr += __shfl_down(pr, off, 32);
            }
            if (c == 0) { sl[n] = pl; sr[n] = pr; }
        }
        __syncthreads();
    }
}

// -------- fallback atomic path --------
__global__ __launch_bounds__(256) void s_dinit(float* __restrict__ den, int n)
{
    int i = blockIdx.x * 256 + threadIdx.x;
    if (i < n) den[i] = 0.f;
}
__global__ __launch_bounds__(256) void s_edge(
    const float* __restrict__ sl, const float* __restrict__ sr,
    const int* __restrict__ src, const int* __restrict__ dst,
    float* __restrict__ e, float* __restrict__ den, int E)
{
    int j = blockIdx.x * 256 + threadIdx.x;
    if (j >= E) return;
    float ee = expf(lrelu_c(sl[src[j]] + sr[dst[j]]));
    e[j] = ee;
    atomicAdd(&den[dst[j]], ee);
}
__global__ __launch_bounds__(256) void s_scatter(
    const float* __restrict__ e, const float* __restrict__ den,
    const int* __restrict__ src, const int* __restrict__ dst,
    const __half* __restrict__ z, float* __restrict__ acc, int E)
{
    long i = (long)blockIdx.x * 256 + threadIdx.x;
    if (i >= (long)E * 128) return;
    int j = (int)(i >> 7), d = (int)(i & 127);
    int dj = dst[j];
    atomicAdd(&acc[(size_t)dj * 128 + d], (e[j] / den[dj]) * __half2float(z[(size_t)src[j] * 128 + d]));
}

__global__ __launch_bounds__(512) void t_gatefeat(
    const float* __restrict__ h0, const float* __restrict__ h1,
    const void* __restrict__ W, const void* __restrict__ bias,
    const int* __restrict__ fl,
    float* __restrict__ feat, int nrows)
{
    __shared__ float Ws[8192];
    __shared__ float hrow[16][256];
    const int det = *fl;
    const int tid = threadIdx.x, c = tid & 31, slot = tid >> 5;
    float4 bv;
    bv.x = gldf(bias, c * 4 + 0, det); bv.y = gldf(bias, c * 4 + 1, det);
    bv.z = gldf(bias, c * 4 + 2, det); bv.w = gldf(bias, c * 4 + 3, det);
    for (int base = blockIdx.x * 16; base < nrows; base += gridDim.x * 16) {
        const int n = base + slot;
        if (n < nrows) {
            for (int j = c; j < 128; j += 32) {
                hrow[slot][j]       = h0[(size_t)n * 128 + j];
                hrow[slot][128 + j] = h1[(size_t)n * 128 + j];
            }
        }
        float4 acc = make_float4(0.f, 0.f, 0.f, 0.f);
        for (int kb = 0; kb < 256; kb += 64) {
            __syncthreads();
            for (int i = tid; i < 8192; i += 512) Ws[i] = gldf(W, (size_t)kb * 128 + i, det);
            __syncthreads();
            if (n < nrows) {
                #pragma unroll 8
                for (int k = 0; k < 64; ++k) {
                    float hv = hrow[slot][kb + k];
                    float4 w = *(const float4*)&Ws[k * 128 + c * 4];
                    acc.x += hv * w.x; acc.y += hv * w.y; acc.z += hv * w.z; acc.w += hv * w.w;
                }
            }
        }
        if (n < nrows) {
            float4 a = *(const float4*)&hrow[slot][c * 4];
            float4 b = *(const float4*)&hrow[slot][128 + c * 4];
            float gx = sigm(acc.x + bv.x), gy = sigm(acc.y + bv.y);
            float gz = sigm(acc.z + bv.z), gw = sigm(acc.w + bv.w);
            float4 o;
            o.x = gx * a.x + (1.f - gx) * b.x;
            o.y = gy * a.y + (1.f - gy) * b.y;
            o.z = gz * a.z + (1.f - gz) * b.z;
            o.w = gw * a.w + (1.f - gw) * b.w;
            *(float4*)&feat[(size_t)n * 128 + c * 4] = o;
        }
        __syncthreads();
    }
}

__global__ __launch_bounds__(256) void s_hall0(
    const void* __restrict__ item, const int* __restrict__ seq,
    const int* __restrict__ alias, const int* __restrict__ mask,
    const float* __restrict__ feat, const void* __restrict__ xs,
    const int* __restrict__ fl, float* __restrict__ out)
{
    long i = (long)blockIdx.x * 256 + threadIdx.x;
    if (i >= (long)B_ * T_ * 128) return;
    const int det = *fl;
    int bt = (int)(i >> 7), d = (int)(i & 127);
    float x = gldf(xs, 0, det);
    out[i] = gldf(item, (size_t)seq[bt] * 128 + d, det) * x
           + feat[(size_t)alias[bt] * 128 + d] * (float)mask[bt];
}

// fused attn: hs->softmax->hsv->LN1 then linout+glu2 (per batch row)
__global__ __launch_bounds__(128) void t_attn12(
    const float* __restrict__ hall0, const void* __restrict__ q,
    const int* __restrict__ mask,
    const void* __restrict__ g, const void* __restrict__ bb,
    const void* __restrict__ lw, const void* __restrict__ lb,
    const void* __restrict__ gw, const int* __restrict__ fl,
    float* __restrict__ g2)
{
    __shared__ float qs[128];
    __shared__ float hs_s[T_];
    __shared__ float red[128];
    __shared__ float h1s[128];
    __shared__ float h2[128];
    const int b = blockIdx.x, tid = threadIdx.x;
    const int det = *fl;
    qs[tid] = gldf(q, tid, det);
    __syncthreads();
    if (tid < T_) {
        const float* hp = hall0 + ((size_t)b * T_ + tid) * 128;
        float a = 0.f;
        for (int d = 0; d < 128; ++d) a += hp[d] * qs[d];
        hs_s[tid] = a;
    }
    __syncthreads();
    float mx = -1e30f;
    for (int t = 0; t < T_; ++t) mx = fmaxf(mx, hs_s[t]);
    float ssum = 0.f;
    for (int t = 0; t < T_; ++t) ssum += expf(hs_s[t] - mx);
    float inv = 1.f / ssum;
    __syncthreads();
    if (tid < T_)
        hs_s[tid] = expf(hs_s[tid] - mx) * inv * (float)mask[b * T_ + tid];
    __syncthreads();
    float a = 0.f;
    for (int t = 0; t < T_; ++t) a += hs_s[t] * hall0[((size_t)b * T_ + t) * 128 + tid];
    red[tid] = a; __syncthreads();
    for (int o = 64; o > 0; o >>= 1) { if (tid < o) red[tid] += red[tid + o]; __syncthreads(); }
    float mu = red[0] * (1.f / 128.f);
    __syncthreads();
    float dv = a - mu;
    red[tid] = dv * dv; __syncthreads();
    for (int o = 64; o > 0; o >>= 1) { if (tid < o) red[tid] += red[tid + o]; __syncthreads(); }
    float rs = 1.f / sqrtf(red[0] * (1.f / 128.f) + 1e-8f);
    h1s[tid] = dv * rs * gldf(g, tid, det) + gldf(bb, tid, det);
    __syncthreads();
    // linout
    float a2 = gldf(lb, tid, det);
    for (int k = 0; k < 128; ++k)
        a2 += h1s[k] * gldf(lw, (size_t)k * 128 + tid, det);
    for (int k = 0; k < 128; ++k)
        a2 += hall0[(size_t)b * T_ * 128 + k] * gldf(lw, (size_t)(128 + k) * 128 + tid, det);
    h2[tid] = a2;
    __syncthreads();
    float g2v = 0.f;
    for (int k = 0; k < 128; ++k)
        g2v += h2[k] * gldf(gw, (size_t)k * 128 + tid, det);
    g2[(size_t)b * 128 + tid] = g2v;
}

__global__ __launch_bounds__(512) void t_nh(
    const void* __restrict__ pos, const float* __restrict__ hall0,
    const void* __restrict__ W, const int* __restrict__ fl,
    float* __restrict__ nh, int nrows)
{
    __shared__ float Ws[8192];
    __shared__ float hrow[16][256];
    const int det = *fl;
    const int tid = threadIdx.x, c = tid & 31, slot = tid >> 5;
    for (int base = blockIdx.x * 16; base < nrows; base += gridDim.x * 16) {
        const int n = base + slot;
        if (n < nrows) {
            const int t = n - (n / T_) * T_;
            for (int j = c; j < 128; j += 32) {
                hrow[slot][j]       = gldf(pos, (size_t)t * 128 + j, det);
                hrow[slot][128 + j] = hall0[(size_t)n * 128 + j];
            }
        }
        float4 acc = make_float4(0.f, 0.f, 0.f, 0.f);
        for (int kb = 0; kb < 256; kb += 64) {
            __syncthreads();
            for (int i = tid; i < 8192; i += 512) Ws[i] = gldf(W, (size_t)kb * 128 + i, det);
            __syncthreads();
            if (n < nrows) {
                #pragma unroll 8
                for (int k = 0; k < 64; ++k) {
                    float hv = hrow[slot][kb + k];
                    float4 w = *(const float4*)&Ws[k * 128 + c * 4];
                    acc.x += hv * w.x; acc.y += hv * w.y; acc.z += hv * w.z; acc.w += hv * w.w;
                }
            }
        }
        if (n < nrows) {
            float4 o;
            o.x = tanhf(acc.x); o.y = tanhf(acc.y); o.z = tanhf(acc.z); o.w = tanhf(acc.w);
            *(float4*)&nh[(size_t)n * 128 + c * 4] = o;
        }
        __syncthreads();
    }
}

__global__ __launch_bounds__(512) void t_glu_beta(
    const float* __restrict__ nh, const void* __restrict__ W, const void* __restrict__ gb,
    const float* __restrict__ g2, const void* __restrict__ w2, const int* __restrict__ mask,
    const int* __restrict__ fl, float* __restrict__ beta, int nrows)
{
    __shared__ float Ws[8192];
    __shared__ float hrow[16][128];
    const int det = *fl;
    const int tid = threadIdx.x, c = tid & 31, slot = tid >> 5;
    float4 gbv, w2v;
    gbv.x = gldf(gb, c * 4 + 0, det); gbv.y = gldf(gb, c * 4 + 1, det);
    gbv.z = gldf(gb, c * 4 + 2, det); gbv.w = gldf(gb, c * 4 + 3, det);
    w2v.x = gldf(w2, c * 4 + 0, det); w2v.y = gldf(w2, c * 4 + 1, det);
    w2v.z = gldf(w2, c * 4 + 2, det); w2v.w = gldf(w2, c * 4 + 3, det);
    for (int base = blockIdx.x * 16; base < nrows; base += gridDim.x * 16) {
        const int n = base + slot;
        if (n < nrows) for (int j = c; j < 128; j += 32) hrow[slot][j] = nh[(size_t)n * 128 + j];
        float4 acc = make_float4(0.f, 0.f, 0.f, 0.f);
        for (int kb = 0; kb < 128; kb += 64) {
            __syncthreads();
            for (int i = tid; i < 8192; i += 512) Ws[i] = gldf(W, (size_t)kb * 128 + i, det);
            __syncthreads();
            if (n < nrows) {
                #pragma unroll 8
                for (int k = 0; k < 64; ++k) {
                    float hv = hrow[slot][kb + k];
                    float4 w = *(const float4*)&Ws[k * 128 + c * 4];
                    acc.x += hv * w.x; acc.y += hv * w.y; acc.z += hv * w.z; acc.w += hv * w.w;
                }
            }
        }
        if (n < nrows) {
            const int b = n / T_;
            float4 gv = *(const float4*)&g2[(size_t)b * 128 + c * 4];
            float vx = sigm(acc.x + gbv.x + gv.x);
            float vy = sigm(acc.y + gbv.y + gv.y);
            float vz = sigm(acc.z + gbv.z + gv.z);
            float vw = sigm(acc.w + gbv.w + gv.w);
            float part = vx * w2v.x + vy * w2v.y + vz * w2v.z + vw * w2v.w;
            #pragma unroll
            for (int off = 16; off > 0; off >>= 1) part += __shfl_down(part, off, 32);
            if (c == 0) beta[n] = part * (float)mask[n];
        }
        __syncthreads();
    }
}

__global__ __launch_bounds__(128) void t_sel(
    const float* __restrict__ hall0, const float* __restrict__ beta,
    const void* __restrict__ g2, const void* __restrict__ b2,
    const float* __restrict__ feat, const int* __restrict__ lasti,
    const void* __restrict__ ys, const int* __restrict__ fl,
    float* __restrict__ hallf, float* __restrict__ fenmu, float* __restrict__ outh)
{
    __shared__ float bet[T_];
    __shared__ float red[128];
    const int b = blockIdx.x, tid = threadIdx.x;
    const int det = *fl;
    if (tid < T_) bet[tid] = beta[b * T_ + tid];
    __syncthreads();
    float acc = 0.f;
    for (int t = 0; t < T_; ++t) acc += bet[t] * hall0[((size_t)b * T_ + t) * 128 + tid];
    red[tid] = acc; __syncthreads();
    for (int off = 64; off > 0; off >>= 1) { if (tid < off) red[tid] += red[tid + off]; __syncthreads(); }
    float mu = red[0] * (1.f / 128.f);
    __syncthreads();
    float dv = acc - mu;
    red[tid] = dv * dv; __syncthreads();
    for (int off = 64; off > 0; off >>= 1) { if (tid < off) red[tid] += red[tid + off]; __syncthreads(); }
    float rs = 1.f / sqrtf(red[0] * (1.f / 128.f) + 1e-8f);
    __syncthreads();
    float h = dv * rs * gldf(g2, tid, det) + gldf(b2, tid, det)
            + feat[(size_t)lasti[b] * 128 + tid] * gldf(ys, 0, det);
    hallf[(size_t)b * 128 + tid] = h;
    outh[(size_t)b * 128 + tid] = h;
    red[tid] = h * h; __syncthreads();
    for (int off = 64; off > 0; off >>= 1) { if (tid < off) red[tid] += red[tid + off]; __syncthreads(); }
    if (tid == 0) fenmu[b] = sqrtf(red[0] + 128.f * 1e-6f);
}

__global__ __launch_bounds__(256) void t_cos(
    const float* __restrict__ hallf, const float* __restrict__ fenmu, float* __restrict__ out)
{
    __shared__ float hi[128];
    const int i = blockIdx.x, tid = threadIdx.x;
    if (tid < 128) hi[tid] = hallf[(size_t)i * 128 + tid];
    __syncthreads();
    const float fi = fenmu[i];
    for (int j = tid; j < B_; j += 256) {
        const float* hj = &hallf[(size_t)j * 128];
        float s = 0.f;
        for (int d = 0; d < 128; d += 4) {
            float4 a = *(const float4*)&hi[d];
            float4 bb = *(const float4*)&hj[d];
            s += a.x * bb.x + a.y * bb.y + a.z * bb.z + a.w * bb.w;
        }
        out[(size_t)i * B_ + j] = s / (fi * fenmu[j]);
    }
}

extern "C" void kernel_launch(void* const* d_in, const int* in_sizes, int n_in,
                              void* d_out, int out_size, void* d_ws, size_t ws_size,
                              hipStream_t stream)
{
    float* outf = (float*)d_out;
    const long OUT_N = (long)B_ * 128 + (long)B_ * B_;

    static const int EXP_SZ[41] = {
        12800000, 1280000, 25600, 32768, 131072, 1024, 1024, 1024, 32768, 128,
        32768, 128, 128, 32768, 128, 32768, 128, 16384, 128, 16384,
        128, 128, 128, 128, 1, 1, 100000, 100000, 10000, 800000,
        800000, 100000, 100000, 400000, 400000, 400000, 400000, 25600, 25600, 25600, 512 };
    float code = 0.f;
    if (n_in != 41) code = 90000.f + (float)n_in;
    else {
        for (int i = 0; i < 41; ++i)
            if (in_sizes[i] != EXP_SZ[i]) { code = 10000.f * (float)(i + 1); break; }
    }
    if (code == 0.f && out_size != (int)OUT_N) code = 95000.f;
    if (code != 0.f) {
        s_sig<<<dim3((unsigned)((OUT_N + 255) / 256)), dim3(256), 0, stream>>>(outf, OUT_N, code);
        return;
    }

    const void* item_emb = d_in[0];
    const void* cate_emb = d_in[1];
    const void* pos_emb  = d_in[2];
    const void* W_pos    = d_in[3];
    const void* gat_W    = d_in[4];
    const void* gat_al   = d_in[5];
    const void* gat_ar   = d_in[6];
    const void* gat_b    = d_in[7];
    const void* Wg1_w    = d_in[8];
    const void* Wg1_b    = d_in[9];
    const void* q        = d_in[12];
    const void* lin_w    = d_in[13];
    const void* lin_b    = d_in[14];
    const void* w_1      = d_in[15];
    const void* w_2      = d_in[16];
    const void* glu1_w   = d_in[17];
    const void* glu1_b   = d_in[18];
    const void* glu2_w   = d_in[19];
    const void* ln1_g    = d_in[20];
    const void* ln1_b    = d_in[21];
    const void* ln2_g    = d_in[22];
    const void* ln2_b    = d_in[23];
    const void* x_s      = d_in[24];
    const void* y_s      = d_in[25];
    const int* iid    = (const int*)d_in[26];
    const int* icate  = (const int*)d_in[27];
    const int* cid    = (const int*)d_in[28];
    const int* src_ii = (const int*)d_in[29];
    const int* dst_ii = (const int*)d_in[30];
    const int* src_cc = (const int*)d_in[31];
    const int* dst_cc = (const int*)d_in[32];
    const int* src_ci = (const int*)d_in[33];
    const int* dst_ci = (const int*)d_in[34];
    const int* src_ic = (const int*)d_in[35];
    const int* dst_ic = (const int*)d_in[36];
    const int* alias  = (const int*)d_in[37];
    const int* seq    = (const int*)d_in[38];
    const int* mask   = (const int*)d_in[39];
    const int* lasti  = (const int*)d_in[40];

    const size_t NEED_BASE = 64 + ((size_t)4 * NI_ + 3 * NC_) * 128 * 4
                                + ((size_t)3 * NI_ + 2 * NC_ + EII_) * 4;
    const size_t CSR_EXTRA = ((size_t)2 * (NI_ + 1) + 2 * (NC_ + 1)
                                + ECI_ + ECC_ + EIC_ + NI_) * 4;
    const size_t NEED_CSR = NEED_BASE + CSR_EXTRA;
    if (ws_size < NEED_BASE) {
        s_sig<<<dim3((unsigned)((OUT_N + 255) / 256)), dim3(256), 0, stream>>>(outf, OUT_N, 80000.f);
        return;
    }
    const bool useCSR = (ws_size >= NEED_CSR);
    const int mf = useCSR ? 1 : 0;

    int* flagp = (int*)d_ws;
    char* basep = (char*)d_ws;
    size_t off = 64;
    auto AL = [&](size_t nfl) { float* p = (float*)(basep + off); off += nfl * 4; return p; };
    float* hi0 = AL((size_t)NI_ * 128);
    float* HiA = AL((size_t)NI_ * 128);
    float* HiB = AL((size_t)NI_ * 128);   // binned edges during build | score scratch | L1 acc
    float* zA  = AL((size_t)NI_ * 128);   // two fp16 z's | feat fp32 later
    float* hc0 = AL((size_t)NC_ * 128);
    float* HcA = AL((size_t)NC_ * 128);
    float* zC  = AL((size_t)NC_ * 128);   // two fp16 z's
    float* sAl = AL(NI_); float* sAr = AL(NI_);
    float* sCl = AL(NC_); float* sCr = AL(NC_);
    float* denF = AL(NI_);          // fallback den | CSR: bsum[0,4KB) wars gcur wt_lo[17408,..)
    float* eF   = AL(EII_);         // fallback e   | CSR: colsrc_ii
    int* rpII = (int*)AL(NI_ + 1);
    int* rpCI = (int*)AL(NI_ + 1);
    int* rpCC = (int*)AL(NC_ + 1);
    int* rpIC = (int*)AL(NC_ + 1);
    int* csCI = (int*)AL(ECI_);
    int* csCC = (int*)AL(ECC_);
    int* csIC = (int*)AL(EIC_);
    int* wtregion = (int*)AL(NI_);  // wt_hi (320 KB)
    int* csII = (int*)eF;
    int* bsum = (int*)denF;                         // ints [0,1024)
    float* wars = denF + 1024;                      // 3x128 floats
    int* gcur = ((int*)denF) + 1408;                // 432 ints (ends at 1840 < 4352)
    u16* wt_hi = (u16*)wtregion;                    // 20480 slots * 16 B
    u16* wt_lo = (u16*)((char*)denF + 17408);
    __half* zAh  = (__half*)zA;
    __half* zA2h = zAh + (size_t)NI_ * 128;
    __half* zCh  = (__half*)zC;
    __half* zC2h = zCh + (size_t)NC_ * 128;
    // binned edge arrays (build-time) live in HiB
    u32* binII = (u32*)HiB;
    u32* binCI = binII + EII_;
    u32* binCC = binCI + ECI_;
    u32* binIC = binCC + ECC_;
    // layer-0 score scratch (after build) also in HiB
    float* sl03p = HiB;
    float* sr03s = HiB + NI_;
    float* sl02p = HiB + 2 * (size_t)NI_;
    float* sr02s = sl02p + NC_;
    // attention-phase packed weights (w_1 + glu1_w = 6144 slots) live in dead HiA
    u16* wt2_hi = (u16*)HiA;
    u16* wt2_lo = wt2_hi + (size_t)6144 * 8;

    auto WTS = [&](int l, int k) {                  // slot base (u16 units) for gat_W (l,k)
        int midx = (l == 0) ? k : ((k == 0) ? 4 : 5);
        return (size_t)(8192 + midx * 2048) * 8;
    };

    float* feat = zA;
    float* hall0 = hi0;
    float* nh    = hall0 + (size_t)B_ * T_ * 128;
    float* vbuf  = nh    + (size_t)B_ * T_ * 128;
    float* hsb   = vbuf  + (size_t)B_ * T_ * 128;
    float* hsv   = hsb   + (size_t)B_ * T_;
    float* hsvn  = hsv   + (size_t)B_ * 128;
    float* hsv2  = hsvn  + (size_t)B_ * 128;
    float* g2b   = hsv2  + (size_t)B_ * 128;
    float* betab = g2b   + (size_t)B_ * 128;
    float* hallf = betab + (size_t)B_ * T_;
    float* fenmu = hallf + (size_t)B_ * 128;

    #define GRL(n) dim3((unsigned)(((long)(n) + 255) / 256))
    auto WOFF = [](int l, int k) { return (l * 4 + k) * 16384; };
    auto VOFF = [](int l, int k) { return (l * 4 + k) * 128; };

    auto seg = [&](const float* sl, const float* sr, const int* s, const int* d,
                   int E, int ndst, const __half* z, float* acc) {
        s_dinit<<<GRL(ndst), dim3(256), 0, stream>>>(denF, ndst);
        s_edge<<<GRL(E), dim3(256), 0, stream>>>(sl, sr, s, d, eF, denF, E);
        s_scatter<<<GRL((long)E * 128), dim3(256), 0, stream>>>(eF, denF, s, d, z, acc, E);
    };

    k_init<<<dim3(1), dim3(128), 0, stream>>>(item_emb, flagp);

    if (useCSR) {
        int* cu0 = (int*)sAr; int* cu1 = (int*)sAl; int* cu2 = (int*)sCl; int* cu3 = (int*)sCr;
        const int ET = EII_ + ECI_ + ECC_ + EIC_;
        const int NB4 = ((NI_ + 1023) >> 10) * 2 + ((NC_ + 1023) >> 10) * 2;
        k_pre<<<dim3(5943), dim3(256), 0, stream>>>(
            cate_emb, cid, hc0, cu0, cu1, cu2, cu3,
            W_pos, Wg1_w, gat_W, wt_hi, wt_lo, gat_ar, wars, flagp);
        k_hist4<<<GRL(ET), dim3(256), 0, stream>>>(dst_ii, EII_, dst_ci, ECI_, dst_cc, ECC_, dst_ic, EIC_,
                                                   cu0, cu1, cu2, cu3);
        k_bsum4<<<dim3(NB4), dim3(256), 0, stream>>>(cu0, NI_, cu1, NI_, cu2, NC_, cu3, NC_, bsum);
        k_scanb4<<<dim3(4), dim3(1), 0, stream>>>(bsum, NI_, NI_, NC_, NC_, rpII, rpCI, rpCC, rpIC);
        k_scanfinal4<<<dim3(NB4), dim3(256), 0, stream>>>(cu0, NI_, cu1, NI_, cu2, NC_, cu3, NC_,
                                                          bsum, rpII, rpCI, rpCC, rpIC);
        k_gcur<<<dim3(1), dim3(512), 0, stream>>>(rpII, rpCI, rpCC, rpIC, gcur);
        k_binA<<<dim3((ET + ECH_ - 1) / ECH_), dim3(256), 0, stream>>>(
            src_ii, dst_ii, src_ci, dst_ci, src_cc, dst_cc, src_ic, dst_ic,
            gcur, binII, binCI, binCC, binIC);
        k_binB<<<dim3(NBK_), dim3(256), 0, stream>>>(
            rpII, rpCI, rpCC, rpIC, binII, binCI, binCC, binIC,
            csII, csCI, csCC, csIC);
        m_hi0<<<dim3((NI_ + 63) / 64), dim3(256), 0, stream>>>(
            item_emb, cate_emb, iid, icate, wt_hi, wt_lo, flagp, flagp + 1, hi0, NI_);
        // ---- layer 0 z-gemms (dual-weight)
        m_zgemm2<<<dim3((NI_ + 63) / 64), dim3(256), 0, stream>>>(
            hi0, NI_,
            wt_hi + WTS(0, 0), wt_lo + WTS(0, 0), VOFF(0, 0), VOFF(0, 0), zAh,  sAl,   sAr,
            wt_hi + WTS(0, 3), wt_lo + WTS(0, 3), VOFF(0, 3), VOFF(0, 3), zA2h, sl03p, sr03s,
            gat_al, gat_ar, flagp, flagp + 1);
        m_zgemm2<<<dim3((NC_ + 63) / 64), dim3(256), 0, stream>>>(
            hc0, NC_,
            wt_hi + WTS(0, 1), wt_lo + WTS(0, 1), VOFF(0, 1), VOFF(0, 1), zC2h, sCl,   sCr,
            wt_hi + WTS(0, 2), wt_lo + WTS(0, 2), VOFF(0, 2), VOFF(0, 2), zCh,  sl02p, sr02s,
            gat_al, gat_ar, flagp, flagp + 1);
        // ---- layer 0 aggs
        t_gat_fused<<<dim3((NI_ + 3) / 4), dim3(256), 0, stream>>>(
            rpII, csII, sAl, sAr, (const __half2*)zAh,
            rpCI, csCI, sl02p, wars + 0, (const __half2*)zCh,
            hi0, gat_b, VOFF(0, 0), VOFF(0, 2), flagp, HiA, NI_);
        t_gat_fused<<<dim3((NC_ + 3) / 4), dim3(256), 0, stream>>>(
            rpCC, csCC, sCl, sCr, (const __half2*)zC2h,
            rpIC, csIC, sl03p, wars + 128, (const __half2*)zA2h,
            hc0, gat_b, VOFF(0, 1), VOFF(0, 3), flagp, HcA, NC_);
        // ---- layer 1
        m_zgemm<<<dim3((NI_ + 63) / 64), dim3(256), 0, stream>>>(
            HiA, NI_, wt_hi + WTS(1, 0), wt_lo + WTS(1, 0),
            gat_al, VOFF(1, 0), gat_ar, VOFF(1, 0), flagp, flagp + 1, zAh, sAl, sAr);
        m_zgemm<<<dim3((NC_ + 63) / 64), dim3(256), 0, stream>>>(
            HcA, NC_, wt_hi + WTS(1, 2), wt_lo + WTS(1, 2),
            gat_al, VOFF(1, 2), gat_ar, VOFF(1, 2), flagp, flagp + 1, zCh, sCl, sCr);
        t_gat_fused<<<dim3((NI_ + 3) / 4), dim3(256), 0, stream>>>(
            rpII, csII, sAl, sAr, (const __half2*)zAh,
            rpCI, csCI, sCl, wars + 256, (const __half2*)zCh,
            HiA, gat_b, VOFF(1, 0), VOFF(1, 2), flagp, HiB, NI_);
        // HiA now dead: pack attention-phase weights into it
        k_prepw3<<<dim3(24), dim3(256), 0, stream>>>(w_1, glu1_w, flagp, wt2_hi, wt2_lo);
        m_gatefeat<<<dim3((NI_ + 63) / 64), dim3(256), 0, stream>>>(
            hi0, HiB, wt_hi + (size_t)4096 * 8, wt_lo + (size_t)4096 * 8, Wg1_b, flagp, flagp + 1, feat, NI_);
    } else {
        s_hc0<<<GRL((long)NC_ * 128), dim3(256), 0, stream>>>(cate_emb, cid, flagp, hc0);
        t_hi0<<<dim3(768), dim3(512), 0, stream>>>(item_emb, cate_emb, iid, icate, W_pos, flagp, hi0, NI_);
        s_initacc<<<GRL((long)NI_ * 128), dim3(256), 0, stream>>>(hi0, gat_b, VOFF(0, 0), VOFF(0, 2), flagp, HiA, (long)NI_ * 128);
        s_initacc<<<GRL((long)NC_ * 128), dim3(256), 0, stream>>>(hc0, gat_b, VOFF(0, 1), VOFF(0, 3), flagp, HcA, (long)NC_ * 128);
        t_zgemm<<<dim3(1024), dim3(512), 0, stream>>>(hi0, NI_, gat_W, WOFF(0, 0), gat_al, VOFF(0, 0), gat_ar, VOFF(0, 0), flagp, zAh, sAl, sAr);
        seg(sAl, sAr, src_ii, dst_ii, EII_, NI_, zAh, HiA);
        t_zgemm<<<dim3(625), dim3(512), 0, stream>>>(hc0, NC_, gat_W, WOFF(0, 2), gat_al, VOFF(0, 2), gat_ar, VOFF(0, 2), flagp, zCh, sCl, sCr);
        t_zgemm<<<dim3(1024), dim3(512), 0, stream>>>(hi0, NI_, gat_W, WOFF(0, 2), gat_al, VOFF(0, 2), gat_ar, VOFF(0, 2), flagp, zAh, sAl, sAr);
        seg(sCl, sAr, src_ci, dst_ci, ECI_, NI_, zCh, HiA);
        t_zgemm<<<dim3(625), dim3(512), 0, stream>>>(hc0, NC_, gat_W, WOFF(0, 1), gat_al, VOFF(0, 1), gat_ar, VOFF(0, 1), flagp, zCh, sCl, sCr);
        seg(sCl, sCr, src_cc, dst_cc, ECC_, NC_, zCh, HcA);
        t_zgemm<<<dim3(1024), dim3(512), 0, stream>>>(hi0, NI_, gat_W, WOFF(0, 3), gat_al, VOFF(0, 3), gat_ar, VOFF(0, 3), flagp, zAh, sAl, sAr);
        t_zgemm<<<dim3(625), dim3(512), 0, stream>>>(hc0, NC_, gat_W, WOFF(0, 3), gat_al, VOFF(0, 3), gat_ar, VOFF(0, 3), flagp, zCh, sCl, sCr);
        seg(sAl, sCr, src_ic, dst_ic, EIC_, NC_, zAh, HcA);
        s_initacc<<<GRL((long)NI_ * 128), dim3(256), 0, stream>>>(HiA, gat_b, VOFF(1, 0), VOFF(1, 2), flagp, HiB, (long)NI_ * 128);
        t_zgemm<<<dim3(1024), dim3(512), 0, stream>>>(HiA, NI_, gat_W, WOFF(1, 0), gat_al, VOFF(1, 0), gat_ar, VOFF(1, 0), flagp, zAh, sAl, sAr);
        seg(sAl, sAr, src_ii, dst_ii, EII_, NI_, zAh, HiB);
        t_zgemm<<<dim3(625), dim3(512), 0, stream>>>(HcA, NC_, gat_W, WOFF(1, 2), gat_al, VOFF(1, 2), gat_ar, VOFF(1, 2), flagp, zCh, sCl, sCr);
        t_zgemm<<<dim3(1024), dim3(512), 0, stream>>>(HiA, NI_, gat_W, WOFF(1, 2), gat_al, VOFF(1, 2), gat_ar, VOFF(1, 2), flagp, zAh, sAl, sAr);
        seg(sCl, sAr, src_ci, dst_ci, ECI_, NI_, zCh, HiB);
        t_gatefeat<<<dim3(768), dim3(512), 0, stream>>>(hi0, HiB, Wg1_w, Wg1_b, flagp, feat, NI_);
    }

    s_hall0<<<GRL((long)B_ * T_ * 128), dim3(256), 0, stream>>>(item_emb, seq, alias, mask, feat, x_s, flagp, hall0);
    t_attn12<<<dim3(B_), dim3(128), 0, stream>>>(hall0, q, mask, ln1_g, ln1_b, lin_w, lin_b, glu2_w, flagp, g2b);
    if (mf) {
        m_nh<<<dim3((B_ * T_ + 63) / 64), dim3(256), 0, stream>>>(
            pos_emb, hall0, wt2_hi, wt2_lo, flagp, flagp + 1, nh, B_ * T_);
        m_glub<<<dim3((B_ * T_ + 63) / 64), dim3(256), 0, stream>>>(
            nh, wt2_hi + (size_t)4096 * 8, wt2_lo + (size_t)4096 * 8,
            glu1_b, g2b, w_2, mask, flagp, flagp + 1, betab, B_ * T_);
    } else {
        int grid = (B_ * T_ + 15) / 16; if (grid > 1024) grid = 1024;
        t_nh<<<dim3(grid), dim3(512), 0, stream>>>(pos_emb, hall0, w_1, flagp, nh, B_ * T_);
        t_glu_beta<<<dim3(grid), dim3(512), 0, stream>>>(nh, glu1_w, glu1_b, g2b, w_2, mask, flagp, betab, B_ * T_);
    }
    t_sel<<<dim3(B_), dim3(128), 0, stream>>>(hall0, betab, ln2_g, ln2_b, feat, lasti, y_s, flagp, hallf, fenmu, outf);
    t_cos<<<dim3(B_), dim3(256), 0, stream>>>(hallf, fenmu, outf + (size_t)B_ * 128);
}

// Round 9
// 860.806 us; speedup vs baseline: 1.1880x; 1.0827x over previous
//
#include <hip/hip_runtime.h>
#include <hip/hip_fp16.h>

typedef unsigned short u16;
typedef unsigned int u32;
typedef unsigned long long u64;
typedef __attribute__((ext_vector_type(8))) short bf16x8;   // 8 bf16 = 4 VGPRs
typedef __attribute__((ext_vector_type(4))) float f32x4;    // MFMA 16x16 accumulator

#define NI_ 100000
#define NC_ 10000
#define EII_ 800000
#define ECC_ 100000
#define ECI_ 400000
#define EIC_ 400000
#define B_ 512
#define T_ 50
#define BSH_ 9            // 512-dst buckets
#define NBII_ 196         // ceil(100000/512)
#define NBNC_ 20          // ceil(10000/512)
#define NBK_ 432          // 196 II + 196 CI + 20 CC + 20 IC
#define ECH_ 4096         // edges per binning chunk

__device__ __forceinline__ float bf2f(u16 u) { return __uint_as_float(((u32)u) << 16); }
__device__ __forceinline__ u16 f2bf(float x) {
    u32 u = __float_as_uint(x);
    return (u16)((u + 0x7FFFu + ((u >> 16) & 1u)) >> 16);   // RNE
}
__device__ __forceinline__ float sigm(float x) { return 1.f / (1.f + expf(-x)); }
__device__ __forceinline__ float gldf(const void* p, size_t i, int isf) {
    return isf ? ((const float*)p)[i] : bf2f(((const u16*)p)[i]);
}
__device__ __forceinline__ float lrelu_c(float v) {
    v = (v >= 0.f) ? v : 0.2f * v;
    return fminf(fmaxf(v, -60.f), 60.f);
}

// init: dtype detect + MFMA layout self-check + bucket-counter zero
__global__ void k_init(const void* __restrict__ item, int* __restrict__ flag,
                       int* __restrict__ bcnt)
{
    const int tid = threadIdx.x;
    for (int i = tid; i < NBK_; i += 128) bcnt[i] = 0;
    if (tid < 64) {
        const int l = tid;
        bf16x8 a, b;
        #pragma unroll
        for (int j = 0; j < 8; ++j) {
            int ka = (l >> 4) * 8 + j;
            float av = (float)((((l & 15) * 5 + ka * 3) & 15) - 7);
            float bv = (float)(((ka * 7 + (l & 15) * 11) & 15) - 8);
            a[j] = (short)f2bf(av);
            b[j] = (short)f2bf(bv);
        }
        f32x4 d = {0.f, 0.f, 0.f, 0.f};
        d = __builtin_amdgcn_mfma_f32_16x16x32_bf16(a, b, d, 0, 0, 0);
        bool ok = true;
        #pragma unroll
        for (int j = 0; j < 4; ++j) {
            int row = (l >> 4) * 4 + j, col = l & 15;
            float ref = 0.f;
            for (int k = 0; k < 32; ++k)
                ref += (float)(((row * 5 + k * 3) & 15) - 7) * (float)(((k * 7 + col * 11) & 15) - 8);
            ok = ok && (d[j] == ref);
        }
        unsigned long long vote = __ballot(ok);
        if (l == 0) flag[1] = (vote == ~0ull) ? 1 : 0;
    } else if (tid == 64) {
        const u16* p = (const u16*)item;
        int cnt = 0;
        for (int i = 0; i < 128; ++i) {
            float v = bf2f(p[i]);
            if (fabsf(v) <= 0.0886f) ++cnt;
        }
        flag[0] = (cnt >= 120) ? 0 : 1;
    }
}

__global__ void s_sig(float* __restrict__ out, long n, float code)
{
    long i = (long)blockIdx.x * 256 + threadIdx.x;
    if (i < n) out[i] = (i == 0) ? code : 0.f;
}

// ============ merged pre-pass: hc0 gather | weight pack | war vecs | bucket hist ============
// roles: [0,5000) hc0, [5000,5080) prepw2, [5080,5083) wvec3, [5083,5499) bucket-hist
__global__ __launch_bounds__(256) void k_pre(
    const void* __restrict__ cate, const int* __restrict__ cid, float* __restrict__ hc0,
    const void* __restrict__ Wp, const void* __restrict__ Wg1, const void* __restrict__ gW,
    u16* __restrict__ whi, u16* __restrict__ wlo,
    const void* __restrict__ ar, float* __restrict__ wars,
    const int* __restrict__ d0, const int* __restrict__ d1,
    const int* __restrict__ d2, const int* __restrict__ d3,
    int* __restrict__ bcnt,
    const int* __restrict__ fl)
{
    __shared__ int bl[NBK_];
    const int det = fl[0];
    int bid = blockIdx.x, tid = threadIdx.x;
    if (bid < 5000) {
        long i = (long)bid * 256 + tid;
        if (i < (long)NC_ * 128)
            hc0[i] = gldf(cate, (size_t)cid[i >> 7] * 128 + (i & 127), det);
        return;
    }
    bid -= 5000;
    if (bid < 80) {
        int s = bid * 256 + tid;
        if (s >= 20480) return;
        const void* src; int K, local; size_t soff;
        if (s < 4096)       { src = Wp;  K = 256; local = s;        soff = 0; }
        else if (s < 8192)  { src = Wg1; K = 256; local = s - 4096; soff = 0; }
        else {
            int t = s - 8192; int m = t >> 11; local = t & 2047; K = 128;
            const int MK[6] = {0, 1, 2, 3, 4, 6};
            src = gW; soff = (size_t)MK[m] * 16384;
        }
        const int KK = K >> 5;
        int r = local & 15, g = (local >> 4) & 3, q2 = local >> 6;
        int kk = q2 % KK, ni = q2 / KK;
        bf16x8 hv, lv;
        #pragma unroll
        for (int j = 0; j < 8; ++j) {
            float x = gldf(src, soff + (size_t)(kk * 32 + 8 * g + j) * 128 + ni * 16 + r, det);
            u16 hb = f2bf(x);
            hv[j] = (short)hb;
            lv[j] = (short)f2bf(x - bf2f(hb));
        }
        *(bf16x8*)(whi + (size_t)s * 8) = hv;
        *(bf16x8*)(wlo + (size_t)s * 8) = lv;
        return;
    }
    bid -= 80;
    if (bid < 3) {
        if (tid < 128) {
            // wars: g=0 -> (0,2), g=1 -> (0,3), g=2 -> (1,2)
            const int WO[3] = {2 * 16384, 3 * 16384, 6 * 16384};
            const int AO[3] = {2 * 128, 3 * 128, 6 * 128};
            int g = bid, k = tid;
            float a = 0.f;
            for (int c = 0; c < 128; ++c)
                a += gldf(gW, (size_t)WO[g] + (size_t)k * 128 + c, det) * gldf(ar, AO[g] + c, det);
            wars[g * 128 + k] = a;
        }
        return;
    }
    bid -= 3;
    // ---- bucket histogram (416 blocks x 4096 edges) ----
    for (int i = tid; i < NBK_; i += 256) bl[i] = 0;
    __syncthreads();
    const long ET = (long)EII_ + ECI_ + ECC_ + EIC_;
    const long base = (long)bid * ECH_;
    #pragma unroll
    for (int j = 0; j < 16; ++j) {
        long i = base + j * 256 + tid;
        if (i < ET) {
            int dst, boff;
            long ii = i;
            if (ii < EII_) { dst = d0[ii]; boff = 0; }
            else { ii -= EII_;
            if (ii < ECI_) { dst = d1[ii]; boff = NBII_; }
            else { ii -= ECI_;
            if (ii < ECC_) { dst = d2[ii]; boff = 2 * NBII_; }
            else { ii -= ECC_; dst = d3[ii]; boff = 2 * NBII_ + NBNC_; } } }
            atomicAdd(&bl[boff + (dst >> BSH_)], 1);
        }
    }
    __syncthreads();
    for (int i = tid; i < NBK_; i += 256)
        if (bl[i]) atomicAdd(&bcnt[i], bl[i]);
}

// per-graph-segment scan of bucket counts -> bstart (kept) + gcur (consumed by binA)
__global__ void k_bscan(const int* __restrict__ bcnt,
                        int* __restrict__ bstart, int* __restrict__ gcur)
{
    if (threadIdx.x != 0 || blockIdx.x != 0) return;
    int run = 0;
    for (int i = 0; i < NBII_; ++i) { bstart[i] = run; gcur[i] = run; run += bcnt[i]; }
    run = 0;
    for (int i = NBII_; i < 2 * NBII_; ++i) { bstart[i] = run; gcur[i] = run; run += bcnt[i]; }
    run = 0;
    for (int i = 2 * NBII_; i < 2 * NBII_ + NBNC_; ++i) { bstart[i] = run; gcur[i] = run; run += bcnt[i]; }
    run = 0;
    for (int i = 2 * NBII_ + NBNC_; i < NBK_; ++i) { bstart[i] = run; gcur[i] = run; run += bcnt[i]; }
}

// phase A: bin edges by 512-dst bucket; LDS-compact, burst-write (src<<BSH|dstlocal)
__global__ __launch_bounds__(256) void k_binA(
    const int* s0, const int* d0, const int* s1, const int* d1,
    const int* s2, const int* d2, const int* s3, const int* d3,
    int* __restrict__ gcur,
    u32* __restrict__ b0, u32* __restrict__ b1,
    u32* __restrict__ b2, u32* __restrict__ b3)
{
    __shared__ u32 stag[ECH_];
    __shared__ int cnt[NBK_], base_l[NBK_ + 1], gbase[NBK_], cur_l[NBK_];
    const int tid = threadIdx.x;
    const long estart = (long)blockIdx.x * ECH_;
    const long ET = (long)EII_ + ECI_ + ECC_ + EIC_;
    for (int b = tid; b < NBK_; b += 256) cnt[b] = 0;
    __syncthreads();
    int gidv[16]; u32 pk[16];
    #pragma unroll
    for (int j = 0; j < 16; ++j) {
        long i = estart + j * 256 + tid;
        gidv[j] = -1;
        if (i < ET) {
            int src, dst, boff;
            long ii = i;
            if (ii < EII_) { src = s0[ii]; dst = d0[ii]; boff = 0; }
            else { ii -= EII_;
            if (ii < ECI_) { src = s1[ii]; dst = d1[ii]; boff = NBII_; }
            else { ii -= ECI_;
            if (ii < ECC_) { src = s2[ii]; dst = d2[ii]; boff = 2 * NBII_; }
            else { ii -= ECC_; src = s3[ii]; dst = d3[ii]; boff = 2 * NBII_ + NBNC_; } } }
            int gid = boff + (dst >> BSH_);
            gidv[j] = gid;
            pk[j] = ((u32)src << BSH_) | (u32)(dst & ((1 << BSH_) - 1));
            atomicAdd(&cnt[gid], 1);
        }
    }
    __syncthreads();
    if (tid == 0) {
        int run = 0;
        for (int b = 0; b < NBK_; ++b) { base_l[b] = run; run += cnt[b]; }
        base_l[NBK_] = run;
    }
    __syncthreads();
    for (int b = tid; b < NBK_; b += 256) {
        gbase[b] = cnt[b] ? atomicAdd(&gcur[b], cnt[b]) : 0;
        cur_l[b] = base_l[b];
    }
    __syncthreads();
    #pragma unroll
    for (int j = 0; j < 16; ++j)
        if (gidv[j] >= 0) {
            int l = atomicAdd(&cur_l[gidv[j]], 1);
            stag[l] = pk[j];
        }
    __syncthreads();
    const int total = base_l[NBK_];
    for (int t = tid; t < total; t += 256) {
        int lo = 0, hi = NBK_ - 1;
        while (lo < hi) { int mid = (lo + hi + 1) >> 1; if (base_l[mid] <= t) lo = mid; else hi = mid - 1; }
        int pos = gbase[lo] + (t - base_l[lo]);
        u32* bp = (lo < NBII_) ? b0 : (lo < 2 * NBII_) ? b1 : (lo < 2 * NBII_ + NBNC_) ? b2 : b3;
        bp[pos] = stag[t];
    }
}

// phase B: per-bucket — per-dst count, local scan -> rowptr, fine fill in 2KB window
__global__ __launch_bounds__(512) void k_binB(
    const int* __restrict__ bstart, const int* __restrict__ bcnt,
    const u32* __restrict__ b0, const u32* __restrict__ b1,
    const u32* __restrict__ b2, const u32* __restrict__ b3,
    int* __restrict__ rpII, int* __restrict__ rpCI,
    int* __restrict__ rpCC, int* __restrict__ rpIC,
    int* __restrict__ csII, int* __restrict__ csCI,
    int* __restrict__ csCC, int* __restrict__ csIC)
{
    __shared__ int cnt[512], cur[512];
    const int gid = blockIdx.x, tid = threadIdx.x;
    int* rp; const u32* bp; int* cs; int b, n, Eg; bool last;
    if (gid < NBII_)                  { rp = rpII; bp = b0; cs = csII; b = gid;                     n = NI_; Eg = EII_; last = (gid == NBII_ - 1); }
    else if (gid < 2 * NBII_)         { rp = rpCI; bp = b1; cs = csCI; b = gid - NBII_;             n = NI_; Eg = ECI_; last = (gid == 2 * NBII_ - 1); }
    else if (gid < 2 * NBII_ + NBNC_) { rp = rpCC; bp = b2; cs = csCC; b = gid - 2 * NBII_;         n = NC_; Eg = ECC_; last = (gid == 2 * NBII_ + NBNC_ - 1); }
    else                              { rp = rpIC; bp = b3; cs = csIC; b = gid - 2 * NBII_ - NBNC_; n = NC_; Eg = EIC_; last = (gid == NBK_ - 1); }
    const int dz = b << BSH_;
    const int d1v = (dz + 512 < n) ? dz + 512 : n;
    const int ndl = d1v - dz;
    cnt[tid] = 0;
    __syncthreads();
    const int e0 = bstart[gid], e1 = e0 + bcnt[gid];
    for (int e = e0 + tid; e < e1; e += 512)
        atomicAdd(&cnt[bp[e] & 511], 1);
    __syncthreads();
    for (int s = 1; s < 512; s <<= 1) {
        int v = (tid >= s) ? cnt[tid - s] : 0;
        __syncthreads();
        cnt[tid] += v;
        __syncthreads();
    }
    const int excl = (tid == 0) ? 0 : cnt[tid - 1];
    cur[tid] = e0 + excl;
    if (tid < ndl) rp[dz + tid] = e0 + excl;
    if (last && tid == 0) rp[n] = Eg;
    __syncthreads();
    for (int e = e0 + tid; e < e1; e += 512) {
        u32 p = bp[e];
        int pos = atomicAdd(&cur[p & 511], 1);
        cs[pos] = (int)(p >> BSH_);
    }
}

// ========== GAT aggregation (fused, shuffle-cached alphas, fp16 z, 8-wide ILP) ==========
__device__ __forceinline__ void gat_gather(
    const int* __restrict__ rp, const int* __restrict__ cs,
    const float* __restrict__ sl, float srd, const __half2* __restrict__ z,
    int w, int lane, float& a0, float& a1)
{
    const int start = rp[w], end = rp[w + 1];
    if (end <= start) return;
    const int cnt = end - start;
    int   sE = 0; float eE = 0.f;
    if (lane < cnt) {
        sE = cs[start + lane];
        eE = expf(lrelu_c(sl[sE] + srd));
    }
    float local = eE;
    for (int k = start + 64 + lane; k < end; k += 64)
        local += expf(lrelu_c(sl[cs[k]] + srd));
    #pragma unroll
    for (int o = 32; o > 0; o >>= 1) local += __shfl_xor(local, o, 64);
    const float inv = 1.f / local;
    const int m = (cnt < 64) ? cnt : 64;
    int k = 0;
    for (; k + 8 <= m; k += 8) {
        int   s[8]; float lw[8]; float2 f[8];
        #pragma unroll
        for (int u = 0; u < 8; ++u) {
            s[u]  = __shfl(sE, k + u, 64);
            lw[u] = __shfl(eE, k + u, 64) * inv;
        }
        #pragma unroll
        for (int u = 0; u < 8; ++u) f[u] = __half22float2(z[(size_t)s[u] * 64 + lane]);
        #pragma unroll
        for (int u = 0; u < 8; ++u) { a0 += lw[u] * f[u].x; a1 += lw[u] * f[u].y; }
    }
    for (; k + 4 <= m; k += 4) {
        int s0 = __shfl(sE, k, 64),     s1 = __shfl(sE, k + 1, 64);
        int s2 = __shfl(sE, k + 2, 64), s3 = __shfl(sE, k + 3, 64);
        float l0 = __shfl(eE, k, 64) * inv,     l1 = __shfl(eE, k + 1, 64) * inv;
        float l2 = __shfl(eE, k + 2, 64) * inv, l3 = __shfl(eE, k + 3, 64) * inv;
        float2 f0 = __half22float2(z[(size_t)s0 * 64 + lane]);
        float2 f1 = __half22float2(z[(size_t)s1 * 64 + lane]);
        float2 f2 = __half22float2(z[(size_t)s2 * 64 + lane]);
        float2 f3 = __half22float2(z[(size_t)s3 * 64 + lane]);
        a0 += l0 * f0.x + l1 * f1.x + l2 * f2.x + l3 * f3.x;
        a1 += l0 * f0.y + l1 * f1.y + l2 * f2.y + l3 * f3.y;
    }
    for (; k < m; ++k) {
        int s = __shfl(sE, k, 64);
        float al = __shfl(eE, k, 64) * inv;
        float2 f = __half22float2(z[(size_t)s * 64 + lane]);
        a0 += al * f.x;
        a1 += al * f.y;
    }
    for (int kk = start + 64; kk < end; ++kk) {   // rare: degree > 64
        int s = cs[kk];
        float al = expf(lrelu_c(sl[s] + srd)) * inv;
        float2 f = __half22float2(z[(size_t)s * 64 + lane]);
        a0 += al * f.x;
        a1 += al * f.y;
    }
}

// acc = 2*h0 + gb[b0] + gb[b1] + sum_A(alpha*zA[src]) + sum_B(alpha*zB[src])
__global__ __launch_bounds__(256) void t_gat_fused(
    const int* __restrict__ rpA, const int* __restrict__ csA,
    const float* __restrict__ slA, const float* __restrict__ srA, const __half2* __restrict__ zA_,
    const int* __restrict__ rpB, const int* __restrict__ csB,
    const float* __restrict__ slB, const float* __restrict__ war, const __half2* __restrict__ zB_,
    const float* __restrict__ h0, const void* __restrict__ gb, int b0off, int b1off,
    const int* __restrict__ fl, float* __restrict__ acc, int ndst)
{
    int w = blockIdx.x * 4 + (threadIdx.x >> 6);
    int lane = threadIdx.x & 63;
    if (w >= ndst) return;
    const int det = *fl;
    const int d0 = 2 * lane, d1 = 2 * lane + 1;
    float2 h0v = *(const float2*)(h0 + (size_t)w * 128 + d0);
    float2 wv  = *(const float2*)(war + d0);
    float srB = h0v.x * wv.x + h0v.y * wv.y;
    #pragma unroll
    for (int off = 32; off > 0; off >>= 1) srB += __shfl_xor(srB, off, 64);
    float a0 = 2.f * h0v.x + gldf(gb, b0off + d0, det) + gldf(gb, b1off + d0, det);
    float a1 = 2.f * h0v.y + gldf(gb, b0off + d1, det) + gldf(gb, b1off + d1, det);
    gat_gather(rpA, csA, slA, srA[w], zA_, w, lane, a0, a1);
    gat_gather(rpB, csB, slB, srB,    zB_, w, lane, a0, a1);
    *(float2*)(acc + (size_t)w * 128 + d0) = make_float2(a0, a1);
}

// attention-phase weight pack (w_1 + glu1_w), re-done each iter (wt2 overlays HiA)
__global__ __launch_bounds__(256) void k_prepw3(
    const void* __restrict__ w1, const void* __restrict__ g1w,
    const int* __restrict__ fl, u16* __restrict__ whi, u16* __restrict__ wlo)
{
    int s = blockIdx.x * 256 + threadIdx.x;
    if (s >= 6144) return;
    const int det = *fl;
    const void* src; int K, local;
    if (s < 4096) { src = w1;  K = 256; local = s; }
    else          { src = g1w; K = 128; local = s - 4096; }
    const int KK = K >> 5;
    int r = local & 15, g = (local >> 4) & 3, q2 = local >> 6;
    int kk = q2 % KK, ni = q2 / KK;
    bf16x8 hv, lv;
    #pragma unroll
    for (int j = 0; j < 8; ++j) {
        float x = gldf(src, (size_t)(kk * 32 + 8 * g + j) * 128 + ni * 16 + r, det);
        u16 hb = f2bf(x);
        hv[j] = (short)hb;
        lv[j] = (short)f2bf(x - bf2f(hb));
    }
    *(bf16x8*)(whi + (size_t)s * 8) = hv;
    *(bf16x8*)(wlo + (size_t)s * 8) = lv;
}

// hi0 = [item[iid] | cate[icate]] @ W_pos   (K=256)
__global__ __launch_bounds__(256, 2) void m_hi0(
    const void* __restrict__ item, const void* __restrict__ cate,
    const int* __restrict__ iid, const int* __restrict__ icate,
    const u16* __restrict__ whi, const u16* __restrict__ wlo,
    const int* __restrict__ fl, const int* __restrict__ mfok,
    float* __restrict__ out, int nrows)
{
    if (*mfok == 0) return;
    __shared__ __align__(16) short Ah[2048 * 8];   // 32 KB
    __shared__ __align__(16) short Alo[2048 * 8];  // 32 KB
    const int det = *fl;
    const int tid = threadIdx.x, l = tid & 63, w = tid >> 6;
    const int base = blockIdx.x * 64;
    {
        int row = tid >> 2, q = tid & 3;
        int n = base + row, mi = row >> 4, r = row & 15;
        const int it = (n < nrows) ? iid[n] : 0;
        const int ct = (n < nrows) ? icate[n] : 0;
        #pragma unroll
        for (int i = 0; i < 8; ++i) {
            int c = q + 4 * i, kk = c >> 2, g = c & 3;
            int slot = ((mi * 8 + kk) * 4 + g) * 16 + r;
            bf16x8 hv = {0,0,0,0,0,0,0,0}, lv = {0,0,0,0,0,0,0,0};
            if (n < nrows) {
                #pragma unroll
                for (int j = 0; j < 8; ++j) {
                    float x = (c < 16) ? gldf(item, (size_t)it * 128 + c * 8 + j, det)
                                       : gldf(cate, (size_t)ct * 128 + (c - 16) * 8 + j, det);
                    u16 hb2 = f2bf(x);
                    hv[j] = (short)hb2;
                    lv[j] = (short)f2bf(x - bf2f(hb2));
                }
            }
            *(bf16x8*)&Ah[slot * 8]  = hv;
            *(bf16x8*)&Alo[slot * 8] = lv;
        }
    }
    bf16x8 breg[2][8];
    #pragma unroll
    for (int t = 0; t < 2; ++t)
        #pragma unroll
        for (int kk = 0; kk < 8; ++kk)
            breg[t][kk] = *(const bf16x8*)(whi + ((size_t)((w * 2 + t) * 8 + kk) * 64 + l) * 8);
    __syncthreads();
    f32x4 acc[4][2];
    #pragma unroll
    for (int mi = 0; mi < 4; ++mi) { acc[mi][0] = (f32x4){0.f,0.f,0.f,0.f}; acc[mi][1] = (f32x4){0.f,0.f,0.f,0.f}; }
    auto pass = [&](const short* AS) {
        #pragma unroll
        for (int kk = 0; kk < 8; ++kk) {
            bf16x8 a[4];
            #pragma unroll
            for (int mi = 0; mi < 4; ++mi) a[mi] = *(const bf16x8*)&AS[((mi * 8 + kk) * 64 + l) * 8];
            #pragma unroll
            for (int mi = 0; mi < 4; ++mi) {
                acc[mi][0] = __builtin_amdgcn_mfma_f32_16x16x32_bf16(a[mi], breg[0][kk], acc[mi][0], 0, 0, 0);
                acc[mi][1] = __builtin_amdgcn_mfma_f32_16x16x32_bf16(a[mi], breg[1][kk], acc[mi][1], 0, 0, 0);
            }
        }
    };
    pass(Ah);
    pass(Alo);
    #pragma unroll
    for (int t = 0; t < 2; ++t)
        #pragma unroll
        for (int kk = 0; kk < 8; ++kk)
            breg[t][kk] = *(const bf16x8*)(wlo + ((size_t)((w * 2 + t) * 8 + kk) * 64 + l) * 8);
    pass(Ah);
    const int g = l >> 4, r = l & 15, wn0 = w * 32;
    #pragma unroll
    for (int mi = 0; mi < 4; ++mi)
        #pragma unroll
        for (int j = 0; j < 4; ++j) {
            int row = base + mi * 16 + 4 * g + j;
            if (row < nrows) {
                out[(size_t)row * 128 + wn0 + r]      = acc[mi][0][j];
                out[(size_t)row * 128 + wn0 + 16 + r] = acc[mi][1][j];
            }
        }
}

// z = h @ W (K=128, fp32 h) -> fp16 z + fused sl = z@al, sr = z@ar
__global__ __launch_bounds__(256, 2) void m_zgemm(
    const float* __restrict__ h, int nrows,
    const u16* __restrict__ whi, const u16* __restrict__ wlo,
    const void* __restrict__ al, int aloff, const void* __restrict__ ar, int aroff,
    const int* __restrict__ fl, const int* __restrict__ mfok,
    __half* __restrict__ z, float* __restrict__ sl, float* __restrict__ sr)
{
    if (*mfok == 0) return;
    __shared__ __align__(16) short Ah[1024 * 8];   // 16 KB
    __shared__ __align__(16) short Alo[1024 * 8];  // 16 KB
    __shared__ float part[2][4][64];               // 2 KB
    const int det = *fl;
    const int tid = threadIdx.x, l = tid & 63, w = tid >> 6;
    const int base = blockIdx.x * 64;
    {
        int row = tid >> 2, q = tid & 3;
        int n = base + row, mi = row >> 4, r = row & 15;
        #pragma unroll
        for (int i = 0; i < 4; ++i) {
            int c = q + 4 * i, kk = c >> 2, g = c & 3;
            int slot = ((mi * 4 + kk) * 4 + g) * 16 + r;
            bf16x8 hv = {0,0,0,0,0,0,0,0}, lv = {0,0,0,0,0,0,0,0};
            if (n < nrows) {
                const float* sp = h + (size_t)n * 128 + c * 8;
                #pragma unroll
                for (int j = 0; j < 8; ++j) {
                    float x = sp[j];
                    u16 hb = f2bf(x);
                    hv[j] = (short)hb;
                    lv[j] = (short)f2bf(x - bf2f(hb));
                }
            }
            *(bf16x8*)&Ah[slot * 8]  = hv;
            *(bf16x8*)&Alo[slot * 8] = lv;
        }
    }
    bf16x8 breg[2][4];
    #pragma unroll
    for (int t = 0; t < 2; ++t)
        #pragma unroll
        for (int kk = 0; kk < 4; ++kk)
            breg[t][kk] = *(const bf16x8*)(whi + ((size_t)((w * 2 + t) * 4 + kk) * 64 + l) * 8);
    __syncthreads();
    f32x4 acc[4][2];
    #pragma unroll
    for (int mi = 0; mi < 4; ++mi) { acc[mi][0] = (f32x4){0.f,0.f,0.f,0.f}; acc[mi][1] = (f32x4){0.f,0.f,0.f,0.f}; }
    auto pass = [&](const short* AS) {
        #pragma unroll
        for (int kk = 0; kk < 4; ++kk) {
            bf16x8 a[4];
            #pragma unroll
            for (int mi = 0; mi < 4; ++mi) a[mi] = *(const bf16x8*)&AS[((mi * 4 + kk) * 64 + l) * 8];
            #pragma unroll
            for (int mi = 0; mi < 4; ++mi) {
                acc[mi][0] = __builtin_amdgcn_mfma_f32_16x16x32_bf16(a[mi], breg[0][kk], acc[mi][0], 0, 0, 0);
                acc[mi][1] = __builtin_amdgcn_mfma_f32_16x16x32_bf16(a[mi], breg[1][kk], acc[mi][1], 0, 0, 0);
            }
        }
    };
    pass(Ah);
    pass(Alo);
    #pragma unroll
    for (int t = 0; t < 2; ++t)
        #pragma unroll
        for (int kk = 0; kk < 4; ++kk)
            breg[t][kk] = *(const bf16x8*)(wlo + ((size_t)((w * 2 + t) * 4 + kk) * 64 + l) * 8);
    pass(Ah);
    const int g = l >> 4, r = l & 15, wn0 = w * 32;
    const float alv0 = gldf(al, (size_t)aloff + wn0 + r, det);
    const float alv1 = gldf(al, (size_t)aloff + wn0 + 16 + r, det);
    const float arv0 = gldf(ar, (size_t)aroff + wn0 + r, det);
    const float arv1 = gldf(ar, (size_t)aroff + wn0 + 16 + r, det);
    #pragma unroll
    for (int mi = 0; mi < 4; ++mi)
        #pragma unroll
        for (int j = 0; j < 4; ++j) {
            int row = base + mi * 16 + 4 * g + j;
            float d0 = acc[mi][0][j], d1 = acc[mi][1][j];
            if (row < nrows) {
                z[(size_t)row * 128 + wn0 + r]      = __float2half_rn(d0);
                z[(size_t)row * 128 + wn0 + 16 + r] = __float2half_rn(d1);
            }
            float pl = d0 * alv0 + d1 * alv1;
            float pr = d0 * arv0 + d1 * arv1;
            #pragma unroll
            for (int m2 = 1; m2 < 16; m2 <<= 1) {
                pl += __shfl_xor(pl, m2, 64);
                pr += __shfl_xor(pr, m2, 64);
            }
            if (r == 0) {
                part[0][w][mi * 16 + 4 * g + j] = pl;
                part[1][w][mi * 16 + 4 * g + j] = pr;
            }
        }
    __syncthreads();
    if (tid < 128) {
        int which = tid >> 6, t = tid & 63;
        int n2 = base + t;
        if (n2 < nrows) {
            float s = part[which][0][t] + part[which][1][t] + part[which][2][t] + part[which][3][t];
            (which ? sr : sl)[n2] = s;
        }
    }
}

// dual-weight z-gemm
__global__ __launch_bounds__(256, 2) void m_zgemm2(
    const float* __restrict__ h, int nrows,
    const u16* __restrict__ whi1, const u16* __restrict__ wlo1,
    int alo1, int aro1, __half* __restrict__ z1,
    float* __restrict__ sl1, float* __restrict__ sr1,
    const u16* __restrict__ whi2, const u16* __restrict__ wlo2,
    int alo2, int aro2, __half* __restrict__ z2,
    float* __restrict__ sl2, float* __restrict__ sr2,
    const void* __restrict__ al, const void* __restrict__ ar,
    const int* __restrict__ fl, const int* __restrict__ mfok)
{
    if (*mfok == 0) return;
    __shared__ __align__(16) short Ah[1024 * 8];   // 16 KB
    __shared__ __align__(16) short Alo[1024 * 8];  // 16 KB
    __shared__ float part[2][4][64];               // 2 KB
    const int det = *fl;
    const int tid = threadIdx.x, l = tid & 63, w = tid >> 6;
    const int base = blockIdx.x * 64;
    {
        int row = tid >> 2, q = tid & 3;
        int n = base + row, mi = row >> 4, r = row & 15;
        #pragma unroll
        for (int i = 0; i < 4; ++i) {
            int c = q + 4 * i, kk = c >> 2, g = c & 3;
            int slot = ((mi * 4 + kk) * 4 + g) * 16 + r;
            bf16x8 hv = {0,0,0,0,0,0,0,0}, lv = {0,0,0,0,0,0,0,0};
            if (n < nrows) {
                const float* sp = h + (size_t)n * 128 + c * 8;
                #pragma unroll
                for (int j = 0; j < 8; ++j) {
                    float x = sp[j];
                    u16 hb = f2bf(x);
                    hv[j] = (short)hb;
                    lv[j] = (short)f2bf(x - bf2f(hb));
                }
            }
            *(bf16x8*)&Ah[slot * 8]  = hv;
            *(bf16x8*)&Alo[slot * 8] = lv;
        }
    }
    __syncthreads();
    const int g = l >> 4, r = l & 15, wn0 = w * 32;
    auto doSet = [&](const u16* whi, const u16* wlo, int aloff, int aroff,
                     __half* z, float* sl, float* sr) {
        bf16x8 breg[2][4];
        #pragma unroll
        for (int t = 0; t < 2; ++t)
            #pragma unroll
            for (int kk = 0; kk < 4; ++kk)
                breg[t][kk] = *(const bf16x8*)(whi + ((size_t)((w * 2 + t) * 4 + kk) * 64 + l) * 8);
        f32x4 acc[4][2];
        #pragma unroll
        for (int mi = 0; mi < 4; ++mi) { acc[mi][0] = (f32x4){0.f,0.f,0.f,0.f}; acc[mi][1] = (f32x4){0.f,0.f,0.f,0.f}; }
        auto pass = [&](const short* AS) {
            #pragma unroll
            for (int kk = 0; kk < 4; ++kk) {
                bf16x8 a[4];
                #pragma unroll
                for (int mi = 0; mi < 4; ++mi) a[mi] = *(const bf16x8*)&AS[((mi * 4 + kk) * 64 + l) * 8];
                #pragma unroll
                for (int mi = 0; mi < 4; ++mi) {
                    acc[mi][0] = __builtin_amdgcn_mfma_f32_16x16x32_bf16(a[mi], breg[0][kk], acc[mi][0], 0, 0, 0);
                    acc[mi][1] = __builtin_amdgcn_mfma_f32_16x16x32_bf16(a[mi], breg[1][kk], acc[mi][1], 0, 0, 0);
                }
            }
        };
        pass(Ah);
        pass(Alo);
        #pragma unroll
        for (int t = 0; t < 2; ++t)
            #pragma unroll
            for (int kk = 0; kk < 4; ++kk)
                breg[t][kk] = *(const bf16x8*)(wlo + ((size_t)((w * 2 + t) * 4 + kk) * 64 + l) * 8);
        pass(Ah);
        const float alv0 = gldf(al, (size_t)aloff + wn0 + r, det);
        const float alv1 = gldf(al, (size_t)aloff + wn0 + 16 + r, det);
        const float arv0 = gldf(ar, (size_t)aroff + wn0 + r, det);
        const float arv1 = gldf(ar, (size_t)aroff + wn0 + 16 + r, det);
        #pragma unroll
        for (int mi = 0; mi < 4; ++mi)
            #pragma unroll
            for (int j = 0; j < 4; ++j) {
                int row = base + mi * 16 + 4 * g + j;
                float d0 = acc[mi][0][j], d1 = acc[mi][1][j];
                if (row < nrows) {
                    z[(size_t)row * 128 + wn0 + r]      = __float2half_rn(d0);
                    z[(size_t)row * 128 + wn0 + 16 + r] = __float2half_rn(d1);
                }
                float pl = d0 * alv0 + d1 * alv1;
                float pr = d0 * arv0 + d1 * arv1;
                #pragma unroll
                for (int m2 = 1; m2 < 16; m2 <<= 1) {
                    pl += __shfl_xor(pl, m2, 64);
                    pr += __shfl_xor(pr, m2, 64);
                }
                if (r == 0) {
                    part[0][w][mi * 16 + 4 * g + j] = pl;
                    part[1][w][mi * 16 + 4 * g + j] = pr;
                }
            }
        __syncthreads();
        if (tid < 128) {
            int which = tid >> 6, t = tid & 63;
            int n2 = base + t;
            if (n2 < nrows) {
                float s = part[which][0][t] + part[which][1][t] + part[which][2][t] + part[which][3][t];
                (which ? sr : sl)[n2] = s;
            }
        }
        __syncthreads();
    };
    doSet(whi1, wlo1, alo1, aro1, z1, sl1, sr1);
    doSet(whi2, wlo2, alo2, aro2, z2, sl2, sr2);
}

// feat = g*h0 + (1-g)*h1, g = sigm([h0|h1] @ W + b)   (K=256)
__global__ __launch_bounds__(256, 2) void m_gatefeat(
    const float* __restrict__ h0, const float* __restrict__ h1,
    const u16* __restrict__ whi, const u16* __restrict__ wlo,
    const void* __restrict__ bias,
    const int* __restrict__ fl, const int* __restrict__ mfok,
    float* __restrict__ feat, int nrows)
{
    if (*mfok == 0) return;
    __shared__ __align__(16) short Ah[2048 * 8];   // 32 KB
    __shared__ __align__(16) short Alo[2048 * 8];  // 32 KB
    const int det = *fl;
    const int tid = threadIdx.x, l = tid & 63, w = tid >> 6;
    const int base = blockIdx.x * 64;
    {
        int row = tid >> 2, q = tid & 3;
        int n = base + row, mi = row >> 4, r = row & 15;
        #pragma unroll
        for (int i = 0; i < 8; ++i) {
            int c = q + 4 * i, kk = c >> 2, g = c & 3;
            int slot = ((mi * 8 + kk) * 4 + g) * 16 + r;
            bf16x8 hv = {0,0,0,0,0,0,0,0}, lv = {0,0,0,0,0,0,0,0};
            if (n < nrows) {
                const float* sp = ((c < 16) ? h0 : h1) + (size_t)n * 128 + (c & 15) * 8;
                #pragma unroll
                for (int j = 0; j < 8; ++j) {
                    float x = sp[j];
                    u16 hb = f2bf(x);
                    hv[j] = (short)hb;
                    lv[j] = (short)f2bf(x - bf2f(hb));
                }
            }
            *(bf16x8*)&Ah[slot * 8]  = hv;
            *(bf16x8*)&Alo[slot * 8] = lv;
        }
    }
    bf16x8 breg[2][8];
    #pragma unroll
    for (int t = 0; t < 2; ++t)
        #pragma unroll
        for (int kk = 0; kk < 8; ++kk)
            breg[t][kk] = *(const bf16x8*)(whi + ((size_t)((w * 2 + t) * 8 + kk) * 64 + l) * 8);
    __syncthreads();
    f32x4 acc[4][2];
    #pragma unroll
    for (int mi = 0; mi < 4; ++mi) { acc[mi][0] = (f32x4){0.f,0.f,0.f,0.f}; acc[mi][1] = (f32x4){0.f,0.f,0.f,0.f}; }
    auto pass = [&](const short* AS) {
        #pragma unroll
        for (int kk = 0; kk < 8; ++kk) {
            bf16x8 a[4];
            #pragma unroll
            for (int mi = 0; mi < 4; ++mi) a[mi] = *(const bf16x8*)&AS[((mi * 8 + kk) * 64 + l) * 8];
            #pragma unroll
            for (int mi = 0; mi < 4; ++mi) {
                acc[mi][0] = __builtin_amdgcn_mfma_f32_16x16x32_bf16(a[mi], breg[0][kk], acc[mi][0], 0, 0, 0);
                acc[mi][1] = __builtin_amdgcn_mfma_f32_16x16x32_bf16(a[mi], breg[1][kk], acc[mi][1], 0, 0, 0);
            }
        }
    };
    pass(Ah);
    pass(Alo);
    #pragma unroll
    for (int t = 0; t < 2; ++t)
        #pragma unroll
        for (int kk = 0; kk < 8; ++kk)
            breg[t][kk] = *(const bf16x8*)(wlo + ((size_t)((w * 2 + t) * 8 + kk) * 64 + l) * 8);
    pass(Ah);
    const int g = l >> 4, r = l & 15, wn0 = w * 32;
    const float bv0 = gldf(bias, wn0 + r, det);
    const float bv1 = gldf(bias, wn0 + 16 + r, det);
    #pragma unroll
    for (int mi = 0; mi < 4; ++mi)
        #pragma unroll
        for (int j = 0; j < 4; ++j) {
            int row = base + mi * 16 + 4 * g + j;
            if (row < nrows) {
                size_t o0 = (size_t)row * 128 + wn0 + r;
                size_t o1 = o0 + 16;
                float ga  = sigm(acc[mi][0][j] + bv0);
                float gb2 = sigm(acc[mi][1][j] + bv1);
                feat[o0] = ga  * h0[o0] + (1.f - ga)  * h1[o0];
                feat[o1] = gb2 * h0[o1] + (1.f - gb2) * h1[o1];
            }
        }
}

// fused: nh = tanh([pos|hall0]@w1) (K=256) then beta = (sigm(nh@glu1+b+g2).w2)*mask (K=128)
__global__ __launch_bounds__(256, 2) void m_nhglu(
    const void* __restrict__ pos, const float* __restrict__ hall0,
    const u16* __restrict__ whi1, const u16* __restrict__ wlo1,
    const u16* __restrict__ whi2, const u16* __restrict__ wlo2,
    const void* __restrict__ gb, const float* __restrict__ g2,
    const void* __restrict__ w2, const int* __restrict__ mask,
    const int* __restrict__ fl, const int* __restrict__ mfok,
    float* __restrict__ beta, int nrows)
{
    if (*mfok == 0) return;
    __shared__ __align__(16) short Ah[2048 * 8];   // 32 KB (phase2 reuses first 16 KB)
    __shared__ __align__(16) short Alo[2048 * 8];  // 32 KB
    __shared__ float part[4][64];
    const int det = *fl;
    const int tid = threadIdx.x, l = tid & 63, w = tid >> 6;
    const int base = blockIdx.x * 64;
    // ---- phase 1 staging: [pos(t) | hall0], K=256 ----
    {
        int row = tid >> 2, q = tid & 3;
        int n = base + row, mi = row >> 4, r = row & 15;
        const int t = (n < nrows) ? (n - (n / T_) * T_) : 0;
        #pragma unroll
        for (int i = 0; i < 8; ++i) {
            int c = q + 4 * i, kk = c >> 2, g = c & 3;
            int slot = ((mi * 8 + kk) * 4 + g) * 16 + r;
            bf16x8 hv = {0,0,0,0,0,0,0,0}, lv = {0,0,0,0,0,0,0,0};
            if (n < nrows) {
                #pragma unroll
                for (int j = 0; j < 8; ++j) {
                    float x = (c < 16) ? gldf(pos, (size_t)t * 128 + c * 8 + j, det)
                                       : hall0[(size_t)n * 128 + (c - 16) * 8 + j];
                    u16 hb = f2bf(x);
                    hv[j] = (short)hb;
                    lv[j] = (short)f2bf(x - bf2f(hb));
                }
            }
            *(bf16x8*)&Ah[slot * 8]  = hv;
            *(bf16x8*)&Alo[slot * 8] = lv;
        }
    }
    bf16x8 breg[2][8];
    #pragma unroll
    for (int t = 0; t < 2; ++t)
        #pragma unroll
        for (int kk = 0; kk < 8; ++kk)
            breg[t][kk] = *(const bf16x8*)(whi1 + ((size_t)((w * 2 + t) * 8 + kk) * 64 + l) * 8);
    __syncthreads();
    f32x4 acc[4][2];
    #pragma unroll
    for (int mi = 0; mi < 4; ++mi) { acc[mi][0] = (f32x4){0.f,0.f,0.f,0.f}; acc[mi][1] = (f32x4){0.f,0.f,0.f,0.f}; }
    auto pass1 = [&](const short* AS) {
        #pragma unroll
        for (int kk = 0; kk < 8; ++kk) {
            bf16x8 a[4];
            #pragma unroll
            for (int mi = 0; mi < 4; ++mi) a[mi] = *(const bf16x8*)&AS[((mi * 8 + kk) * 64 + l) * 8];
            #pragma unroll
            for (int mi = 0; mi < 4; ++mi) {
                acc[mi][0] = __builtin_amdgcn_mfma_f32_16x16x32_bf16(a[mi], breg[0][kk], acc[mi][0], 0, 0, 0);
                acc[mi][1] = __builtin_amdgcn_mfma_f32_16x16x32_bf16(a[mi], breg[1][kk], acc[mi][1], 0, 0, 0);
            }
        }
    };
    pass1(Ah);
    pass1(Alo);
    #pragma unroll
    for (int t = 0; t < 2; ++t)
        #pragma unroll
        for (int kk = 0; kk < 8; ++kk)
            breg[t][kk] = *(const bf16x8*)(wlo1 + ((size_t)((w * 2 + t) * 8 + kk) * 64 + l) * 8);
    pass1(Ah);
    // ---- write tanh(acc) into LDS in K=128 frag-native layout ----
    __syncthreads();
    {
        const int g = l >> 4, r = l & 15, wn0 = w * 32;
        #pragma unroll
        for (int mi = 0; mi < 4; ++mi)
            #pragma unroll
            for (int j = 0; j < 4; ++j) {
                int nloc = mi * 16 + 4 * g + j;
                int rr = nloc & 15, mi2 = nloc >> 4;
                #pragma unroll
                for (int hh = 0; hh < 2; ++hh) {
                    int col = wn0 + 16 * hh + r;
                    float x = tanhf(acc[mi][hh][j]);
                    int c = col >> 3, jj = col & 7;
                    int slot = ((mi2 * 4 + (c >> 2)) * 4 + (c & 3)) * 16 + rr;
                    u16 hb = f2bf(x);
                    Ah[slot * 8 + jj]  = (short)hb;
                    Alo[slot * 8 + jj] = (short)f2bf(x - bf2f(hb));
                }
            }
    }
    __syncthreads();
    // ---- phase 2: K=128 GEMM vs glu1 + epilogue ----
    bf16x8 breg2[2][4];
    #pragma unroll
    for (int t = 0; t < 2; ++t)
        #pragma unroll
        for (int kk = 0; kk < 4; ++kk)
            breg2[t][kk] = *(const bf16x8*)(whi2 + ((size_t)((w * 2 + t) * 4 + kk) * 64 + l) * 8);
    f32x4 acc2[4][2];
    #pragma unroll
    for (int mi = 0; mi < 4; ++mi) { acc2[mi][0] = (f32x4){0.f,0.f,0.f,0.f}; acc2[mi][1] = (f32x4){0.f,0.f,0.f,0.f}; }
    auto pass2 = [&](const short* AS) {
        #pragma unroll
        for (int kk = 0; kk < 4; ++kk) {
            bf16x8 a[4];
            #pragma unroll
            for (int mi = 0; mi < 4; ++mi) a[mi] = *(const bf16x8*)&AS[((mi * 4 + kk) * 64 + l) * 8];
            #pragma unroll
            for (int mi = 0; mi < 4; ++mi) {
                acc2[mi][0] = __builtin_amdgcn_mfma_f32_16x16x32_bf16(a[mi], breg2[0][kk], acc2[mi][0], 0, 0, 0);
                acc2[mi][1] = __builtin_amdgcn_mfma_f32_16x16x32_bf16(a[mi], breg2[1][kk], acc2[mi][1], 0, 0, 0);
            }
        }
    };
    pass2(Ah);
    pass2(Alo);
    #pragma unroll
    for (int t = 0; t < 2; ++t)
        #pragma unroll
        for (int kk = 0; kk < 4; ++kk)
            breg2[t][kk] = *(const bf16x8*)(wlo2 + ((size_t)((w * 2 + t) * 4 + kk) * 64 + l) * 8);
    pass2(Ah);
    const int g = l >> 4, r = l & 15, wn0 = w * 32;
    const float gbv0 = gldf(gb, wn0 + r, det);
    const float gbv1 = gldf(gb, wn0 + 16 + r, det);
    const float w2v0 = gldf(w2, wn0 + r, det);
    const float w2v1 = gldf(w2, wn0 + 16 + r, det);
    #pragma unroll
    for (int mi = 0; mi < 4; ++mi)
        #pragma unroll
        for (int j = 0; j < 4; ++j) {
            int row = base + mi * 16 + 4 * g + j;
            int b = row / T_;
            float gv0 = (row < nrows) ? g2[(size_t)b * 128 + wn0 + r]      : 0.f;
            float gv1 = (row < nrows) ? g2[(size_t)b * 128 + wn0 + 16 + r] : 0.f;
            float v0 = sigm(acc2[mi][0][j] + gbv0 + gv0);
            float v1 = sigm(acc2[mi][1][j] + gbv1 + gv1);
            float pl = v0 * w2v0 + v1 * w2v1;
            #pragma unroll
            for (int m2 = 1; m2 < 16; m2 <<= 1) pl += __shfl_xor(pl, m2, 64);
            if (r == 0) part[w][mi * 16 + 4 * g + j] = pl;
        }
    __syncthreads();
    if (tid < 64) {
        int n2 = base + tid;
        if (n2 < nrows) {
            float s = part[0][tid] + part[1][tid] + part[2][tid] + part[3][tid];
            beta[n2] = s * (float)mask[n2];
        }
    }
}

// ================= tiled GEMM kernels (VALU fallback, only launched when !mf) =================
__global__ __launch_bounds__(512) void t_hi0(
    const void* __restrict__ item, const void* __restrict__ cate,
    const int* __restrict__ iid, const int* __restrict__ icate,
    const void* __restrict__ Wp, const int* __restrict__ fl,
    float* __restrict__ out, int nrows)
{
    __shared__ float Ws[8192];
    __shared__ float hrow[16][256];
    const int det = *fl;
    const int tid = threadIdx.x, c = tid & 31, slot = tid >> 5;
    for (int base = blockIdx.x * 16; base < nrows; base += gridDim.x * 16) {
        const int n = base + slot;
        if (n < nrows) {
            const int it = iid[n], ct = icate[n];
            for (int j = c; j < 128; j += 32) {
                hrow[slot][j]       = gldf(item, (size_t)it * 128 + j, det);
                hrow[slot][128 + j] = gldf(cate, (size_t)ct * 128 + j, det);
            }
        }
        float4 acc = make_float4(0.f, 0.f, 0.f, 0.f);
        for (int kb = 0; kb < 256; kb += 64) {
            __syncthreads();
            for (int i = tid; i < 8192; i += 512) Ws[i] = gldf(Wp, (size_t)kb * 128 + i, det);
            __syncthreads();
            if (n < nrows) {
                #pragma unroll 8
                for (int k = 0; k < 64; ++k) {
                    float hv = hrow[slot][kb + k];
                    float4 w = *(const float4*)&Ws[k * 128 + c * 4];
                    acc.x += hv * w.x; acc.y += hv * w.y; acc.z += hv * w.z; acc.w += hv * w.w;
                }
            }
        }
        if (n < nrows) *(float4*)&out[(size_t)n * 128 + c * 4] = acc;
        __syncthreads();
    }
}

__global__ __launch_bounds__(256) void s_hc0(
    const void* __restrict__ cate, const int* __restrict__ cid,
    const int* __restrict__ fl, float* __restrict__ out)
{
    long i = (long)blockIdx.x * 256 + threadIdx.x;
    if (i >= (long)NC_ * 128) return;
    out[i] = gldf(cate, (size_t)cid[i >> 7] * 128 + (i & 127), *fl);
}

__global__ __launch_bounds__(256) void s_initacc(
    const float* __restrict__ h, const void* __restrict__ gb, int b0off, int b1off,
    const int* __restrict__ fl, float* __restrict__ acc, long total)
{
    long i = (long)blockIdx.x * 256 + threadIdx.x;
    if (i >= total) return;
    const int det = *fl, d = (int)(i & 127);
    acc[i] = 2.f * h[i] + gldf(gb, b0off + d, det) + gldf(gb, b1off + d, det);
}

__global__ __launch_bounds__(512) void t_zgemm(
    const float* __restrict__ h, int nrows,
    const void* __restrict__ W, int woff,
    const void* __restrict__ al, int aloff,
    const void* __restrict__ ar, int aroff,
    const int* __restrict__ fl,
    __half* __restrict__ z, float* __restrict__ sl, float* __restrict__ sr)
{
    __shared__ float Ws[8192];
    __shared__ float hrow[16][128];
    const int det = *fl;
    const int tid = threadIdx.x, c = tid & 31, slot = tid >> 5;
    float4 alv, arv;
    alv.x = gldf(al, (size_t)aloff + c * 4 + 0, det); alv.y = gldf(al, (size_t)aloff + c * 4 + 1, det);
    alv.z = gldf(al, (size_t)aloff + c * 4 + 2, det); alv.w = gldf(al, (size_t)aloff + c * 4 + 3, det);
    arv.x = gldf(ar, (size_t)aroff + c * 4 + 0, det); arv.y = gldf(ar, (size_t)aroff + c * 4 + 1, det);
    arv.z = gldf(ar, (size_t)aroff + c * 4 + 2, det); arv.w = gldf(ar, (size_t)aroff + c * 4 + 3, det);
    for (int base = blockIdx.x * 16; base < nrows; base += gridDim.x * 16) {
        const int n = base + slot;
        if (n < nrows) for (int j = c; j < 128; j += 32) hrow[slot][j] = h[(size_t)n * 128 + j];
        float4 acc = make_float4(0.f, 0.f, 0.f, 0.f);
        for (int kb = 0; kb < 128; kb += 64) {
            __syncthreads();
            for (int i = tid; i < 8192; i += 512) Ws[i] = gldf(W, (size_t)woff + (size_t)kb * 128 + i, det);
            __syncthreads();
            if (n < nrows) {
                #pragma unroll 8
                for (int k = 0; k < 64; ++k) {
                    float hv = hrow[slot][kb + k];
                    float4 w = *(const float4*)&Ws[k * 128 + c * 4];
                    acc.x += hv * w.x; acc.y += hv * w.y; acc.z += hv * w.z; acc.w += hv * w.w;
                }
            }
        }
        if (n < nrows) {
            z[(size_t)n * 128 + c * 4 + 0] = __float2half_rn(acc.x);
            z[(size_t)n * 128 + c * 4 + 1] = __float2half_rn(acc.y);
            z[(size_t)n * 128 + c * 4 + 2] = __float2half_rn(acc.z);
            z[(size_t)n * 128 + c * 4 + 3] = __float2half_rn(acc.w);
            float pl = acc.x * alv.x + acc.y * alv.y + acc.z * alv.z + acc.w * alv.w;
            float pr = acc.x * arv.x + acc.y * arv.y + acc.z * arv.z + acc.w * arv.w;
            #pragma unroll
            for (int off = 16; off > 0; off >>= 1) {
                pl += __shfl_down(pl, off, 32);
                pr += __shfl_down(pr, off, 32);
            }
            if (c == 0) { sl[n] = pl; sr[n] = pr; }
        }
        __syncthreads();
    }
}

// -------- fallback atomic path --------
__global__ __launch_bounds__(256) void s_dinit(float* __restrict__ den, int n)
{
    int i = blockIdx.x * 256 + threadIdx.x;
    if (i < n) den[i] = 0.f;
}
__global__ __launch_bounds__(256) void s_edge(
    const float* __restrict__ sl, const float* __restrict__ sr,
    const int* __restrict__ src, const int* __restrict__ dst,
    float* __restrict__ e, float* __restrict__ den, int E)
{
    int j = blockIdx.x * 256 + threadIdx.x;
    if (j >= E) return;
    float ee = expf(lrelu_c(sl[src[j]] + sr[dst[j]]));
    e[j] = ee;
    atomicAdd(&den[dst[j]], ee);
}
__global__ __launch_bounds__(256) void s_scatter(
    const float* __restrict__ e, const float* __restrict__ den,
    const int* __restrict__ src, const int* __restrict__ dst,
    const __half* __restrict__ z, float* __restrict__ acc, int E)
{
    long i = (long)blockIdx.x * 256 + threadIdx.x;
    if (i >= (long)E * 128) return;
    int j = (int)(i >> 7), d = (int)(i & 127);
    int dj = dst[j];
    atomicAdd(&acc[(size_t)dj * 128 + d], (e[j] / den[dj]) * __half2float(z[(size_t)src[j] * 128 + d]));
}

__global__ __launch_bounds__(512) void t_gatefeat(
    const float* __restrict__ h0, const float* __restrict__ h1,
    const void* __restrict__ W, const void* __restrict__ bias,
    const int* __restrict__ fl,
    float* __restrict__ feat, int nrows)
{
    __shared__ float Ws[8192];
    __shared__ float hrow[16][256];
    const int det = *fl;
    const int tid = threadIdx.x, c = tid & 31, slot = tid >> 5;
    float4 bv;
    bv.x = gldf(bias, c * 4 + 0, det); bv.y = gldf(bias, c * 4 + 1, det);
    bv.z = gldf(bias, c * 4 + 2, det); bv.w = gldf(bias, c * 4 + 3, det);
    for (int base = blockIdx.x * 16; base < nrows; base += gridDim.x * 16) {
        const int n = base + slot;
        if (n < nrows) {
            for (int j = c; j < 128; j += 32) {
                hrow[slot][j]       = h0[(size_t)n * 128 + j];
                hrow[slot][128 + j] = h1[(size_t)n * 128 + j];
            }
        }
        float4 acc = make_float4(0.f, 0.f, 0.f, 0.f);
        for (int kb = 0; kb < 256; kb += 64) {
            __syncthreads();
            for (int i = tid; i < 8192; i += 512) Ws[i] = gldf(W, (size_t)kb * 128 + i, det);
            __syncthreads();
            if (n < nrows) {
                #pragma unroll 8
                for (int k = 0; k < 64; ++k) {
                    float hv = hrow[slot][kb + k];
                    float4 w = *(const float4*)&Ws[k * 128 + c * 4];
                    acc.x += hv * w.x; acc.y += hv * w.y; acc.z += hv * w.z; acc.w += hv * w.w;
                }
            }
        }
        if (n < nrows) {
            float4 a = *(const float4*)&hrow[slot][c * 4];
            float4 b = *(const float4*)&hrow[slot][128 + c * 4];
            float gx = sigm(acc.x + bv.x), gy = sigm(acc.y + bv.y);
            float gz = sigm(acc.z + bv.z), gw = sigm(acc.w + bv.w);
            float4 o;
            o.x = gx * a.x + (1.f - gx) * b.x;
            o.y = gy * a.y + (1.f - gy) * b.y;
            o.z = gz * a.z + (1.f - gz) * b.z;
            o.w = gw * a.w + (1.f - gw) * b.w;
            *(float4*)&feat[(size_t)n * 128 + c * 4] = o;
        }
        __syncthreads();
    }
}

// fused attn: build hall0 rows + hs->softmax->hsv->LN1 + linout + glu2 (per batch row)
__global__ __launch_bounds__(128) void t_attn12(
    const void* __restrict__ item, const int* __restrict__ seq,
    const int* __restrict__ alias, const int* __restrict__ maskp,
    const float* __restrict__ feat, const void* __restrict__ xs,
    const void* __restrict__ q,
    const void* __restrict__ g, const void* __restrict__ bb,
    const void* __restrict__ lw, const void* __restrict__ lb,
    const void* __restrict__ gw, const int* __restrict__ fl,
    float* __restrict__ hall0, float* __restrict__ g2)
{
    __shared__ float hl[T_][129];
    __shared__ float qs[128];
    __shared__ float hs_s[T_];
    __shared__ float red[128];
    __shared__ float h1s[128];
    __shared__ float h2[128];
    const int b = blockIdx.x, tid = threadIdx.x;
    const int det = *fl;
    const float x = gldf(xs, 0, det);
    qs[tid] = gldf(q, tid, det);
    for (int t = 0; t < T_; ++t) {
        int bt = b * T_ + t;
        float v = gldf(item, (size_t)seq[bt] * 128 + tid, det) * x
                + feat[(size_t)alias[bt] * 128 + tid] * (float)maskp[bt];
        hl[t][tid] = v;
        hall0[(size_t)bt * 128 + tid] = v;
    }
    __syncthreads();
    if (tid < T_) {
        float a = 0.f;
        for (int d = 0; d < 128; ++d) a += hl[tid][d] * qs[d];
        hs_s[tid] = a;
    }
    __syncthreads();
    float mx = -1e30f;
    for (int t = 0; t < T_; ++t) mx = fmaxf(mx, hs_s[t]);
    float ssum = 0.f;
    for (int t = 0; t < T_; ++t) ssum += expf(hs_s[t] - mx);
    float inv = 1.f / ssum;
    __syncthreads();
    if (tid < T_)
        hs_s[tid] = expf(hs_s[tid] - mx) * inv * (float)maskp[b * T_ + tid];
    __syncthreads();
    float a = 0.f;
    for (int t = 0; t < T_; ++t) a += hs_s[t] * hl[t][tid];
    red[tid] = a; __syncthreads();
    for (int o = 64; o > 0; o >>= 1) { if (tid < o) red[tid] += red[tid + o]; __syncthreads(); }
    float mu = red[0] * (1.f / 128.f);
    __syncthreads();
    float dv = a - mu;
    red[tid] = dv * dv; __syncthreads();
    for (int o = 64; o > 0; o >>= 1) { if (tid < o) red[tid] += red[tid + o]; __syncthreads(); }
    float rs = 1.f / sqrtf(red[0] * (1.f / 128.f) + 1e-8f);
    h1s[tid] = dv * rs * gldf(g, tid, det) + gldf(bb, tid, det);
    __syncthreads();
    float a2 = gldf(lb, tid, det);
    for (int k = 0; k < 128; ++k)
        a2 += h1s[k] * gldf(lw, (size_t)k * 128 + tid, det);
    for (int k = 0; k < 128; ++k)
        a2 += hl[0][k] * gldf(lw, (size_t)(128 + k) * 128 + tid, det);
    h2[tid] = a2;
    __syncthreads();
    float g2v = 0.f;
    for (int k = 0; k < 128; ++k)
        g2v += h2[k] * gldf(gw, (size_t)k * 128 + tid, det);
    g2[(size_t)b * 128 + tid] = g2v;
}

__global__ __launch_bounds__(512) void t_nh(
    const void* __restrict__ pos, const float* __restrict__ hall0,
    const void* __restrict__ W, const int* __restrict__ fl,
    float* __restrict__ nh, int nrows)
{
    __shared__ float Ws[8192];
    __shared__ float hrow[16][256];
    const int det = *fl;
    const int tid = threadIdx.x, c = tid & 31, slot = tid >> 5;
    for (int base = blockIdx.x * 16; base < nrows; base += gridDim.x * 16) {
        const int n = base + slot;
        if (n < nrows) {
            const int t = n - (n / T_) * T_;
            for (int j = c; j < 128; j += 32) {
                hrow[slot][j]       = gldf(pos, (size_t)t * 128 + j, det);
                hrow[slot][128 + j] = hall0[(size_t)n * 128 + j];
            }
        }
        float4 acc = make_float4(0.f, 0.f, 0.f, 0.f);
        for (int kb = 0; kb < 256; kb += 64) {
            __syncthreads();
            for (int i = tid; i < 8192; i += 512) Ws[i] = gldf(W, (size_t)kb * 128 + i, det);
            __syncthreads();
            if (n < nrows) {
                #pragma unroll 8
                for (int k = 0; k < 64; ++k) {
                    float hv = hrow[slot][kb + k];
                    float4 w = *(const float4*)&Ws[k * 128 + c * 4];
                    acc.x += hv * w.x; acc.y += hv * w.y; acc.z += hv * w.z; acc.w += hv * w.w;
                }
            }
        }
        if (n < nrows) {
            float4 o;
            o.x = tanhf(acc.x); o.y = tanhf(acc.y); o.z = tanhf(acc.z); o.w = tanhf(acc.w);
            *(float4*)&nh[(size_t)n * 128 + c * 4] = o;
        }
        __syncthreads();
    }
}

__global__ __launch_bounds__(512) void t_glu_beta(
    const float* __restrict__ nh, const void* __restrict__ W, const void* __restrict__ gb,
    const float* __restrict__ g2, const void* __restrict__ w2, const int* __restrict__ mask,
    const int* __restrict__ fl, float* __restrict__ beta, int nrows)
{
    __shared__ float Ws[8192];
    __shared__ float hrow[16][128];
    const int det = *fl;
    const int tid = threadIdx.x, c = tid & 31, slot = tid >> 5;
    float4 gbv, w2v;
    gbv.x = gldf(gb, c * 4 + 0, det); gbv.y = gldf(gb, c * 4 + 1, det);
    gbv.z = gldf(gb, c * 4 + 2, det); gbv.w = gldf(gb, c * 4 + 3, det);
    w2v.x = gldf(w2, c * 4 + 0, det); w2v.y = gldf(w2, c * 4 + 1, det);
    w2v.z = gldf(w2, c * 4 + 2, det); w2v.w = gldf(w2, c * 4 + 3, det);
    for (int base = blockIdx.x * 16; base < nrows; base += gridDim.x * 16) {
        const int n = base + slot;
        if (n < nrows) for (int j = c; j < 128; j += 32) hrow[slot][j] = nh[(size_t)n * 128 + j];
        float4 acc = make_float4(0.f, 0.f, 0.f, 0.f);
        for (int kb = 0; kb < 128; kb += 64) {
            __syncthreads();
            for (int i = tid; i < 8192; i += 512) Ws[i] = gldf(W, (size_t)kb * 128 + i, det);
            __syncthreads();
            if (n < nrows) {
                #pragma unroll 8
                for (int k = 0; k < 64; ++k) {
                    float hv = hrow[slot][kb + k];
                    float4 w = *(const float4*)&Ws[k * 128 + c * 4];
                    acc.x += hv * w.x; acc.y += hv * w.y; acc.z += hv * w.z; acc.w += hv * w.w;
                }
            }
        }
        if (n < nrows) {
            const int b = n / T_;
            float4 gv = *(const float4*)&g2[(size_t)b * 128 + c * 4];
            float vx = sigm(acc.x + gbv.x + gv.x);
            float vy = sigm(acc.y + gbv.y + gv.y);
            float vz = sigm(acc.z + gbv.z + gv.z);
            float vw = sigm(acc.w + gbv.w + gv.w);
            float part = vx * w2v.x + vy * w2v.y + vz * w2v.z + vw * w2v.w;
            #pragma unroll
            for (int off = 16; off > 0; off >>= 1) part += __shfl_down(part, off, 32);
            if (c == 0) beta[n] = part * (float)mask[n];
        }
        __syncthreads();
    }
}

__global__ __launch_bounds__(128) void t_sel(
    const float* __restrict__ hall0, const float* __restrict__ beta,
    const void* __restrict__ g2, const void* __restrict__ b2,
    const float* __restrict__ feat, const int* __restrict__ lasti,
    const void* __restrict__ ys, const int* __restrict__ fl,
    float* __restrict__ hallf, float* __restrict__ fenmu, float* __restrict__ outh)
{
    __shared__ float bet[T_];
    __shared__ float red[128];
    const int b = blockIdx.x, tid = threadIdx.x;
    const int det = *fl;
    if (tid < T_) bet[tid] = beta[b * T_ + tid];
    __syncthreads();
    float acc = 0.f;
    for (int t = 0; t < T_; ++t) acc += bet[t] * hall0[((size_t)b * T_ + t) * 128 + tid];
    red[tid] = acc; __syncthreads();
    for (int off = 64; off > 0; off >>= 1) { if (tid < off) red[tid] += red[tid + off]; __syncthreads(); }
    float mu = red[0] * (1.f / 128.f);
    __syncthreads();
    float dv = acc - mu;
    red[tid] = dv * dv; __syncthreads();
    for (int off = 64; off > 0; off >>= 1) { if (tid < off) red[tid] += red[tid + off]; __syncthreads(); }
    float rs = 1.f / sqrtf(red[0] * (1.f / 128.f) + 1e-8f);
    __syncthreads();
    float h = dv * rs * gldf(g2, tid, det) + gldf(b2, tid, det)
            + feat[(size_t)lasti[b] * 128 + tid] * gldf(ys, 0, det);
    hallf[(size_t)b * 128 + tid] = h;
    outh[(size_t)b * 128 + tid] = h;
    red[tid] = h * h; __syncthreads();
    for (int off = 64; off > 0; off >>= 1) { if (tid < off) red[tid] += red[tid + off]; __syncthreads(); }
    if (tid == 0) fenmu[b] = sqrtf(red[0] + 128.f * 1e-6f);
}

__global__ __launch_bounds__(256) void t_cos(
    const float* __restrict__ hallf, const float* __restrict__ fenmu, float* __restrict__ out)
{
    __shared__ float hi[128];
    const int i = blockIdx.x, tid = threadIdx.x;
    if (tid < 128) hi[tid] = hallf[(size_t)i * 128 + tid];
    __syncthreads();
    const float fi = fenmu[i];
    for (int j = tid; j < B_; j += 256) {
        const float* hj = &hallf[(size_t)j * 128];
        float s = 0.f;
        for (int d = 0; d < 128; d += 4) {
            float4 a = *(const float4*)&hi[d];
            float4 bb = *(const float4*)&hj[d];
            s += a.x * bb.x + a.y * bb.y + a.z * bb.z + a.w * bb.w;
        }
        out[(size_t)i * B_ + j] = s / (fi * fenmu[j]);
    }
}

extern "C" void kernel_launch(void* const* d_in, const int* in_sizes, int n_in,
                              void* d_out, int out_size, void* d_ws, size_t ws_size,
                              hipStream_t stream)
{
    float* outf = (float*)d_out;
    const long OUT_N = (long)B_ * 128 + (long)B_ * B_;

    static const int EXP_SZ[41] = {
        12800000, 1280000, 25600, 32768, 131072, 1024, 1024, 1024, 32768, 128,
        32768, 128, 128, 32768, 128, 32768, 128, 16384, 128, 16384,
        128, 128, 128, 128, 1, 1, 100000, 100000, 10000, 800000,
        800000, 100000, 100000, 400000, 400000, 400000, 400000, 25600, 25600, 25600, 512 };
    float code = 0.f;
    if (n_in != 41) code = 90000.f + (float)n_in;
    else {
        for (int i = 0; i < 41; ++i)
            if (in_sizes[i] != EXP_SZ[i]) { code = 10000.f * (float)(i + 1); break; }
    }
    if (code == 0.f && out_size != (int)OUT_N) code = 95000.f;
    if (code != 0.f) {
        s_sig<<<dim3((unsigned)((OUT_N + 255) / 256)), dim3(256), 0, stream>>>(outf, OUT_N, code);
        return;
    }

    const void* item_emb = d_in[0];
    const void* cate_emb = d_in[1];
    const void* pos_emb  = d_in[2];
    const void* W_pos    = d_in[3];
    const void* gat_W    = d_in[4];
    const void* gat_al   = d_in[5];
    const void* gat_ar   = d_in[6];
    const void* gat_b    = d_in[7];
    const void* Wg1_w    = d_in[8];
    const void* Wg1_b    = d_in[9];
    const void* q        = d_in[12];
    const void* lin_w    = d_in[13];
    const void* lin_b    = d_in[14];
    const void* w_1      = d_in[15];
    const void* w_2      = d_in[16];
    const void* glu1_w   = d_in[17];
    const void* glu1_b   = d_in[18];
    const void* glu2_w   = d_in[19];
    const void* ln1_g    = d_in[20];
    const void* ln1_b    = d_in[21];
    const void* ln2_g    = d_in[22];
    const void* ln2_b    = d_in[23];
    const void* x_s      = d_in[24];
    const void* y_s      = d_in[25];
    const int* iid    = (const int*)d_in[26];
    const int* icate  = (const int*)d_in[27];
    const int* cid    = (const int*)d_in[28];
    const int* src_ii = (const int*)d_in[29];
    const int* dst_ii = (const int*)d_in[30];
    const int* src_cc = (const int*)d_in[31];
    const int* dst_cc = (const int*)d_in[32];
    const int* src_ci = (const int*)d_in[33];
    const int* dst_ci = (const int*)d_in[34];
    const int* src_ic = (const int*)d_in[35];
    const int* dst_ic = (const int*)d_in[36];
    const int* alias  = (const int*)d_in[37];
    const int* seq    = (const int*)d_in[38];
    const int* mask   = (const int*)d_in[39];
    const int* lasti  = (const int*)d_in[40];

    const size_t NEED_BASE = 64 + ((size_t)4 * NI_ + 3 * NC_) * 128 * 4
                                + ((size_t)3 * NI_ + 2 * NC_ + EII_) * 4;
    const size_t CSR_EXTRA = ((size_t)2 * (NI_ + 1) + 2 * (NC_ + 1)
                                + ECI_ + ECC_ + EIC_ + NI_) * 4;
    const size_t NEED_CSR = NEED_BASE + CSR_EXTRA;
    if (ws_size < NEED_BASE) {
        s_sig<<<dim3((unsigned)((OUT_N + 255) / 256)), dim3(256), 0, stream>>>(outf, OUT_N, 80000.f);
        return;
    }
    const bool useCSR = (ws_size >= NEED_CSR);
    const int mf = useCSR ? 1 : 0;

    int* flagp = (int*)d_ws;
    char* basep = (char*)d_ws;
    size_t off = 64;
    auto AL = [&](size_t nfl) { float* p = (float*)(basep + off); off += nfl * 4; return p; };
    float* hi0 = AL((size_t)NI_ * 128);
    float* HiA = AL((size_t)NI_ * 128);
    float* HiB = AL((size_t)NI_ * 128);   // binned edges during build | score scratch | L1 acc
    float* zA  = AL((size_t)NI_ * 128);   // two fp16 z's | feat fp32 later
    float* hc0 = AL((size_t)NC_ * 128);
    float* HcA = AL((size_t)NC_ * 128);
    float* zC  = AL((size_t)NC_ * 128);   // two fp16 z's
    float* sAl = AL(NI_); float* sAr = AL(NI_);
    float* sCl = AL(NC_); float* sCr = AL(NC_);
    float* denF = AL(NI_);          // fallback den | CSR: bcnt/bstart/gcur/wars, wt_lo@17408
    float* eF   = AL(EII_);         // fallback e   | CSR: colsrc_ii
    int* rpII = (int*)AL(NI_ + 1);
    int* rpCI = (int*)AL(NI_ + 1);
    int* rpCC = (int*)AL(NC_ + 1);
    int* rpIC = (int*)AL(NC_ + 1);
    int* csCI = (int*)AL(ECI_);
    int* csCC = (int*)AL(ECC_);
    int* csIC = (int*)AL(EIC_);
    int* wtregion = (int*)AL(NI_);  // wt_hi (320 KB)
    int* csII = (int*)eF;
    int* denFi = (int*)denF;
    int* bcnt   = denFi;                            // [0,432)
    int* bstart = denFi + 512;                      // [512,944)
    int* gcur   = denFi + 1024;                     // [1024,1456)
    float* wars = denF + 2048;                      // [2048,2432)
    u16* wt_hi = (u16*)wtregion;                    // 20480 slots * 16 B
    u16* wt_lo = (u16*)((char*)denF + 17408);
    __half* zAh  = (__half*)zA;
    __half* zA2h = zAh + (size_t)NI_ * 128;
    __half* zCh  = (__half*)zC;
    __half* zC2h = zCh + (size_t)NC_ * 128;
    // binned edge arrays (build-time) live in HiB
    u32* binII = (u32*)HiB;
    u32* binCI = binII + EII_;
    u32* binCC = binCI + ECI_;
    u32* binIC = binCC + ECC_;
    // layer-0 score scratch (after build) also in HiB
    float* sl03p = HiB;
    float* sr03s = HiB + NI_;
    float* sl02p = HiB + 2 * (size_t)NI_;
    float* sr02s = sl02p + NC_;
    // attention-phase packed weights (w_1 + glu1_w = 6144 slots) live in dead HiA
    u16* wt2_hi = (u16*)HiA;
    u16* wt2_lo = wt2_hi + (size_t)6144 * 8;

    auto WTS = [&](int l, int k) {                  // slot base (u16 units) for gat_W (l,k)
        int midx = (l == 0) ? k : ((k == 0) ? 4 : 5);
        return (size_t)(8192 + midx * 2048) * 8;
    };

    float* feat = zA;
    float* hall0 = hi0;
    float* nh    = hall0 + (size_t)B_ * T_ * 128;
    float* vbuf  = nh    + (size_t)B_ * T_ * 128;
    float* hsb   = vbuf  + (size_t)B_ * T_ * 128;
    float* hsv   = hsb   + (size_t)B_ * T_;
    float* hsvn  = hsv   + (size_t)B_ * 128;
    float* hsv2  = hsvn  + (size_t)B_ * 128;
    float* g2b   = hsv2  + (size_t)B_ * 128;
    float* betab = g2b   + (size_t)B_ * 128;
    float* hallf = betab + (size_t)B_ * T_;
    float* fenmu = hallf + (size_t)B_ * 128;

    #define GRL(n) dim3((unsigned)(((long)(n) + 255) / 256))
    auto WOFF = [](int l, int k) { return (l * 4 + k) * 16384; };
    auto VOFF = [](int l, int k) { return (l * 4 + k) * 128; };

    auto seg = [&](const float* sl, const float* sr, const int* s, const int* d,
                   int E, int ndst, const __half* z, float* acc) {
        s_dinit<<<GRL(ndst), dim3(256), 0, stream>>>(denF, ndst);
        s_edge<<<GRL(E), dim3(256), 0, stream>>>(sl, sr, s, d, eF, denF, E);
        s_scatter<<<GRL((long)E * 128), dim3(256), 0, stream>>>(eF, denF, s, d, z, acc, E);
    };

    k_init<<<dim3(1), dim3(128), 0, stream>>>(item_emb, flagp, bcnt);

    if (useCSR) {
        const int ET = EII_ + ECI_ + ECC_ + EIC_;
        const int NBA = (ET + ECH_ - 1) / ECH_;
        k_pre<<<dim3(5083 + NBA), dim3(256), 0, stream>>>(
            cate_emb, cid, hc0,
            W_pos, Wg1_w, gat_W, wt_hi, wt_lo, gat_ar, wars,
            dst_ii, dst_ci, dst_cc, dst_ic, bcnt, flagp);
        k_bscan<<<dim3(1), dim3(1), 0, stream>>>(bcnt, bstart, gcur);
        k_binA<<<dim3(NBA), dim3(256), 0, stream>>>(
            src_ii, dst_ii, src_ci, dst_ci, src_cc, dst_cc, src_ic, dst_ic,
            gcur, binII, binCI, binCC, binIC);
        k_binB<<<dim3(NBK_), dim3(512), 0, stream>>>(
            bstart, bcnt, binII, binCI, binCC, binIC,
            rpII, rpCI, rpCC, rpIC, csII, csCI, csCC, csIC);
        m_hi0<<<dim3((NI_ + 63) / 64), dim3(256), 0, stream>>>(
            item_emb, cate_emb, iid, icate, wt_hi, wt_lo, flagp, flagp + 1, hi0, NI_);
        // ---- layer 0 z-gemms (dual-weight)
        m_zgemm2<<<dim3((NI_ + 63) / 64), dim3(256), 0, stream>>>(
            hi0, NI_,
            wt_hi + WTS(0, 0), wt_lo + WTS(0, 0), VOFF(0, 0), VOFF(0, 0), zAh,  sAl,   sAr,
            wt_hi + WTS(0, 3), wt_lo + WTS(0, 3), VOFF(0, 3), VOFF(0, 3), zA2h, sl03p, sr03s,
            gat_al, gat_ar, flagp, flagp + 1);
        m_zgemm2<<<dim3((NC_ + 63) / 64), dim3(256), 0, stream>>>(
            hc0, NC_,
            wt_hi + WTS(0, 1), wt_lo + WTS(0, 1), VOFF(0, 1), VOFF(0, 1), zC2h, sCl,   sCr,
            wt_hi + WTS(0, 2), wt_lo + WTS(0, 2), VOFF(0, 2), VOFF(0, 2), zCh,  sl02p, sr02s,
            gat_al, gat_ar, flagp, flagp + 1);
        // ---- layer 0 aggs
        t_gat_fused<<<dim3((NI_ + 3) / 4), dim3(256), 0, stream>>>(
            rpII, csII, sAl, sAr, (const __half2*)zAh,
            rpCI, csCI, sl02p, wars + 0, (const __half2*)zCh,
            hi0, gat_b, VOFF(0, 0), VOFF(0, 2), flagp, HiA, NI_);
        t_gat_fused<<<dim3((NC_ + 3) / 4), dim3(256), 0, stream>>>(
            rpCC, csCC, sCl, sCr, (const __half2*)zC2h,
            rpIC, csIC, sl03p, wars + 128, (const __half2*)zA2h,
            hc0, gat_b, VOFF(0, 1), VOFF(0, 3), flagp, HcA, NC_);
        // ---- layer 1
        m_zgemm<<<dim3((NI_ + 63) / 64), dim3(256), 0, stream>>>(
            HiA, NI_, wt_hi + WTS(1, 0), wt_lo + WTS(1, 0),
            gat_al, VOFF(1, 0), gat_ar, VOFF(1, 0), flagp, flagp + 1, zAh, sAl, sAr);
        m_zgemm<<<dim3((NC_ + 63) / 64), dim3(256), 0, stream>>>(
            HcA, NC_, wt_hi + WTS(1, 2), wt_lo + WTS(1, 2),
            gat_al, VOFF(1, 2), gat_ar, VOFF(1, 2), flagp, flagp + 1, zCh, sCl, sCr);
        t_gat_fused<<<dim3((NI_ + 3) / 4), dim3(256), 0, stream>>>(
            rpII, csII, sAl, sAr, (const __half2*)zAh,
            rpCI, csCI, sCl, wars + 256, (const __half2*)zCh,
            HiA, gat_b, VOFF(1, 0), VOFF(1, 2), flagp, HiB, NI_);
        // HiA now dead: pack attention-phase weights into it
        k_prepw3<<<dim3(24), dim3(256), 0, stream>>>(w_1, glu1_w, flagp, wt2_hi, wt2_lo);
        m_gatefeat<<<dim3((NI_ + 63) / 64), dim3(256), 0, stream>>>(
            hi0, HiB, wt_hi + (size_t)4096 * 8, wt_lo + (size_t)4096 * 8, Wg1_b, flagp, flagp + 1, feat, NI_);
    } else {
        s_hc0<<<GRL((long)NC_ * 128), dim3(256), 0, stream>>>(cate_emb, cid, flagp, hc0);
        t_hi0<<<dim3(768), dim3(512), 0, stream>>>(item_emb, cate_emb, iid, icate, W_pos, flagp, hi0, NI_);
        s_initacc<<<GRL((long)NI_ * 128), dim3(256), 0, stream>>>(hi0, gat_b, VOFF(0, 0), VOFF(0, 2), flagp, HiA, (long)NI_ * 128);
        s_initacc<<<GRL((long)NC_ * 128), dim3(256), 0, stream>>>(hc0, gat_b, VOFF(0, 1), VOFF(0, 3), flagp, HcA, (long)NC_ * 128);
        t_zgemm<<<dim3(1024), dim3(512), 0, stream>>>(hi0, NI_, gat_W, WOFF(0, 0), gat_al, VOFF(0, 0), gat_ar, VOFF(0, 0), flagp, zAh, sAl, sAr);
        seg(sAl, sAr, src_ii, dst_ii, EII_, NI_, zAh, HiA);
        t_zgemm<<<dim3(625), dim3(512), 0, stream>>>(hc0, NC_, gat_W, WOFF(0, 2), gat_al, VOFF(0, 2), gat_ar, VOFF(0, 2), flagp, zCh, sCl, sCr);
        t_zgemm<<<dim3(1024), dim3(512), 0, stream>>>(hi0, NI_, gat_W, WOFF(0, 2), gat_al, VOFF(0, 2), gat_ar, VOFF(0, 2), flagp, zAh, sAl, sAr);
        seg(sCl, sAr, src_ci, dst_ci, ECI_, NI_, zCh, HiA);
        t_zgemm<<<dim3(625), dim3(512), 0, stream>>>(hc0, NC_, gat_W, WOFF(0, 1), gat_al, VOFF(0, 1), gat_ar, VOFF(0, 1), flagp, zCh, sCl, sCr);
        seg(sCl, sCr, src_cc, dst_cc, ECC_, NC_, zCh, HcA);
        t_zgemm<<<dim3(1024), dim3(512), 0, stream>>>(hi0, NI_, gat_W, WOFF(0, 3), gat_al, VOFF(0, 3), gat_ar, VOFF(0, 3), flagp, zAh, sAl, sAr);
        t_zgemm<<<dim3(625), dim3(512), 0, stream>>>(hc0, NC_, gat_W, WOFF(0, 3), gat_al, VOFF(0, 3), gat_ar, VOFF(0, 3), flagp, zCh, sCl, sCr);
        seg(sAl, sCr, src_ic, dst_ic, EIC_, NC_, zAh, HcA);
        s_initacc<<<GRL((long)NI_ * 128), dim3(256), 0, stream>>>(HiA, gat_b, VOFF(1, 0), VOFF(1, 2), flagp, HiB, (long)NI_ * 128);
        t_zgemm<<<dim3(1024), dim3(512), 0, stream>>>(HiA, NI_, gat_W, WOFF(1, 0), gat_al, VOFF(1, 0), gat_ar, VOFF(1, 0), flagp, zAh, sAl, sAr);
        seg(sAl, sAr, src_ii, dst_ii, EII_, NI_, zAh, HiB);
        t_zgemm<<<dim3(625), dim3(512), 0, stream>>>(HcA, NC_, gat_W, WOFF(1, 2), gat_al, VOFF(1, 2), gat_ar, VOFF(1, 2), flagp, zCh, sCl, sCr);
        t_zgemm<<<dim3(1024), dim3(512), 0, stream>>>(HiA, NI_, gat_W, WOFF(1, 2), gat_al, VOFF(1, 2), gat_ar, VOFF(1, 2), flagp, zAh, sAl, sAr);
        seg(sCl, sAr, src_ci, dst_ci, ECI_, NI_, zCh, HiB);
        t_gatefeat<<<dim3(768), dim3(512), 0, stream>>>(hi0, HiB, Wg1_w, Wg1_b, flagp, feat, NI_);
    }

    t_attn12<<<dim3(B_), dim3(128), 0, stream>>>(
        item_emb, seq, alias, mask, feat, x_s, q,
        ln1_g, ln1_b, lin_w, lin_b, glu2_w, flagp, hall0, g2b);
    if (mf) {
        m_nhglu<<<dim3((B_ * T_ + 63) / 64), dim3(256), 0, stream>>>(
            pos_emb, hall0, wt2_hi, wt2_lo,
            wt2_hi + (size_t)4096 * 8, wt2_lo + (size_t)4096 * 8,
            glu1_b, g2b, w_2, mask, flagp, flagp + 1, betab, B_ * T_);
    } else {
        int grid = (B_ * T_ + 15) / 16; if (grid > 1024) grid = 1024;
        t_nh<<<dim3(grid), dim3(512), 0, stream>>>(pos_emb, hall0, w_1, flagp, nh, B_ * T_);
        t_glu_beta<<<dim3(grid), dim3(512), 0, stream>>>(nh, glu1_w, glu1_b, g2b, w_2, mask, flagp, betab, B_ * T_);
    }
    t_sel<<<dim3(B_), dim3(128), 0, stream>>>(hall0, betab, ln2_g, ln2_b, feat, lasti, y_s, flagp, hallf, fenmu, outf);
    t_cos<<<dim3(B_), dim3(256), 0, stream>>>(hallf, fenmu, outf + (size_t)B_ * 128);
}

// Round 10
// 793.576 us; speedup vs baseline: 1.2886x; 1.0847x over previous
//
#include <hip/hip_runtime.h>
#include <hip/hip_fp16.h>

typedef unsigned short u16;
typedef unsigned int u32;
typedef unsigned long long u64;
typedef __attribute__((ext_vector_type(8))) short bf16x8;   // 8 bf16 = 4 VGPRs
typedef __attribute__((ext_vector_type(4))) float f32x4;    // MFMA 16x16 accumulator

#define NI_ 100000
#define NC_ 10000
#define EII_ 800000
#define ECC_ 100000
#define ECI_ 400000
#define EIC_ 400000
#define B_ 512
#define T_ 50
#define BSH_ 9            // 512-dst buckets
#define NBII_ 196         // ceil(100000/512)
#define NBNC_ 20          // ceil(10000/512)
#define NBK_ 432          // 196 II + 196 CI + 20 CC + 20 IC
#define ECH_ 4096         // edges per binning chunk

__device__ __forceinline__ float bf2f(u16 u) { return __uint_as_float(((u32)u) << 16); }
__device__ __forceinline__ u16 f2bf(float x) {
    u32 u = __float_as_uint(x);
    return (u16)((u + 0x7FFFu + ((u >> 16) & 1u)) >> 16);   // RNE
}
__device__ __forceinline__ float sigm(float x) { return 1.f / (1.f + expf(-x)); }
__device__ __forceinline__ float gldf(const void* p, size_t i, int isf) {
    return isf ? ((const float*)p)[i] : bf2f(((const u16*)p)[i]);
}
__device__ __forceinline__ float lrelu_c(float v) {
    v = (v >= 0.f) ? v : 0.2f * v;
    return fminf(fmaxf(v, -60.f), 60.f);
}

// init: dtype detect + MFMA layout self-check + bucket-counter zero
__global__ void k_init(const void* __restrict__ item, int* __restrict__ flag,
                       int* __restrict__ bcnt)
{
    const int tid = threadIdx.x;
    for (int i = tid; i < NBK_; i += 128) bcnt[i] = 0;
    if (tid < 64) {
        const int l = tid;
        bf16x8 a, b;
        #pragma unroll
        for (int j = 0; j < 8; ++j) {
            int ka = (l >> 4) * 8 + j;
            float av = (float)((((l & 15) * 5 + ka * 3) & 15) - 7);
            float bv = (float)(((ka * 7 + (l & 15) * 11) & 15) - 8);
            a[j] = (short)f2bf(av);
            b[j] = (short)f2bf(bv);
        }
        f32x4 d = {0.f, 0.f, 0.f, 0.f};
        d = __builtin_amdgcn_mfma_f32_16x16x32_bf16(a, b, d, 0, 0, 0);
        bool ok = true;
        #pragma unroll
        for (int j = 0; j < 4; ++j) {
            int row = (l >> 4) * 4 + j, col = l & 15;
            float ref = 0.f;
            for (int k = 0; k < 32; ++k)
                ref += (float)(((row * 5 + k * 3) & 15) - 7) * (float)(((k * 7 + col * 11) & 15) - 8);
            ok = ok && (d[j] == ref);
        }
        unsigned long long vote = __ballot(ok);
        if (l == 0) flag[1] = (vote == ~0ull) ? 1 : 0;
    } else if (tid == 64) {
        const u16* p = (const u16*)item;
        int cnt = 0;
        for (int i = 0; i < 128; ++i) {
            float v = bf2f(p[i]);
            if (fabsf(v) <= 0.0886f) ++cnt;
        }
        flag[0] = (cnt >= 120) ? 0 : 1;
    }
}

__global__ void s_sig(float* __restrict__ out, long n, float code)
{
    long i = (long)blockIdx.x * 256 + threadIdx.x;
    if (i < n) out[i] = (i == 0) ? code : 0.f;
}

// ============ merged pre-pass: hc0 gather | weight pack | war vecs | bucket hist ============
__global__ __launch_bounds__(256) void k_pre(
    const void* __restrict__ cate, const int* __restrict__ cid, float* __restrict__ hc0,
    const void* __restrict__ Wp, const void* __restrict__ Wg1, const void* __restrict__ gW,
    u16* __restrict__ whi, u16* __restrict__ wlo,
    const void* __restrict__ ar, float* __restrict__ wars,
    const int* __restrict__ d0, const int* __restrict__ d1,
    const int* __restrict__ d2, const int* __restrict__ d3,
    int* __restrict__ bcnt,
    const int* __restrict__ fl)
{
    __shared__ int bl[NBK_];
    const int det = fl[0];
    int bid = blockIdx.x, tid = threadIdx.x;
    if (bid < 5000) {
        long i = (long)bid * 256 + tid;
        if (i < (long)NC_ * 128)
            hc0[i] = gldf(cate, (size_t)cid[i >> 7] * 128 + (i & 127), det);
        return;
    }
    bid -= 5000;
    if (bid < 80) {
        int s = bid * 256 + tid;
        if (s >= 20480) return;
        const void* src; int K, local; size_t soff;
        if (s < 4096)       { src = Wp;  K = 256; local = s;        soff = 0; }
        else if (s < 8192)  { src = Wg1; K = 256; local = s - 4096; soff = 0; }
        else {
            int t = s - 8192; int m = t >> 11; local = t & 2047; K = 128;
            const int MK[6] = {0, 1, 2, 3, 4, 6};
            src = gW; soff = (size_t)MK[m] * 16384;
        }
        const int KK = K >> 5;
        int r = local & 15, g = (local >> 4) & 3, q2 = local >> 6;
        int kk = q2 % KK, ni = q2 / KK;
        bf16x8 hv, lv;
        #pragma unroll
        for (int j = 0; j < 8; ++j) {
            float x = gldf(src, soff + (size_t)(kk * 32 + 8 * g + j) * 128 + ni * 16 + r, det);
            u16 hb = f2bf(x);
            hv[j] = (short)hb;
            lv[j] = (short)f2bf(x - bf2f(hb));
        }
        *(bf16x8*)(whi + (size_t)s * 8) = hv;
        *(bf16x8*)(wlo + (size_t)s * 8) = lv;
        return;
    }
    bid -= 80;
    if (bid < 3) {
        if (tid < 128) {
            const int WO[3] = {2 * 16384, 3 * 16384, 6 * 16384};
            const int AO[3] = {2 * 128, 3 * 128, 6 * 128};
            int g = bid, k = tid;
            float a = 0.f;
            for (int c = 0; c < 128; ++c)
                a += gldf(gW, (size_t)WO[g] + (size_t)k * 128 + c, det) * gldf(ar, AO[g] + c, det);
            wars[g * 128 + k] = a;
        }
        return;
    }
    bid -= 3;
    for (int i = tid; i < NBK_; i += 256) bl[i] = 0;
    __syncthreads();
    const long ET = (long)EII_ + ECI_ + ECC_ + EIC_;
    const long base = (long)bid * ECH_;
    #pragma unroll
    for (int j = 0; j < 16; ++j) {
        long i = base + j * 256 + tid;
        if (i < ET) {
            int dst, boff;
            long ii = i;
            if (ii < EII_) { dst = d0[ii]; boff = 0; }
            else { ii -= EII_;
            if (ii < ECI_) { dst = d1[ii]; boff = NBII_; }
            else { ii -= ECI_;
            if (ii < ECC_) { dst = d2[ii]; boff = 2 * NBII_; }
            else { ii -= ECC_; dst = d3[ii]; boff = 2 * NBII_ + NBNC_; } } }
            atomicAdd(&bl[boff + (dst >> BSH_)], 1);
        }
    }
    __syncthreads();
    for (int i = tid; i < NBK_; i += 256)
        if (bl[i]) atomicAdd(&bcnt[i], bl[i]);
}

// per-graph-segment scan of bucket counts -> bstart + gcur
__global__ void k_bscan(const int* __restrict__ bcnt,
                        int* __restrict__ bstart, int* __restrict__ gcur)
{
    if (threadIdx.x != 0 || blockIdx.x != 0) return;
    int run = 0;
    for (int i = 0; i < NBII_; ++i) { bstart[i] = run; gcur[i] = run; run += bcnt[i]; }
    run = 0;
    for (int i = NBII_; i < 2 * NBII_; ++i) { bstart[i] = run; gcur[i] = run; run += bcnt[i]; }
    run = 0;
    for (int i = 2 * NBII_; i < 2 * NBII_ + NBNC_; ++i) { bstart[i] = run; gcur[i] = run; run += bcnt[i]; }
    run = 0;
    for (int i = 2 * NBII_ + NBNC_; i < NBK_; ++i) { bstart[i] = run; gcur[i] = run; run += bcnt[i]; }
}

// phase A: bin edges by 512-dst bucket
__global__ __launch_bounds__(256) void k_binA(
    const int* s0, const int* d0, const int* s1, const int* d1,
    const int* s2, const int* d2, const int* s3, const int* d3,
    int* __restrict__ gcur,
    u32* __restrict__ b0, u32* __restrict__ b1,
    u32* __restrict__ b2, u32* __restrict__ b3)
{
    __shared__ u32 stag[ECH_];
    __shared__ int cnt[NBK_], base_l[NBK_ + 1], gbase[NBK_], cur_l[NBK_];
    const int tid = threadIdx.x;
    const long estart = (long)blockIdx.x * ECH_;
    const long ET = (long)EII_ + ECI_ + ECC_ + EIC_;
    for (int b = tid; b < NBK_; b += 256) cnt[b] = 0;
    __syncthreads();
    int gidv[16]; u32 pk[16];
    #pragma unroll
    for (int j = 0; j < 16; ++j) {
        long i = estart + j * 256 + tid;
        gidv[j] = -1;
        if (i < ET) {
            int src, dst, boff;
            long ii = i;
            if (ii < EII_) { src = s0[ii]; dst = d0[ii]; boff = 0; }
            else { ii -= EII_;
            if (ii < ECI_) { src = s1[ii]; dst = d1[ii]; boff = NBII_; }
            else { ii -= ECI_;
            if (ii < ECC_) { src = s2[ii]; dst = d2[ii]; boff = 2 * NBII_; }
            else { ii -= ECC_; src = s3[ii]; dst = d3[ii]; boff = 2 * NBII_ + NBNC_; } } }
            int gid = boff + (dst >> BSH_);
            gidv[j] = gid;
            pk[j] = ((u32)src << BSH_) | (u32)(dst & ((1 << BSH_) - 1));
            atomicAdd(&cnt[gid], 1);
        }
    }
    __syncthreads();
    if (tid == 0) {
        int run = 0;
        for (int b = 0; b < NBK_; ++b) { base_l[b] = run; run += cnt[b]; }
        base_l[NBK_] = run;
    }
    __syncthreads();
    for (int b = tid; b < NBK_; b += 256) {
        gbase[b] = cnt[b] ? atomicAdd(&gcur[b], cnt[b]) : 0;
        cur_l[b] = base_l[b];
    }
    __syncthreads();
    #pragma unroll
    for (int j = 0; j < 16; ++j)
        if (gidv[j] >= 0) {
            int l = atomicAdd(&cur_l[gidv[j]], 1);
            stag[l] = pk[j];
        }
    __syncthreads();
    const int total = base_l[NBK_];
    for (int t = tid; t < total; t += 256) {
        int lo = 0, hi = NBK_ - 1;
        while (lo < hi) { int mid = (lo + hi + 1) >> 1; if (base_l[mid] <= t) lo = mid; else hi = mid - 1; }
        int pos = gbase[lo] + (t - base_l[lo]);
        u32* bp = (lo < NBII_) ? b0 : (lo < 2 * NBII_) ? b1 : (lo < 2 * NBII_ + NBNC_) ? b2 : b3;
        bp[pos] = stag[t];
    }
}

// phase B: per-bucket — per-dst count, local scan -> rowptr, fine fill in small window
__global__ __launch_bounds__(512) void k_binB(
    const int* __restrict__ bstart, const int* __restrict__ bcnt,
    const u32* __restrict__ b0, const u32* __restrict__ b1,
    const u32* __restrict__ b2, const u32* __restrict__ b3,
    int* __restrict__ rpII, int* __restrict__ rpCI,
    int* __restrict__ rpCC, int* __restrict__ rpIC,
    int* __restrict__ csII, int* __restrict__ csCI,
    int* __restrict__ csCC, int* __restrict__ csIC)
{
    __shared__ int cnt[512], cur[512];
    const int gid = blockIdx.x, tid = threadIdx.x;
    int* rp; const u32* bp; int* cs; int b, n, Eg; bool last;
    if (gid < NBII_)                  { rp = rpII; bp = b0; cs = csII; b = gid;                     n = NI_; Eg = EII_; last = (gid == NBII_ - 1); }
    else if (gid < 2 * NBII_)         { rp = rpCI; bp = b1; cs = csCI; b = gid - NBII_;             n = NI_; Eg = ECI_; last = (gid == 2 * NBII_ - 1); }
    else if (gid < 2 * NBII_ + NBNC_) { rp = rpCC; bp = b2; cs = csCC; b = gid - 2 * NBII_;         n = NC_; Eg = ECC_; last = (gid == 2 * NBII_ + NBNC_ - 1); }
    else                              { rp = rpIC; bp = b3; cs = csIC; b = gid - 2 * NBII_ - NBNC_; n = NC_; Eg = EIC_; last = (gid == NBK_ - 1); }
    const int dz = b << BSH_;
    const int d1v = (dz + 512 < n) ? dz + 512 : n;
    const int ndl = d1v - dz;
    cnt[tid] = 0;
    __syncthreads();
    const int e0 = bstart[gid], e1 = e0 + bcnt[gid];
    for (int e = e0 + tid; e < e1; e += 512)
        atomicAdd(&cnt[bp[e] & 511], 1);
    __syncthreads();
    for (int s = 1; s < 512; s <<= 1) {
        int v = (tid >= s) ? cnt[tid - s] : 0;
        __syncthreads();
        cnt[tid] += v;
        __syncthreads();
    }
    const int excl = (tid == 0) ? 0 : cnt[tid - 1];
    cur[tid] = e0 + excl;
    if (tid < ndl) rp[dz + tid] = e0 + excl;
    if (last && tid == 0) rp[n] = Eg;
    __syncthreads();
    for (int e = e0 + tid; e < e1; e += 512) {
        u32 p = bp[e];
        int pos = atomicAdd(&cur[p & 511], 1);
        cs[pos] = (int)(p >> BSH_);
    }
}

// ========== GAT aggregation (fused, shuffle-cached alphas, fp16 z, 8-wide ILP) ==========
__device__ __forceinline__ void gat_gather(
    const int* __restrict__ rp, const int* __restrict__ cs,
    const float* __restrict__ sl, float srd, const __half2* __restrict__ z,
    int w, int lane, float& a0, float& a1)
{
    const int start = rp[w], end = rp[w + 1];
    if (end <= start) return;
    const int cnt = end - start;
    int   sE = 0; float eE = 0.f;
    if (lane < cnt) {
        sE = cs[start + lane];
        eE = expf(lrelu_c(sl[sE] + srd));
    }
    float local = eE;
    for (int k = start + 64 + lane; k < end; k += 64)
        local += expf(lrelu_c(sl[cs[k]] + srd));
    #pragma unroll
    for (int o = 32; o > 0; o >>= 1) local += __shfl_xor(local, o, 64);
    const float inv = 1.f / local;
    const int m = (cnt < 64) ? cnt : 64;
    int k = 0;
    for (; k + 8 <= m; k += 8) {
        int   s[8]; float lw[8]; float2 f[8];
        #pragma unroll
        for (int u = 0; u < 8; ++u) {
            s[u]  = __shfl(sE, k + u, 64);
            lw[u] = __shfl(eE, k + u, 64) * inv;
        }
        #pragma unroll
        for (int u = 0; u < 8; ++u) f[u] = __half22float2(z[(size_t)s[u] * 64 + lane]);
        #pragma unroll
        for (int u = 0; u < 8; ++u) { a0 += lw[u] * f[u].x; a1 += lw[u] * f[u].y; }
    }
    for (; k + 4 <= m; k += 4) {
        int s0 = __shfl(sE, k, 64),     s1 = __shfl(sE, k + 1, 64);
        int s2 = __shfl(sE, k + 2, 64), s3 = __shfl(sE, k + 3, 64);
        float l0 = __shfl(eE, k, 64) * inv,     l1 = __shfl(eE, k + 1, 64) * inv;
        float l2 = __shfl(eE, k + 2, 64) * inv, l3 = __shfl(eE, k + 3, 64) * inv;
        float2 f0 = __half22float2(z[(size_t)s0 * 64 + lane]);
        float2 f1 = __half22float2(z[(size_t)s1 * 64 + lane]);
        float2 f2 = __half22float2(z[(size_t)s2 * 64 + lane]);
        float2 f3 = __half22float2(z[(size_t)s3 * 64 + lane]);
        a0 += l0 * f0.x + l1 * f1.x + l2 * f2.x + l3 * f3.x;
        a1 += l0 * f0.y + l1 * f1.y + l2 * f2.y + l3 * f3.y;
    }
    for (; k < m; ++k) {
        int s = __shfl(sE, k, 64);
        float al = __shfl(eE, k, 64) * inv;
        float2 f = __half22float2(z[(size_t)s * 64 + lane]);
        a0 += al * f.x;
        a1 += al * f.y;
    }
    for (int kk = start + 64; kk < end; ++kk) {   // rare: degree > 64
        int s = cs[kk];
        float al = expf(lrelu_c(sl[s] + srd)) * inv;
        float2 f = __half22float2(z[(size_t)s * 64 + lane]);
        a0 += al * f.x;
        a1 += al * f.y;
    }
}

__device__ __forceinline__ void gat_dst(
    int w, int lane, int det,
    const int* __restrict__ rpA, const int* __restrict__ csA,
    const float* __restrict__ slA, const float* __restrict__ srA, const __half2* __restrict__ zA_,
    const int* __restrict__ rpB, const int* __restrict__ csB,
    const float* __restrict__ slB, const float* __restrict__ war, const __half2* __restrict__ zB_,
    const float* __restrict__ h0, const void* __restrict__ gb, int b0off, int b1off,
    float* __restrict__ acc)
{
    const int d0 = 2 * lane, d1 = 2 * lane + 1;
    float2 h0v = *(const float2*)(h0 + (size_t)w * 128 + d0);
    float2 wv  = *(const float2*)(war + d0);
    float srB = h0v.x * wv.x + h0v.y * wv.y;
    #pragma unroll
    for (int off = 32; off > 0; off >>= 1) srB += __shfl_xor(srB, off, 64);
    float a0 = 2.f * h0v.x + gldf(gb, b0off + d0, det) + gldf(gb, b1off + d0, det);
    float a1 = 2.f * h0v.y + gldf(gb, b0off + d1, det) + gldf(gb, b1off + d1, det);
    gat_gather(rpA, csA, slA, srA[w], zA_, w, lane, a0, a1);
    gat_gather(rpB, csB, slB, srB,    zB_, w, lane, a0, a1);
    *(float2*)(acc + (size_t)w * 128 + d0) = make_float2(a0, a1);
}

__global__ __launch_bounds__(256) void t_gat_fused(
    const int* __restrict__ rpA, const int* __restrict__ csA,
    const float* __restrict__ slA, const float* __restrict__ srA, const __half2* __restrict__ zA_,
    const int* __restrict__ rpB, const int* __restrict__ csB,
    const float* __restrict__ slB, const float* __restrict__ war, const __half2* __restrict__ zB_,
    const float* __restrict__ h0, const void* __restrict__ gb, int b0off, int b1off,
    const int* __restrict__ fl, float* __restrict__ acc, int ndst)
{
    int w = blockIdx.x * 4 + (threadIdx.x >> 6);
    int lane = threadIdx.x & 63;
    if (w >= ndst) return;
    gat_dst(w, lane, *fl, rpA, csA, slA, srA, zA_, rpB, csB, slB, war, zB_, h0, gb, b0off, b1off, acc);
}

// merged layer-0 aggregation: item-dst blocks then cate-dst blocks
__global__ __launch_bounds__(256) void t_gat2(
    const int* rpAi, const int* csAi, const float* slAi, const float* srAi, const __half2* zAi,
    const int* rpBi, const int* csBi, const float* slBi, const float* wari, const __half2* zBi,
    const float* h0i, int b0i, int b1i, float* acci,
    const int* rpAc, const int* csAc, const float* slAc, const float* srAc, const __half2* zAc,
    const int* rpBc, const int* csBc, const float* slBc, const float* warc, const __half2* zBc,
    const float* h0c, int b0c, int b1c, float* accc,
    const void* __restrict__ gb, const int* __restrict__ fl)
{
    const int nblkI = (NI_ + 3) / 4;
    const int lane = threadIdx.x & 63;
    const int det = *fl;
    if ((int)blockIdx.x < nblkI) {
        int w = blockIdx.x * 4 + (threadIdx.x >> 6);
        if (w >= NI_) return;
        gat_dst(w, lane, det, rpAi, csAi, slAi, srAi, zAi, rpBi, csBi, slBi, wari, zBi, h0i, gb, b0i, b1i, acci);
    } else {
        int w = (blockIdx.x - nblkI) * 4 + (threadIdx.x >> 6);
        if (w >= NC_) return;
        gat_dst(w, lane, det, rpAc, csAc, slAc, srAc, zAc, rpBc, csBc, slBc, warc, zBc, h0c, gb, b0c, b1c, accc);
    }
}

// attention-phase weight pack: w_1 [0,4096) K256, glu1 [4096,6144) K128,
// lin_w [6144,10240) K256, glu2_w [10240,12288) K128
__global__ __launch_bounds__(256) void k_prepw3(
    const void* __restrict__ w1, const void* __restrict__ g1w,
    const void* __restrict__ lw, const void* __restrict__ g2w,
    const int* __restrict__ fl, u16* __restrict__ whi, u16* __restrict__ wlo)
{
    int s = blockIdx.x * 256 + threadIdx.x;
    if (s >= 12288) return;
    const int det = *fl;
    const void* src; int K, local;
    if (s < 4096)       { src = w1;  K = 256; local = s; }
    else if (s < 6144)  { src = g1w; K = 128; local = s - 4096; }
    else if (s < 10240) { src = lw;  K = 256; local = s - 6144; }
    else                { src = g2w; K = 128; local = s - 10240; }
    const int KK = K >> 5;
    int r = local & 15, g = (local >> 4) & 3, q2 = local >> 6;
    int kk = q2 % KK, ni = q2 / KK;
    bf16x8 hv, lv;
    #pragma unroll
    for (int j = 0; j < 8; ++j) {
        float x = gldf(src, (size_t)(kk * 32 + 8 * g + j) * 128 + ni * 16 + r, det);
        u16 hb = f2bf(x);
        hv[j] = (short)hb;
        lv[j] = (short)f2bf(x - bf2f(hb));
    }
    *(bf16x8*)(whi + (size_t)s * 8) = hv;
    *(bf16x8*)(wlo + (size_t)s * 8) = lv;
}

// shared K=128 z-gemm tail: breg loads, 3 MFMA passes, z + sl/sr epilogue
__device__ __forceinline__ void zg_doset(
    const short* __restrict__ Ah, const short* __restrict__ Alo,
    float (*part)[4][64],
    int tid, int l, int w, int base, int nrows, int det,
    const u16* __restrict__ whi, const u16* __restrict__ wlo,
    const void* __restrict__ al, int aloff, const void* __restrict__ ar, int aroff,
    __half* __restrict__ z, float* __restrict__ sl, float* __restrict__ sr)
{
    bf16x8 breg[2][4];
    #pragma unroll
    for (int t = 0; t < 2; ++t)
        #pragma unroll
        for (int kk = 0; kk < 4; ++kk)
            breg[t][kk] = *(const bf16x8*)(whi + ((size_t)((w * 2 + t) * 4 + kk) * 64 + l) * 8);
    f32x4 acc[4][2];
    #pragma unroll
    for (int mi = 0; mi < 4; ++mi) { acc[mi][0] = (f32x4){0.f,0.f,0.f,0.f}; acc[mi][1] = (f32x4){0.f,0.f,0.f,0.f}; }
    auto pass = [&](const short* AS) {
        #pragma unroll
        for (int kk = 0; kk < 4; ++kk) {
            bf16x8 a[4];
            #pragma unroll
            for (int mi = 0; mi < 4; ++mi) a[mi] = *(const bf16x8*)&AS[((mi * 4 + kk) * 64 + l) * 8];
            #pragma unroll
            for (int mi = 0; mi < 4; ++mi) {
                acc[mi][0] = __builtin_amdgcn_mfma_f32_16x16x32_bf16(a[mi], breg[0][kk], acc[mi][0], 0, 0, 0);
                acc[mi][1] = __builtin_amdgcn_mfma_f32_16x16x32_bf16(a[mi], breg[1][kk], acc[mi][1], 0, 0, 0);
            }
        }
    };
    pass(Ah);
    pass(Alo);
    #pragma unroll
    for (int t = 0; t < 2; ++t)
        #pragma unroll
        for (int kk = 0; kk < 4; ++kk)
            breg[t][kk] = *(const bf16x8*)(wlo + ((size_t)((w * 2 + t) * 4 + kk) * 64 + l) * 8);
    pass(Ah);
    const int g = l >> 4, r = l & 15, wn0 = w * 32;
    const float alv0 = gldf(al, (size_t)aloff + wn0 + r, det);
    const float alv1 = gldf(al, (size_t)aloff + wn0 + 16 + r, det);
    const float arv0 = gldf(ar, (size_t)aroff + wn0 + r, det);
    const float arv1 = gldf(ar, (size_t)aroff + wn0 + 16 + r, det);
    #pragma unroll
    for (int mi = 0; mi < 4; ++mi)
        #pragma unroll
        for (int j = 0; j < 4; ++j) {
            int row = base + mi * 16 + 4 * g + j;
            float d0 = acc[mi][0][j], d1 = acc[mi][1][j];
            if (row < nrows) {
                z[(size_t)row * 128 + wn0 + r]      = __float2half_rn(d0);
                z[(size_t)row * 128 + wn0 + 16 + r] = __float2half_rn(d1);
            }
            float pl = d0 * alv0 + d1 * alv1;
            float pr = d0 * arv0 + d1 * arv1;
            #pragma unroll
            for (int m2 = 1; m2 < 16; m2 <<= 1) {
                pl += __shfl_xor(pl, m2, 64);
                pr += __shfl_xor(pr, m2, 64);
            }
            if (r == 0) {
                part[0][w][mi * 16 + 4 * g + j] = pl;
                part[1][w][mi * 16 + 4 * g + j] = pr;
            }
        }
    __syncthreads();
    if (tid < 128) {
        int which = tid >> 6, t = tid & 63;
        int n2 = base + t;
        if (n2 < nrows) {
            float s = part[which][0][t] + part[which][1][t] + part[which][2][t] + part[which][3][t];
            (which ? sr : sl)[n2] = s;
        }
    }
    __syncthreads();
}

// fused: hi0 = [item|cate] @ W_pos (K=256), then BOTH layer-0 z-gemms on hi0 in-block
__global__ __launch_bounds__(256, 2) void m_hi0zg(
    const void* __restrict__ item, const void* __restrict__ cate,
    const int* __restrict__ iid, const int* __restrict__ icate,
    const u16* __restrict__ whi0, const u16* __restrict__ wlo0,
    const u16* __restrict__ whiA, const u16* __restrict__ wloA, int aloA, int aroA,
    const u16* __restrict__ whiB, const u16* __restrict__ wloB, int aloB, int aroB,
    const void* __restrict__ al, const void* __restrict__ ar,
    const int* __restrict__ fl, const int* __restrict__ mfok,
    float* __restrict__ hi0,
    __half* __restrict__ z1, float* __restrict__ sl1, float* __restrict__ sr1,
    __half* __restrict__ z2, float* __restrict__ sl2, float* __restrict__ sr2,
    int nrows)
{
    if (*mfok == 0) return;
    __shared__ __align__(16) short Ah[2048 * 8];   // 32 KB
    __shared__ __align__(16) short Alo[2048 * 8];  // 32 KB
    __shared__ float part[2][4][64];
    const int det = *fl;
    const int tid = threadIdx.x, l = tid & 63, w = tid >> 6;
    const int base = blockIdx.x * 64;
    {
        int row = tid >> 2, q = tid & 3;
        int n = base + row, mi = row >> 4, r = row & 15;
        const int it = (n < nrows) ? iid[n] : 0;
        const int ct = (n < nrows) ? icate[n] : 0;
        #pragma unroll
        for (int i = 0; i < 8; ++i) {
            int c = q + 4 * i, kk = c >> 2, g = c & 3;
            int slot = ((mi * 8 + kk) * 4 + g) * 16 + r;
            bf16x8 hv = {0,0,0,0,0,0,0,0}, lv = {0,0,0,0,0,0,0,0};
            if (n < nrows) {
                #pragma unroll
                for (int j = 0; j < 8; ++j) {
                    float x = (c < 16) ? gldf(item, (size_t)it * 128 + c * 8 + j, det)
                                       : gldf(cate, (size_t)ct * 128 + (c - 16) * 8 + j, det);
                    u16 hb2 = f2bf(x);
                    hv[j] = (short)hb2;
                    lv[j] = (short)f2bf(x - bf2f(hb2));
                }
            }
            *(bf16x8*)&Ah[slot * 8]  = hv;
            *(bf16x8*)&Alo[slot * 8] = lv;
        }
    }
    bf16x8 breg[2][8];
    #pragma unroll
    for (int t = 0; t < 2; ++t)
        #pragma unroll
        for (int kk = 0; kk < 8; ++kk)
            breg[t][kk] = *(const bf16x8*)(whi0 + ((size_t)((w * 2 + t) * 8 + kk) * 64 + l) * 8);
    __syncthreads();
    f32x4 acc[4][2];
    #pragma unroll
    for (int mi = 0; mi < 4; ++mi) { acc[mi][0] = (f32x4){0.f,0.f,0.f,0.f}; acc[mi][1] = (f32x4){0.f,0.f,0.f,0.f}; }
    auto pass8 = [&](const short* AS) {
        #pragma unroll
        for (int kk = 0; kk < 8; ++kk) {
            bf16x8 a[4];
            #pragma unroll
            for (int mi = 0; mi < 4; ++mi) a[mi] = *(const bf16x8*)&AS[((mi * 8 + kk) * 64 + l) * 8];
            #pragma unroll
            for (int mi = 0; mi < 4; ++mi) {
                acc[mi][0] = __builtin_amdgcn_mfma_f32_16x16x32_bf16(a[mi], breg[0][kk], acc[mi][0], 0, 0, 0);
                acc[mi][1] = __builtin_amdgcn_mfma_f32_16x16x32_bf16(a[mi], breg[1][kk], acc[mi][1], 0, 0, 0);
            }
        }
    };
    pass8(Ah);
    pass8(Alo);
    #pragma unroll
    for (int t = 0; t < 2; ++t)
        #pragma unroll
        for (int kk = 0; kk < 8; ++kk)
            breg[t][kk] = *(const bf16x8*)(wlo0 + ((size_t)((w * 2 + t) * 8 + kk) * 64 + l) * 8);
    pass8(Ah);
    // epilogue: write hi0 + restage split-bf16 into K=128 frag-native layout
    __syncthreads();   // all MFMA reads of Ah/Alo complete
    {
        const int g = l >> 4, r = l & 15, wn0 = w * 32;
        #pragma unroll
        for (int mi = 0; mi < 4; ++mi)
            #pragma unroll
            for (int j = 0; j < 4; ++j) {
                int nloc = mi * 16 + 4 * g + j;
                int row = base + nloc;
                int rr = nloc & 15, mi2 = nloc >> 4;
                #pragma unroll
                for (int hh = 0; hh < 2; ++hh) {
                    int col = wn0 + 16 * hh + r;
                    float x = acc[mi][hh][j];
                    if (row < nrows) hi0[(size_t)row * 128 + col] = x;
                    int c = col >> 3, jj = col & 7;
                    int slot = ((mi2 * 4 + (c >> 2)) * 4 + (c & 3)) * 16 + rr;
                    u16 hb = f2bf(x);
                    Ah[slot * 8 + jj]  = (short)hb;
                    Alo[slot * 8 + jj] = (short)f2bf(x - bf2f(hb));
                }
            }
    }
    __syncthreads();
    zg_doset(Ah, Alo, part, tid, l, w, base, nrows, det, whiA, wloA, al, aloA, ar, aroA, z1, sl1, sr1);
    zg_doset(Ah, Alo, part, tid, l, w, base, nrows, det, whiB, wloB, al, aloB, ar, aroB, z2, sl2, sr2);
}

// dual-weight z-gemm (layer-0 cate): stage h once, two weight sets
__global__ __launch_bounds__(256, 2) void m_zgemm2(
    const float* __restrict__ h, int nrows,
    const u16* __restrict__ whi1, const u16* __restrict__ wlo1,
    int alo1, int aro1, __half* __restrict__ z1,
    float* __restrict__ sl1, float* __restrict__ sr1,
    const u16* __restrict__ whi2, const u16* __restrict__ wlo2,
    int alo2, int aro2, __half* __restrict__ z2,
    float* __restrict__ sl2, float* __restrict__ sr2,
    const void* __restrict__ al, const void* __restrict__ ar,
    const int* __restrict__ fl, const int* __restrict__ mfok)
{
    if (*mfok == 0) return;
    __shared__ __align__(16) short Ah[1024 * 8];
    __shared__ __align__(16) short Alo[1024 * 8];
    __shared__ float part[2][4][64];
    const int det = *fl;
    const int tid = threadIdx.x, l = tid & 63, w = tid >> 6;
    const int base = blockIdx.x * 64;
    {
        int row = tid >> 2, q = tid & 3;
        int n = base + row, mi = row >> 4, r = row & 15;
        #pragma unroll
        for (int i = 0; i < 4; ++i) {
            int c = q + 4 * i, kk = c >> 2, g = c & 3;
            int slot = ((mi * 4 + kk) * 4 + g) * 16 + r;
            bf16x8 hv = {0,0,0,0,0,0,0,0}, lv = {0,0,0,0,0,0,0,0};
            if (n < nrows) {
                const float* sp = h + (size_t)n * 128 + c * 8;
                #pragma unroll
                for (int j = 0; j < 8; ++j) {
                    float x = sp[j];
                    u16 hb = f2bf(x);
                    hv[j] = (short)hb;
                    lv[j] = (short)f2bf(x - bf2f(hb));
                }
            }
            *(bf16x8*)&Ah[slot * 8]  = hv;
            *(bf16x8*)&Alo[slot * 8] = lv;
        }
    }
    __syncthreads();
    zg_doset(Ah, Alo, part, tid, l, w, base, nrows, det, whi1, wlo1, al, alo1, ar, aro1, z1, sl1, sr1);
    zg_doset(Ah, Alo, part, tid, l, w, base, nrows, det, whi2, wlo2, al, alo2, ar, aro2, z2, sl2, sr2);
}

// merged layer-1 z-gemms: blocks [0,nblkA) -> set A (item), rest -> set B (cate)
__global__ __launch_bounds__(256, 2) void m_zgemm_dual(
    const float* __restrict__ hA, int nA,
    const u16* __restrict__ whiA, const u16* __restrict__ wloA, int aloA, int aroA,
    __half* __restrict__ zA, float* __restrict__ slA, float* __restrict__ srA,
    const float* __restrict__ hB, int nB,
    const u16* __restrict__ whiB, const u16* __restrict__ wloB, int aloB, int aroB,
    __half* __restrict__ zB, float* __restrict__ slB, float* __restrict__ srB,
    const void* __restrict__ al, const void* __restrict__ ar,
    const int* __restrict__ fl, const int* __restrict__ mfok)
{
    if (*mfok == 0) return;
    __shared__ __align__(16) short Ah[1024 * 8];
    __shared__ __align__(16) short Alo[1024 * 8];
    __shared__ float part[2][4][64];
    const int det = *fl;
    const int tid = threadIdx.x, l = tid & 63, w = tid >> 6;
    const int nblkA = (nA + 63) / 64;
    const bool rb = (int)blockIdx.x >= nblkA;
    const float* h = rb ? hB : hA;
    const int nrows = rb ? nB : nA;
    const u16* whi = rb ? whiB : whiA;
    const u16* wlo = rb ? wloB : wloA;
    const int aloff = rb ? aloB : aloA, aroff = rb ? aroB : aroA;
    __half* z = rb ? zB : zA;
    float* sl = rb ? slB : slA;
    float* sr = rb ? srB : srA;
    const int base = (rb ? blockIdx.x - nblkA : blockIdx.x) * 64;
    {
        int row = tid >> 2, q = tid & 3;
        int n = base + row, mi = row >> 4, r = row & 15;
        #pragma unroll
        for (int i = 0; i < 4; ++i) {
            int c = q + 4 * i, kk = c >> 2, g = c & 3;
            int slot = ((mi * 4 + kk) * 4 + g) * 16 + r;
            bf16x8 hv = {0,0,0,0,0,0,0,0}, lv = {0,0,0,0,0,0,0,0};
            if (n < nrows) {
                const float* sp = h + (size_t)n * 128 + c * 8;
                #pragma unroll
                for (int j = 0; j < 8; ++j) {
                    float x = sp[j];
                    u16 hb = f2bf(x);
                    hv[j] = (short)hb;
                    lv[j] = (short)f2bf(x - bf2f(hb));
                }
            }
            *(bf16x8*)&Ah[slot * 8]  = hv;
            *(bf16x8*)&Alo[slot * 8] = lv;
        }
    }
    __syncthreads();
    zg_doset(Ah, Alo, part, tid, l, w, base, nrows, det, whi, wlo, al, aloff, ar, aroff, z, sl, sr);
}

// feat = g*h0 + (1-g)*h1, g = sigm([h0|h1] @ W + b)  — h0/h1 reconstructed from LDS
__global__ __launch_bounds__(256, 2) void m_gatefeat(
    const float* __restrict__ h0, const float* __restrict__ h1,
    const u16* __restrict__ whi, const u16* __restrict__ wlo,
    const void* __restrict__ bias,
    const int* __restrict__ fl, const int* __restrict__ mfok,
    float* __restrict__ feat, int nrows)
{
    if (*mfok == 0) return;
    __shared__ __align__(16) short Ah[2048 * 8];
    __shared__ __align__(16) short Alo[2048 * 8];
    const int det = *fl;
    const int tid = threadIdx.x, l = tid & 63, w = tid >> 6;
    const int base = blockIdx.x * 64;
    {
        int row = tid >> 2, q = tid & 3;
        int n = base + row, mi = row >> 4, r = row & 15;
        #pragma unroll
        for (int i = 0; i < 8; ++i) {
            int c = q + 4 * i, kk = c >> 2, g = c & 3;
            int slot = ((mi * 8 + kk) * 4 + g) * 16 + r;
            bf16x8 hv = {0,0,0,0,0,0,0,0}, lv = {0,0,0,0,0,0,0,0};
            if (n < nrows) {
                const float* sp = ((c < 16) ? h0 : h1) + (size_t)n * 128 + (c & 15) * 8;
                #pragma unroll
                for (int j = 0; j < 8; ++j) {
                    float x = sp[j];
                    u16 hb = f2bf(x);
                    hv[j] = (short)hb;
                    lv[j] = (short)f2bf(x - bf2f(hb));
                }
            }
            *(bf16x8*)&Ah[slot * 8]  = hv;
            *(bf16x8*)&Alo[slot * 8] = lv;
        }
    }
    bf16x8 breg[2][8];
    #pragma unroll
    for (int t = 0; t < 2; ++t)
        #pragma unroll
        for (int kk = 0; kk < 8; ++kk)
            breg[t][kk] = *(const bf16x8*)(whi + ((size_t)((w * 2 + t) * 8 + kk) * 64 + l) * 8);
    __syncthreads();
    f32x4 acc[4][2];
    #pragma unroll
    for (int mi = 0; mi < 4; ++mi) { acc[mi][0] = (f32x4){0.f,0.f,0.f,0.f}; acc[mi][1] = (f32x4){0.f,0.f,0.f,0.f}; }
    auto pass = [&](const short* AS) {
        #pragma unroll
        for (int kk = 0; kk < 8; ++kk) {
            bf16x8 a[4];
            #pragma unroll
            for (int mi = 0; mi < 4; ++mi) a[mi] = *(const bf16x8*)&AS[((mi * 8 + kk) * 64 + l) * 8];
            #pragma unroll
            for (int mi = 0; mi < 4; ++mi) {
                acc[mi][0] = __builtin_amdgcn_mfma_f32_16x16x32_bf16(a[mi], breg[0][kk], acc[mi][0], 0, 0, 0);
                acc[mi][1] = __builtin_amdgcn_mfma_f32_16x16x32_bf16(a[mi], breg[1][kk], acc[mi][1], 0, 0, 0);
            }
        }
    };
    pass(Ah);
    pass(Alo);
    #pragma unroll
    for (int t = 0; t < 2; ++t)
        #pragma unroll
        for (int kk = 0; kk < 8; ++kk)
            breg[t][kk] = *(const bf16x8*)(wlo + ((size_t)((w * 2 + t) * 8 + kk) * 64 + l) * 8);
    pass(Ah);
    const int g = l >> 4, r = l & 15, wn0 = w * 32;
    const float bv0 = gldf(bias, wn0 + r, det);
    const float bv1 = gldf(bias, wn0 + 16 + r, det);
    auto recon = [&](int nloc, int colg) -> float {
        int c = colg >> 3, jj = colg & 7;
        int slot = (((nloc >> 4) * 8 + (c >> 2)) * 4 + (c & 3)) * 16 + (nloc & 15);
        return bf2f((u16)Ah[slot * 8 + jj]) + bf2f((u16)Alo[slot * 8 + jj]);
    };
    #pragma unroll
    for (int mi = 0; mi < 4; ++mi)
        #pragma unroll
        for (int j = 0; j < 4; ++j) {
            int nloc = mi * 16 + 4 * g + j;
            int row = base + nloc;
            if (row < nrows) {
                size_t o0 = (size_t)row * 128 + wn0 + r;
                size_t o1 = o0 + 16;
                float h0a = recon(nloc, wn0 + r);
                float h0b = recon(nloc, wn0 + 16 + r);
                float h1a = recon(nloc, 128 + wn0 + r);
                float h1b = recon(nloc, 128 + wn0 + 16 + r);
                float ga  = sigm(acc[mi][0][j] + bv0);
                float gb2 = sigm(acc[mi][1][j] + bv1);
                feat[o0] = ga  * h0a + (1.f - ga)  * h1a;
                feat[o1] = gb2 * h0b + (1.f - gb2) * h1b;
            }
        }
}

// fused: nh = tanh([pos|hall0]@w1) (K=256) then beta = (sigm(nh@glu1+b+g2).w2)*mask (K=128)
__global__ __launch_bounds__(256, 2) void m_nhglu(
    const void* __restrict__ pos, const float* __restrict__ hall0,
    const u16* __restrict__ whi1, const u16* __restrict__ wlo1,
    const u16* __restrict__ whi2, const u16* __restrict__ wlo2,
    const void* __restrict__ gb, const float* __restrict__ g2,
    const void* __restrict__ w2, const int* __restrict__ mask,
    const int* __restrict__ fl, const int* __restrict__ mfok,
    float* __restrict__ beta, int nrows)
{
    if (*mfok == 0) return;
    __shared__ __align__(16) short Ah[2048 * 8];
    __shared__ __align__(16) short Alo[2048 * 8];
    __shared__ float part[4][64];
    const int det = *fl;
    const int tid = threadIdx.x, l = tid & 63, w = tid >> 6;
    const int base = blockIdx.x * 64;
    {
        int row = tid >> 2, q = tid & 3;
        int n = base + row, mi = row >> 4, r = row & 15;
        const int t = (n < nrows) ? (n - (n / T_) * T_) : 0;
        #pragma unroll
        for (int i = 0; i < 8; ++i) {
            int c = q + 4 * i, kk = c >> 2, g = c & 3;
            int slot = ((mi * 8 + kk) * 4 + g) * 16 + r;
            bf16x8 hv = {0,0,0,0,0,0,0,0}, lv = {0,0,0,0,0,0,0,0};
            if (n < nrows) {
                #pragma unroll
                for (int j = 0; j < 8; ++j) {
                    float x = (c < 16) ? gldf(pos, (size_t)t * 128 + c * 8 + j, det)
                                       : hall0[(size_t)n * 128 + (c - 16) * 8 + j];
                    u16 hb = f2bf(x);
                    hv[j] = (short)hb;
                    lv[j] = (short)f2bf(x - bf2f(hb));
                }
            }
            *(bf16x8*)&Ah[slot * 8]  = hv;
            *(bf16x8*)&Alo[slot * 8] = lv;
        }
    }
    bf16x8 breg[2][8];
    #pragma unroll
    for (int t = 0; t < 2; ++t)
        #pragma unroll
        for (int kk = 0; kk < 8; ++kk)
            breg[t][kk] = *(const bf16x8*)(whi1 + ((size_t)((w * 2 + t) * 8 + kk) * 64 + l) * 8);
    __syncthreads();
    f32x4 acc[4][2];
    #pragma unroll
    for (int mi = 0; mi < 4; ++mi) { acc[mi][0] = (f32x4){0.f,0.f,0.f,0.f}; acc[mi][1] = (f32x4){0.f,0.f,0.f,0.f}; }
    auto pass1 = [&](const short* AS) {
        #pragma unroll
        for (int kk = 0; kk < 8; ++kk) {
            bf16x8 a[4];
            #pragma unroll
            for (int mi = 0; mi < 4; ++mi) a[mi] = *(const bf16x8*)&AS[((mi * 8 + kk) * 64 + l) * 8];
            #pragma unroll
            for (int mi = 0; mi < 4; ++mi) {
                acc[mi][0] = __builtin_amdgcn_mfma_f32_16x16x32_bf16(a[mi], breg[0][kk], acc[mi][0], 0, 0, 0);
                acc[mi][1] = __builtin_amdgcn_mfma_f32_16x16x32_bf16(a[mi], breg[1][kk], acc[mi][1], 0, 0, 0);
            }
        }
    };
    pass1(Ah);
    pass1(Alo);
    #pragma unroll
    for (int t = 0; t < 2; ++t)
        #pragma unroll
        for (int kk = 0; kk < 8; ++kk)
            breg[t][kk] = *(const bf16x8*)(wlo1 + ((size_t)((w * 2 + t) * 8 + kk) * 64 + l) * 8);
    pass1(Ah);
    __syncthreads();
    {
        const int g = l >> 4, r = l & 15, wn0 = w * 32;
        #pragma unroll
        for (int mi = 0; mi < 4; ++mi)
            #pragma unroll
            for (int j = 0; j < 4; ++j) {
                int nloc = mi * 16 + 4 * g + j;
                int rr = nloc & 15, mi2 = nloc >> 4;
                #pragma unroll
                for (int hh = 0; hh < 2; ++hh) {
                    int col = wn0 + 16 * hh + r;
                    float x = tanhf(acc[mi][hh][j]);
                    int c = col >> 3, jj = col & 7;
                    int slot = ((mi2 * 4 + (c >> 2)) * 4 + (c & 3)) * 16 + rr;
                    u16 hb = f2bf(x);
                    Ah[slot * 8 + jj]  = (short)hb;
                    Alo[slot * 8 + jj] = (short)f2bf(x - bf2f(hb));
                }
            }
    }
    __syncthreads();
    bf16x8 breg2[2][4];
    #pragma unroll
    for (int t = 0; t < 2; ++t)
        #pragma unroll
        for (int kk = 0; kk < 4; ++kk)
            breg2[t][kk] = *(const bf16x8*)(whi2 + ((size_t)((w * 2 + t) * 4 + kk) * 64 + l) * 8);
    f32x4 acc2[4][2];
    #pragma unroll
    for (int mi = 0; mi < 4; ++mi) { acc2[mi][0] = (f32x4){0.f,0.f,0.f,0.f}; acc2[mi][1] = (f32x4){0.f,0.f,0.f,0.f}; }
    auto pass2 = [&](const short* AS) {
        #pragma unroll
        for (int kk = 0; kk < 4; ++kk) {
            bf16x8 a[4];
            #pragma unroll
            for (int mi = 0; mi < 4; ++mi) a[mi] = *(const bf16x8*)&AS[((mi * 4 + kk) * 64 + l) * 8];
            #pragma unroll
            for (int mi = 0; mi < 4; ++mi) {
                acc2[mi][0] = __builtin_amdgcn_mfma_f32_16x16x32_bf16(a[mi], breg2[0][kk], acc2[mi][0], 0, 0, 0);
                acc2[mi][1] = __builtin_amdgcn_mfma_f32_16x16x32_bf16(a[mi], breg2[1][kk], acc2[mi][1], 0, 0, 0);
            }
        }
    };
    pass2(Ah);
    pass2(Alo);
    #pragma unroll
    for (int t = 0; t < 2; ++t)
        #pragma unroll
        for (int kk = 0; kk < 4; ++kk)
            breg2[t][kk] = *(const bf16x8*)(wlo2 + ((size_t)((w * 2 + t) * 4 + kk) * 64 + l) * 8);
    pass2(Ah);
    const int g = l >> 4, r = l & 15, wn0 = w * 32;
    const float gbv0 = gldf(gb, wn0 + r, det);
    const float gbv1 = gldf(gb, wn0 + 16 + r, det);
    const float w2v0 = gldf(w2, wn0 + r, det);
    const float w2v1 = gldf(w2, wn0 + 16 + r, det);
    #pragma unroll
    for (int mi = 0; mi < 4; ++mi)
        #pragma unroll
        for (int j = 0; j < 4; ++j) {
            int row = base + mi * 16 + 4 * g + j;
            int b = row / T_;
            float gv0 = (row < nrows) ? g2[(size_t)b * 128 + wn0 + r]      : 0.f;
            float gv1 = (row < nrows) ? g2[(size_t)b * 128 + wn0 + 16 + r] : 0.f;
            float v0 = sigm(acc2[mi][0][j] + gbv0 + gv0);
            float v1 = sigm(acc2[mi][1][j] + gbv1 + gv1);
            float pl = v0 * w2v0 + v1 * w2v1;
            #pragma unroll
            for (int m2 = 1; m2 < 16; m2 <<= 1) pl += __shfl_xor(pl, m2, 64);
            if (r == 0) part[w][mi * 16 + 4 * g + j] = pl;
        }
    __syncthreads();
    if (tid < 64) {
        int n2 = base + tid;
        if (n2 < nrows) {
            float s = part[0][tid] + part[1][tid] + part[2][tid] + part[3][tid];
            beta[n2] = s * (float)mask[n2];
        }
    }
}

// MFMA: hsv2 = [hsvn | hh] @ lin_w + lin_b (K=256), then g2 = hsv2 @ glu2_w (K=128)
__global__ __launch_bounds__(256, 2) void m_lin(
    const float* __restrict__ hsvn, const float* __restrict__ hall0,
    const u16* __restrict__ whi1, const u16* __restrict__ wlo1,
    const u16* __restrict__ whi2, const u16* __restrict__ wlo2,
    const void* __restrict__ lb,
    const int* __restrict__ fl, const int* __restrict__ mfok,
    float* __restrict__ g2, int nrows)
{
    if (*mfok == 0) return;
    __shared__ __align__(16) short Ah[2048 * 8];
    __shared__ __align__(16) short Alo[2048 * 8];
    const int det = *fl;
    const int tid = threadIdx.x, l = tid & 63, w = tid >> 6;
    const int base = blockIdx.x * 64;
    {
        int row = tid >> 2, q = tid & 3;
        int n = base + row, mi = row >> 4, r = row & 15;
        #pragma unroll
        for (int i = 0; i < 8; ++i) {
            int c = q + 4 * i, kk = c >> 2, g = c & 3;
            int slot = ((mi * 8 + kk) * 4 + g) * 16 + r;
            bf16x8 hv = {0,0,0,0,0,0,0,0}, lv = {0,0,0,0,0,0,0,0};
            if (n < nrows) {
                const float* sp = (c < 16) ? hsvn + (size_t)n * 128 + c * 8
                                           : hall0 + (size_t)n * T_ * 128 + (c - 16) * 8;
                #pragma unroll
                for (int j = 0; j < 8; ++j) {
                    float x = sp[j];
                    u16 hb = f2bf(x);
                    hv[j] = (short)hb;
                    lv[j] = (short)f2bf(x - bf2f(hb));
                }
            }
            *(bf16x8*)&Ah[slot * 8]  = hv;
            *(bf16x8*)&Alo[slot * 8] = lv;
        }
    }
    bf16x8 breg[2][8];
    #pragma unroll
    for (int t = 0; t < 2; ++t)
        #pragma unroll
        for (int kk = 0; kk < 8; ++kk)
            breg[t][kk] = *(const bf16x8*)(whi1 + ((size_t)((w * 2 + t) * 8 + kk) * 64 + l) * 8);
    __syncthreads();
    f32x4 acc[4][2];
    #pragma unroll
    for (int mi = 0; mi < 4; ++mi) { acc[mi][0] = (f32x4){0.f,0.f,0.f,0.f}; acc[mi][1] = (f32x4){0.f,0.f,0.f,0.f}; }
    auto pass1 = [&](const short* AS) {
        #pragma unroll
        for (int kk = 0; kk < 8; ++kk) {
            bf16x8 a[4];
            #pragma unroll
            for (int mi = 0; mi < 4; ++mi) a[mi] = *(const bf16x8*)&AS[((mi * 8 + kk) * 64 + l) * 8];
            #pragma unroll
            for (int mi = 0; mi < 4; ++mi) {
                acc[mi][0] = __builtin_amdgcn_mfma_f32_16x16x32_bf16(a[mi], breg[0][kk], acc[mi][0], 0, 0, 0);
                acc[mi][1] = __builtin_amdgcn_mfma_f32_16x16x32_bf16(a[mi], breg[1][kk], acc[mi][1], 0, 0, 0);
            }
        }
    };
    pass1(Ah);
    pass1(Alo);
    #pragma unroll
    for (int t = 0; t < 2; ++t)
        #pragma unroll
        for (int kk = 0; kk < 8; ++kk)
            breg[t][kk] = *(const bf16x8*)(wlo1 + ((size_t)((w * 2 + t) * 8 + kk) * 64 + l) * 8);
    pass1(Ah);
    __syncthreads();
    {
        const int g = l >> 4, r = l & 15, wn0 = w * 32;
        #pragma unroll
        for (int mi = 0; mi < 4; ++mi)
            #pragma unroll
            for (int j = 0; j < 4; ++j) {
                int nloc = mi * 16 + 4 * g + j;
                int rr = nloc & 15, mi2 = nloc >> 4;
                #pragma unroll
                for (int hh = 0; hh < 2; ++hh) {
                    int col = wn0 + 16 * hh + r;
                    float x = acc[mi][hh][j] + gldf(lb, col, det);
                    int c = col >> 3, jj = col & 7;
                    int slot = ((mi2 * 4 + (c >> 2)) * 4 + (c & 3)) * 16 + rr;
                    u16 hb = f2bf(x);
                    Ah[slot * 8 + jj]  = (short)hb;
                    Alo[slot * 8 + jj] = (short)f2bf(x - bf2f(hb));
                }
            }
    }
    __syncthreads();
    bf16x8 breg2[2][4];
    #pragma unroll
    for (int t = 0; t < 2; ++t)
        #pragma unroll
        for (int kk = 0; kk < 4; ++kk)
            breg2[t][kk] = *(const bf16x8*)(whi2 + ((size_t)((w * 2 + t) * 4 + kk) * 64 + l) * 8);
    f32x4 acc2[4][2];
    #pragma unroll
    for (int mi = 0; mi < 4; ++mi) { acc2[mi][0] = (f32x4){0.f,0.f,0.f,0.f}; acc2[mi][1] = (f32x4){0.f,0.f,0.f,0.f}; }
    auto pass2 = [&](const short* AS) {
        #pragma unroll
        for (int kk = 0; kk < 4; ++kk) {
            bf16x8 a[4];
            #pragma unroll
            for (int mi = 0; mi < 4; ++mi) a[mi] = *(const bf16x8*)&AS[((mi * 4 + kk) * 64 + l) * 8];
            #pragma unroll
            for (int mi = 0; mi < 4; ++mi) {
                acc2[mi][0] = __builtin_amdgcn_mfma_f32_16x16x32_bf16(a[mi], breg2[0][kk], acc2[mi][0], 0, 0, 0);
                acc2[mi][1] = __builtin_amdgcn_mfma_f32_16x16x32_bf16(a[mi], breg2[1][kk], acc2[mi][1], 0, 0, 0);
            }
        }
    };
    pass2(Ah);
    pass2(Alo);
    #pragma unroll
    for (int t = 0; t < 2; ++t)
        #pragma unroll
        for (int kk = 0; kk < 4; ++kk)
            breg2[t][kk] = *(const bf16x8*)(wlo2 + ((size_t)((w * 2 + t) * 4 + kk) * 64 + l) * 8);
    pass2(Ah);
    const int g = l >> 4, r = l & 15, wn0 = w * 32;
    #pragma unroll
    for (int mi = 0; mi < 4; ++mi)
        #pragma unroll
        for (int j = 0; j < 4; ++j) {
            int row = base + mi * 16 + 4 * g + j;
            if (row < nrows) {
                g2[(size_t)row * 128 + wn0 + r]      = acc2[mi][0][j];
                g2[(size_t)row * 128 + wn0 + 16 + r] = acc2[mi][1][j];
            }
        }
}

// ================= tiled GEMM kernels (VALU fallback, only launched when !mf) =================
__global__ __launch_bounds__(512) void t_hi0(
    const void* __restrict__ item, const void* __restrict__ cate,
    const int* __restrict__ iid, const int* __restrict__ icate,
    const void* __restrict__ Wp, const int* __restrict__ fl,
    float* __restrict__ out, int nrows)
{
    __shared__ float Ws[8192];
    __shared__ float hrow[16][256];
    const int det = *fl;
    const int tid = threadIdx.x, c = tid & 31, slot = tid >> 5;
    for (int base = blockIdx.x * 16; base < nrows; base += gridDim.x * 16) {
        const int n = base + slot;
        if (n < nrows) {
            const int it = iid[n], ct = icate[n];
            for (int j = c; j < 128; j += 32) {
                hrow[slot][j]       = gldf(item, (size_t)it * 128 + j, det);
                hrow[slot][128 + j] = gldf(cate, (size_t)ct * 128 + j, det);
            }
        }
        float4 acc = make_float4(0.f, 0.f, 0.f, 0.f);
        for (int kb = 0; kb < 256; kb += 64) {
            __syncthreads();
            for (int i = tid; i < 8192; i += 512) Ws[i] = gldf(Wp, (size_t)kb * 128 + i, det);
            __syncthreads();
            if (n < nrows) {
                #pragma unroll 8
                for (int k = 0; k < 64; ++k) {
                    float hv = hrow[slot][kb + k];
                    float4 w = *(const float4*)&Ws[k * 128 + c * 4];
                    acc.x += hv * w.x; acc.y += hv * w.y; acc.z += hv * w.z; acc.w += hv * w.w;
                }
            }
        }
        if (n < nrows) *(float4*)&out[(size_t)n * 128 + c * 4] = acc;
        __syncthreads();
    }
}

__global__ __launch_bounds__(256) void s_hc0(
    const void* __restrict__ cate, const int* __restrict__ cid,
    const int* __restrict__ fl, float* __restrict__ out)
{
    long i = (long)blockIdx.x * 256 + threadIdx.x;
    if (i >= (long)NC_ * 128) return;
    out[i] = gldf(cate, (size_t)cid[i >> 7] * 128 + (i & 127), *fl);
}

__global__ __launch_bounds__(256) void s_initacc(
    const float* __restrict__ h, const void* __restrict__ gb, int b0off, int b1off,
    const int* __restrict__ fl, float* __restrict__ acc, long total)
{
    long i = (long)blockIdx.x * 256 + threadIdx.x;
    if (i >= total) return;
    const int det = *fl, d = (int)(i & 127);
    acc[i] = 2.f * h[i] + gldf(gb, b0off + d, det) + gldf(gb, b1off + d, det);
}

__global__ __launch_bounds__(512) void t_zgemm(
    const float* __restrict__ h, int nrows,
    const void* __restrict__ W, int woff,
    const void* __restrict__ al, int aloff,
    const void* __restrict__ ar, int aroff,
    const int* __restrict__ fl,
    __half* __restrict__ z, float* __restrict__ sl, float* __restrict__ sr)
{
    __shared__ float Ws[8192];
    __shared__ float hrow[16][128];
    const int det = *fl;
    const int tid = threadIdx.x, c = tid & 31, slot = tid >> 5;
    float4 alv, arv;
    alv.x = gldf(al, (size_t)aloff + c * 4 + 0, det); alv.y = gldf(al, (size_t)aloff + c * 4 + 1, det);
    alv.z = gldf(al, (size_t)aloff + c * 4 + 2, det); alv.w = gldf(al, (size_t)aloff + c * 4 + 3, det);
    arv.x = gldf(ar, (size_t)aroff + c * 4 + 0, det); arv.y = gldf(ar, (size_t)aroff + c * 4 + 1, det);
    arv.z = gldf(ar, (size_t)aroff + c * 4 + 2, det); arv.w = gldf(ar, (size_t)aroff + c * 4 + 3, det);
    for (int base = blockIdx.x * 16; base < nrows; base += gridDim.x * 16) {
        const int n = base + slot;
        if (n < nrows) for (int j = c; j < 128; j += 32) hrow[slot][j] = h[(size_t)n * 128 + j];
        float4 acc = make_float4(0.f, 0.f, 0.f, 0.f);
        for (int kb = 0; kb < 128; kb += 64) {
            __syncthreads();
            for (int i = tid; i < 8192; i += 512) Ws[i] = gldf(W, (size_t)woff + (size_t)kb * 128 + i, det);
            __syncthreads();
            if (n < nrows) {
                #pragma unroll 8
                for (int k = 0; k < 64; ++k) {
                    float hv = hrow[slot][kb + k];
                    float4 w = *(const float4*)&Ws[k * 128 + c * 4];
                    acc.x += hv * w.x; acc.y += hv * w.y; acc.z += hv * w.z; acc.w += hv * w.w;
                }
            }
        }
        if (n < nrows) {
            z[(size_t)n * 128 + c * 4 + 0] = __float2half_rn(acc.x);
            z[(size_t)n * 128 + c * 4 + 1] = __float2half_rn(acc.y);
            z[(size_t)n * 128 + c * 4 + 2] = __float2half_rn(acc.z);
            z[(size_t)n * 128 + c * 4 + 3] = __float2half_rn(acc.w);
            float pl = acc.x * alv.x + acc.y * alv.y + acc.z * alv.z + acc.w * alv.w;
            float pr = acc.x * arv.x + acc.y * arv.y + acc.z * arv.z + acc.w * arv.w;
            #pragma unroll
            for (int off = 16; off > 0; off >>= 1) {
                pl += __shfl_down(pl, off, 32);
                pr += __shfl_down(pr, off, 32);
            }
            if (c == 0) { sl[n] = pl; sr[n] = pr; }
        }
        __syncthreads();
    }
}

// -------- fallback atomic path --------
__global__ __launch_bounds__(256) void s_dinit(float* __restrict__ den, int n)
{
    int i = blockIdx.x * 256 + threadIdx.x;
    if (i < n) den[i] = 0.f;
}
__global__ __launch_bounds__(256) void s_edge(
    const float* __restrict__ sl, const float* __restrict__ sr,
    const int* __restrict__ src, const int* __restrict__ dst,
    float* __restrict__ e, float* __restrict__ den, int E)
{
    int j = blockIdx.x * 256 + threadIdx.x;
    if (j >= E) return;
    float ee = expf(lrelu_c(sl[src[j]] + sr[dst[j]]));
    e[j] = ee;
    atomicAdd(&den[dst[j]], ee);
}
__global__ __launch_bounds__(256) void s_scatter(
    const float* __restrict__ e, const float* __restrict__ den,
    const int* __restrict__ src, const int* __restrict__ dst,
    const __half* __restrict__ z, float* __restrict__ acc, int E)
{
    long i = (long)blockIdx.x * 256 + threadIdx.x;
    if (i >= (long)E * 128) return;
    int j = (int)(i >> 7), d = (int)(i & 127);
    int dj = dst[j];
    atomicAdd(&acc[(size_t)dj * 128 + d], (e[j] / den[dj]) * __half2float(z[(size_t)src[j] * 128 + d]));
}

__global__ __launch_bounds__(512) void t_gatefeat(
    const float* __restrict__ h0, const float* __restrict__ h1,
    const void* __restrict__ W, const void* __restrict__ bias,
    const int* __restrict__ fl,
    float* __restrict__ feat, int nrows)
{
    __shared__ float Ws[8192];
    __shared__ float hrow[16][256];
    const int det = *fl;
    const int tid = threadIdx.x, c = tid & 31, slot = tid >> 5;
    float4 bv;
    bv.x = gldf(bias, c * 4 + 0, det); bv.y = gldf(bias, c * 4 + 1, det);
    bv.z = gldf(bias, c * 4 + 2, det); bv.w = gldf(bias, c * 4 + 3, det);
    for (int base = blockIdx.x * 16; base < nrows; base += gridDim.x * 16) {
        const int n = base + slot;
        if (n < nrows) {
            for (int j = c; j < 128; j += 32) {
                hrow[slot][j]       = h0[(size_t)n * 128 + j];
                hrow[slot][128 + j] = h1[(size_t)n * 128 + j];
            }
        }
        float4 acc = make_float4(0.f, 0.f, 0.f, 0.f);
        for (int kb = 0; kb < 256; kb += 64) {
            __syncthreads();
            for (int i = tid; i < 8192; i += 512) Ws[i] = gldf(W, (size_t)kb * 128 + i, det);
            __syncthreads();
            if (n < nrows) {
                #pragma unroll 8
                for (int k = 0; k < 64; ++k) {
                    float hv = hrow[slot][kb + k];
                    float4 w = *(const float4*)&Ws[k * 128 + c * 4];
                    acc.x += hv * w.x; acc.y += hv * w.y; acc.z += hv * w.z; acc.w += hv * w.w;
                }
            }
        }
        if (n < nrows) {
            float4 a = *(const float4*)&hrow[slot][c * 4];
            float4 b = *(const float4*)&hrow[slot][128 + c * 4];
            float gx = sigm(acc.x + bv.x), gy = sigm(acc.y + bv.y);
            float gz = sigm(acc.z + bv.z), gw = sigm(acc.w + bv.w);
            float4 o;
            o.x = gx * a.x + (1.f - gx) * b.x;
            o.y = gy * a.y + (1.f - gy) * b.y;
            o.z = gz * a.z + (1.f - gz) * b.z;
            o.w = gw * a.w + (1.f - gw) * b.w;
            *(float4*)&feat[(size_t)n * 128 + c * 4] = o;
        }
        __syncthreads();
    }
}

// slim attn: build hall0 rows + hs->softmax->hsv->LN1 -> hsvn  (mf path)
__global__ __launch_bounds__(128) void t_attn1n(
    const void* __restrict__ item, const int* __restrict__ seq,
    const int* __restrict__ alias, const int* __restrict__ maskp,
    const float* __restrict__ feat, const void* __restrict__ xs,
    const void* __restrict__ q,
    const void* __restrict__ g, const void* __restrict__ bb,
    const int* __restrict__ fl,
    float* __restrict__ hall0, float* __restrict__ hsvn)
{
    __shared__ float hl[T_][129];
    __shared__ float qs[128];
    __shared__ float hs_s[T_];
    __shared__ float red[128];
    const int b = blockIdx.x, tid = threadIdx.x;
    const int det = *fl;
    const float x = gldf(xs, 0, det);
    qs[tid] = gldf(q, tid, det);
    for (int t = 0; t < T_; ++t) {
        int bt = b * T_ + t;
        float v = gldf(item, (size_t)seq[bt] * 128 + tid, det) * x
                + feat[(size_t)alias[bt] * 128 + tid] * (float)maskp[bt];
        hl[t][tid] = v;
        hall0[(size_t)bt * 128 + tid] = v;
    }
    __syncthreads();
    if (tid < T_) {
        float a = 0.f;
        for (int d = 0; d < 128; ++d) a += hl[tid][d] * qs[d];
        hs_s[tid] = a;
    }
    __syncthreads();
    float mx = -1e30f;
    for (int t = 0; t < T_; ++t) mx = fmaxf(mx, hs_s[t]);
    float ssum = 0.f;
    for (int t = 0; t < T_; ++t) ssum += expf(hs_s[t] - mx);
    float inv = 1.f / ssum;
    __syncthreads();
    if (tid < T_)
        hs_s[tid] = expf(hs_s[tid] - mx) * inv * (float)maskp[b * T_ + tid];
    __syncthreads();
    float a = 0.f;
    for (int t = 0; t < T_; ++t) a += hs_s[t] * hl[t][tid];
    red[tid] = a; __syncthreads();
    for (int o = 64; o > 0; o >>= 1) { if (tid < o) red[tid] += red[tid + o]; __syncthreads(); }
    float mu = red[0] * (1.f / 128.f);
    __syncthreads();
    float dv = a - mu;
    red[tid] = dv * dv; __syncthreads();
    for (int o = 64; o > 0; o >>= 1) { if (tid < o) red[tid] += red[tid + o]; __syncthreads(); }
    float rs = 1.f / sqrtf(red[0] * (1.f / 128.f) + 1e-8f);
    hsvn[(size_t)b * 128 + tid] = dv * rs * gldf(g, tid, det) + gldf(bb, tid, det);
}

// full attn (fallback path): includes linout + glu2
__global__ __launch_bounds__(128) void t_attn12(
    const void* __restrict__ item, const int* __restrict__ seq,
    const int* __restrict__ alias, const int* __restrict__ maskp,
    const float* __restrict__ feat, const void* __restrict__ xs,
    const void* __restrict__ q,
    const void* __restrict__ g, const void* __restrict__ bb,
    const void* __restrict__ lw, const void* __restrict__ lb,
    const void* __restrict__ gw, const int* __restrict__ fl,
    float* __restrict__ hall0, float* __restrict__ g2)
{
    __shared__ float hl[T_][129];
    __shared__ float qs[128];
    __shared__ float hs_s[T_];
    __shared__ float red[128];
    __shared__ float h1s[128];
    __shared__ float h2[128];
    const int b = blockIdx.x, tid = threadIdx.x;
    const int det = *fl;
    const float x = gldf(xs, 0, det);
    qs[tid] = gldf(q, tid, det);
    for (int t = 0; t < T_; ++t) {
        int bt = b * T_ + t;
        float v = gldf(item, (size_t)seq[bt] * 128 + tid, det) * x
                + feat[(size_t)alias[bt] * 128 + tid] * (float)maskp[bt];
        hl[t][tid] = v;
        hall0[(size_t)bt * 128 + tid] = v;
    }
    __syncthreads();
    if (tid < T_) {
        float a = 0.f;
        for (int d = 0; d < 128; ++d) a += hl[tid][d] * qs[d];
        hs_s[tid] = a;
    }
    __syncthreads();
    float mx = -1e30f;
    for (int t = 0; t < T_; ++t) mx = fmaxf(mx, hs_s[t]);
    float ssum = 0.f;
    for (int t = 0; t < T_; ++t) ssum += expf(hs_s[t] - mx);
    float inv = 1.f / ssum;
    __syncthreads();
    if (tid < T_)
        hs_s[tid] = expf(hs_s[tid] - mx) * inv * (float)maskp[b * T_ + tid];
    __syncthreads();
    float a = 0.f;
    for (int t = 0; t < T_; ++t) a += hs_s[t] * hl[t][tid];
    red[tid] = a; __syncthreads();
    for (int o = 64; o > 0; o >>= 1) { if (tid < o) red[tid] += red[tid + o]; __syncthreads(); }
    float mu = red[0] * (1.f / 128.f);
    __syncthreads();
    float dv = a - mu;
    red[tid] = dv * dv; __syncthreads();
    for (int o = 64; o > 0; o >>= 1) { if (tid < o) red[tid] += red[tid + o]; __syncthreads(); }
    float rs = 1.f / sqrtf(red[0] * (1.f / 128.f) + 1e-8f);
    h1s[tid] = dv * rs * gldf(g, tid, det) + gldf(bb, tid, det);
    __syncthreads();
    float a2 = gldf(lb, tid, det);
    for (int k = 0; k < 128; ++k)
        a2 += h1s[k] * gldf(lw, (size_t)k * 128 + tid, det);
    for (int k = 0; k < 128; ++k)
        a2 += hl[0][k] * gldf(lw, (size_t)(128 + k) * 128 + tid, det);
    h2[tid] = a2;
    __syncthreads();
    float g2v = 0.f;
    for (int k = 0; k < 128; ++k)
        g2v += h2[k] * gldf(gw, (size_t)k * 128 + tid, det);
    g2[(size_t)b * 128 + tid] = g2v;
}

__global__ __launch_bounds__(512) void t_nh(
    const void* __restrict__ pos, const float* __restrict__ hall0,
    const void* __restrict__ W, const int* __restrict__ fl,
    float* __restrict__ nh, int nrows)
{
    __shared__ float Ws[8192];
    __shared__ float hrow[16][256];
    const int det = *fl;
    const int tid = threadIdx.x, c = tid & 31, slot = tid >> 5;
    for (int base = blockIdx.x * 16; base < nrows; base += gridDim.x * 16) {
        const int n = base + slot;
        if (n < nrows) {
            const int t = n - (n / T_) * T_;
            for (int j = c; j < 128; j += 32) {
                hrow[slot][j]       = gldf(pos, (size_t)t * 128 + j, det);
                hrow[slot][128 + j] = hall0[(size_t)n * 128 + j];
            }
        }
        float4 acc = make_float4(0.f, 0.f, 0.f, 0.f);
        for (int kb = 0; kb < 256; kb += 64) {
            __syncthreads();
            for (int i = tid; i < 8192; i += 512) Ws[i] = gldf(W, (size_t)kb * 128 + i, det);
            __syncthreads();
            if (n < nrows) {
                #pragma unroll 8
                for (int k = 0; k < 64; ++k) {
                    float hv = hrow[slot][kb + k];
                    float4 w = *(const float4*)&Ws[k * 128 + c * 4];
                    acc.x += hv * w.x; acc.y += hv * w.y; acc.z += hv * w.z; acc.w += hv * w.w;
                }
            }
        }
        if (n < nrows) {
            float4 o;
            o.x = tanhf(acc.x); o.y = tanhf(acc.y); o.z = tanhf(acc.z); o.w = tanhf(acc.w);
            *(float4*)&nh[(size_t)n * 128 + c * 4] = o;
        }
        __syncthreads();
    }
}

__global__ __launch_bounds__(512) void t_glu_beta(
    const float* __restrict__ nh, const void* __restrict__ W, const void* __restrict__ gb,
    const float* __restrict__ g2, const void* __restrict__ w2, const int* __restrict__ mask,
    const int* __restrict__ fl, float* __restrict__ beta, int nrows)
{
    __shared__ float Ws[8192];
    __shared__ float hrow[16][128];
    const int det = *fl;
    const int tid = threadIdx.x, c = tid & 31, slot = tid >> 5;
    float4 gbv, w2v;
    gbv.x = gldf(gb, c * 4 + 0, det); gbv.y = gldf(gb, c * 4 + 1, det);
    gbv.z = gldf(gb, c * 4 + 2, det); gbv.w = gldf(gb, c * 4 + 3, det);
    w2v.x = gldf(w2, c * 4 + 0, det); w2v.y = gldf(w2, c * 4 + 1, det);
    w2v.z = gldf(w2, c * 4 + 2, det); w2v.w = gldf(w2, c * 4 + 3, det);
    for (int base = blockIdx.x * 16; base < nrows; base += gridDim.x * 16) {
        const int n = base + slot;
        if (n < nrows) for (int j = c; j < 128; j += 32) hrow[slot][j] = nh[(size_t)n * 128 + j];
        float4 acc = make_float4(0.f, 0.f, 0.f, 0.f);
        for (int kb = 0; kb < 128; kb += 64) {
            __syncthreads();
            for (int i = tid; i < 8192; i += 512) Ws[i] = gldf(W, (size_t)kb * 128 + i, det);
            __syncthreads();
            if (n < nrows) {
                #pragma unroll 8
                for (int k = 0; k < 64; ++k) {
                    float hv = hrow[slot][kb + k];
                    float4 w = *(const float4*)&Ws[k * 128 + c * 4];
                    acc.x += hv * w.x; acc.y += hv * w.y; acc.z += hv * w.z; acc.w += hv * w.w;
                }
            }
        }
        if (n < nrows) {
            const int b = n / T_;
            float4 gv = *(const float4*)&g2[(size_t)b * 128 + c * 4];
            float vx = sigm(acc.x + gbv.x + gv.x);
            float vy = sigm(acc.y + gbv.y + gv.y);
            float vz = sigm(acc.z + gbv.z + gv.z);
            float vw = sigm(acc.w + gbv.w + gv.w);
            float part = vx * w2v.x + vy * w2v.y + vz * w2v.z + vw * w2v.w;
            #pragma unroll
            for (int off = 16; off > 0; off >>= 1) part += __shfl_down(part, off, 32);
            if (c == 0) beta[n] = part * (float)mask[n];
        }
        __syncthreads();
    }
}

__global__ __launch_bounds__(128) void t_sel(
    const float* __restrict__ hall0, const float* __restrict__ beta,
    const void* __restrict__ g2, const void* __restrict__ b2,
    const float* __restrict__ feat, const int* __restrict__ lasti,
    const void* __restrict__ ys, const int* __restrict__ fl,
    float* __restrict__ hallf, float* __restrict__ fenmu, float* __restrict__ outh)
{
    __shared__ float bet[T_];
    __shared__ float red[128];
    const int b = blockIdx.x, tid = threadIdx.x;
    const int det = *fl;
    if (tid < T_) bet[tid] = beta[b * T_ + tid];
    __syncthreads();
    float acc = 0.f;
    for (int t = 0; t < T_; ++t) acc += bet[t] * hall0[((size_t)b * T_ + t) * 128 + tid];
    red[tid] = acc; __syncthreads();
    for (int off = 64; off > 0; off >>= 1) { if (tid < off) red[tid] += red[tid + off]; __syncthreads(); }
    float mu = red[0] * (1.f / 128.f);
    __syncthreads();
    float dv = acc - mu;
    red[tid] = dv * dv; __syncthreads();
    for (int off = 64; off > 0; off >>= 1) { if (tid < off) red[tid] += red[tid + off]; __syncthreads(); }
    float rs = 1.f / sqrtf(red[0] * (1.f / 128.f) + 1e-8f);
    __syncthreads();
    float h = dv * rs * gldf(g2, tid, det) + gldf(b2, tid, det)
            + feat[(size_t)lasti[b] * 128 + tid] * gldf(ys, 0, det);
    hallf[(size_t)b * 128 + tid] = h;
    outh[(size_t)b * 128 + tid] = h;
    red[tid] = h * h; __syncthreads();
    for (int off = 64; off > 0; off >>= 1) { if (tid < off) red[tid] += red[tid + off]; __syncthreads(); }
    if (tid == 0) fenmu[b] = sqrtf(red[0] + 128.f * 1e-6f);
}

__global__ __launch_bounds__(256) void t_cos(
    const float* __restrict__ hallf, const float* __restrict__ fenmu, float* __restrict__ out)
{
    __shared__ float hi[128];
    const int i = blockIdx.x, tid = threadIdx.x;
    if (tid < 128) hi[tid] = hallf[(size_t)i * 128 + tid];
    __syncthreads();
    const float fi = fenmu[i];
    for (int j = tid; j < B_; j += 256) {
        const float* hj = &hallf[(size_t)j * 128];
        float s = 0.f;
        for (int d = 0; d < 128; d += 4) {
            float4 a = *(const float4*)&hi[d];
            float4 bb = *(const float4*)&hj[d];
            s += a.x * bb.x + a.y * bb.y + a.z * bb.z + a.w * bb.w;
        }
        out[(size_t)i * B_ + j] = s / (fi * fenmu[j]);
    }
}

extern "C" void kernel_launch(void* const* d_in, const int* in_sizes, int n_in,
                              void* d_out, int out_size, void* d_ws, size_t ws_size,
                              hipStream_t stream)
{
    float* outf = (float*)d_out;
    const long OUT_N = (long)B_ * 128 + (long)B_ * B_;

    static const int EXP_SZ[41] = {
        12800000, 1280000, 25600, 32768, 131072, 1024, 1024, 1024, 32768, 128,
        32768, 128, 128, 32768, 128, 32768, 128, 16384, 128, 16384,
        128, 128, 128, 128, 1, 1, 100000, 100000, 10000, 800000,
        800000, 100000, 100000, 400000, 400000, 400000, 400000, 25600, 25600, 25600, 512 };
    float code = 0.f;
    if (n_in != 41) code = 90000.f + (float)n_in;
    else {
        for (int i = 0; i < 41; ++i)
            if (in_sizes[i] != EXP_SZ[i]) { code = 10000.f * (float)(i + 1); break; }
    }
    if (code == 0.f && out_size != (int)OUT_N) code = 95000.f;
    if (code != 0.f) {
        s_sig<<<dim3((unsigned)((OUT_N + 255) / 256)), dim3(256), 0, stream>>>(outf, OUT_N, code);
        return;
    }

    const void* item_emb = d_in[0];
    const void* cate_emb = d_in[1];
    const void* pos_emb  = d_in[2];
    const void* W_pos    = d_in[3];
    const void* gat_W    = d_in[4];
    const void* gat_al   = d_in[5];
    const void* gat_ar   = d_in[6];
    const void* gat_b    = d_in[7];
    const void* Wg1_w    = d_in[8];
    const void* Wg1_b    = d_in[9];
    const void* q        = d_in[12];
    const void* lin_w    = d_in[13];
    const void* lin_b    = d_in[14];
    const void* w_1      = d_in[15];
    const void* w_2      = d_in[16];
    const void* glu1_w   = d_in[17];
    const void* glu1_b   = d_in[18];
    const void* glu2_w   = d_in[19];
    const void* ln1_g    = d_in[20];
    const void* ln1_b    = d_in[21];
    const void* ln2_g    = d_in[22];
    const void* ln2_b    = d_in[23];
    const void* x_s      = d_in[24];
    const void* y_s      = d_in[25];
    const int* iid    = (const int*)d_in[26];
    const int* icate  = (const int*)d_in[27];
    const int* cid    = (const int*)d_in[28];
    const int* src_ii = (const int*)d_in[29];
    const int* dst_ii = (const int*)d_in[30];
    const int* src_cc = (const int*)d_in[31];
    const int* dst_cc = (const int*)d_in[32];
    const int* src_ci = (const int*)d_in[33];
    const int* dst_ci = (const int*)d_in[34];
    const int* src_ic = (const int*)d_in[35];
    const int* dst_ic = (const int*)d_in[36];
    const int* alias  = (const int*)d_in[37];
    const int* seq    = (const int*)d_in[38];
    const int* mask   = (const int*)d_in[39];
    const int* lasti  = (const int*)d_in[40];

    const size_t NEED_BASE = 64 + ((size_t)4 * NI_ + 3 * NC_) * 128 * 4
                                + ((size_t)3 * NI_ + 2 * NC_ + EII_) * 4;
    const size_t CSR_EXTRA = ((size_t)2 * (NI_ + 1) + 2 * (NC_ + 1)
                                + ECI_ + ECC_ + EIC_ + NI_) * 4;
    const size_t NEED_CSR = NEED_BASE + CSR_EXTRA;
    if (ws_size < NEED_BASE) {
        s_sig<<<dim3((unsigned)((OUT_N + 255) / 256)), dim3(256), 0, stream>>>(outf, OUT_N, 80000.f);
        return;
    }
    const bool useCSR = (ws_size >= NEED_CSR);
    const int mf = useCSR ? 1 : 0;

    int* flagp = (int*)d_ws;
    char* basep = (char*)d_ws;
    size_t off = 64;
    auto AL = [&](size_t nfl) { float* p = (float*)(basep + off); off += nfl * 4; return p; };
    float* hi0 = AL((size_t)NI_ * 128);
    float* HiA = AL((size_t)NI_ * 128);
    float* HiB = AL((size_t)NI_ * 128);   // binned edges during build | score scratch | L1 acc
    float* zA  = AL((size_t)NI_ * 128);   // two fp16 z's | feat fp32 later
    float* hc0 = AL((size_t)NC_ * 128);
    float* HcA = AL((size_t)NC_ * 128);
    float* zC  = AL((size_t)NC_ * 128);   // two fp16 z's
    float* sAl = AL(NI_); float* sAr = AL(NI_);
    float* sCl = AL(NC_); float* sCr = AL(NC_);
    float* denF = AL(NI_);          // fallback den | CSR: bcnt/bstart/gcur/wars, wt_lo@17408
    float* eF   = AL(EII_);         // fallback e   | CSR: colsrc_ii
    int* rpII = (int*)AL(NI_ + 1);
    int* rpCI = (int*)AL(NI_ + 1);
    int* rpCC = (int*)AL(NC_ + 1);
    int* rpIC = (int*)AL(NC_ + 1);
    int* csCI = (int*)AL(ECI_);
    int* csCC = (int*)AL(ECC_);
    int* csIC = (int*)AL(EIC_);
    int* wtregion = (int*)AL(NI_);  // wt_hi (320 KB)
    int* csII = (int*)eF;
    int* denFi = (int*)denF;
    int* bcnt   = denFi;                            // [0,432)
    int* bstart = denFi + 512;                      // [512,944)
    int* gcur   = denFi + 1024;                     // [1024,1456)
    float* wars = denF + 2048;                      // [2048,2432)
    u16* wt_hi = (u16*)wtregion;                    // 20480 slots * 16 B
    u16* wt_lo = (u16*)((char*)denF + 17408);
    __half* zAh  = (__half*)zA;
    __half* zA2h = zAh + (size_t)NI_ * 128;
    __half* zCh  = (__half*)zC;
    __half* zC2h = zCh + (size_t)NC_ * 128;
    // binned edge arrays (build-time) live in HiB
    u32* binII = (u32*)HiB;
    u32* binCI = binII + EII_;
    u32* binCC = binCI + ECI_;
    u32* binIC = binCC + ECC_;
    // layer-0 score scratch (after build) also in HiB
    float* sl03p = HiB;
    float* sr03s = HiB + NI_;
    float* sl02p = HiB + 2 * (size_t)NI_;
    float* sr02s = sl02p + NC_;
    // attention-phase packed weights (12288 slots hi+lo) live in dead HiA
    u16* wt2_hi = (u16*)HiA;
    u16* wt2_lo = wt2_hi + (size_t)12288 * 8;

    auto WTS = [&](int l, int k) {                  // slot base (u16 units) for gat_W (l,k)
        int midx = (l == 0) ? k : ((k == 0) ? 4 : 5);
        return (size_t)(8192 + midx * 2048) * 8;
    };

    float* feat = zA;
    float* hall0 = hi0;
    float* nh    = hall0 + (size_t)B_ * T_ * 128;
    float* vbuf  = nh    + (size_t)B_ * T_ * 128;
    float* hsb   = vbuf  + (size_t)B_ * T_ * 128;
    float* hsv   = hsb   + (size_t)B_ * T_;
    float* hsvn  = hsv   + (size_t)B_ * 128;
    float* hsv2  = hsvn  + (size_t)B_ * 128;
    float* g2b   = hsv2  + (size_t)B_ * 128;
    float* betab = g2b   + (size_t)B_ * 128;
    float* hallf = betab + (size_t)B_ * T_;
    float* fenmu = hallf + (size_t)B_ * 128;

    #define GRL(n) dim3((unsigned)(((long)(n) + 255) / 256))
    auto WOFF = [](int l, int k) { return (l * 4 + k) * 16384; };
    auto VOFF = [](int l, int k) { return (l * 4 + k) * 128; };

    auto seg = [&](const float* sl, const float* sr, const int* s, const int* d,
                   int E, int ndst, const __half* z, float* acc) {
        s_dinit<<<GRL(ndst), dim3(256), 0, stream>>>(denF, ndst);
        s_edge<<<GRL(E), dim3(256), 0, stream>>>(sl, sr, s, d, eF, denF, E);
        s_scatter<<<GRL((long)E * 128), dim3(256), 0, stream>>>(eF, denF, s, d, z, acc, E);
    };

    k_init<<<dim3(1), dim3(128), 0, stream>>>(item_emb, flagp, bcnt);

    if (useCSR) {
        const int ET = EII_ + ECI_ + ECC_ + EIC_;
        const int NBA = (ET + ECH_ - 1) / ECH_;
        k_pre<<<dim3(5083 + NBA), dim3(256), 0, stream>>>(
            cate_emb, cid, hc0,
            W_pos, Wg1_w, gat_W, wt_hi, wt_lo, gat_ar, wars,
            dst_ii, dst_ci, dst_cc, dst_ic, bcnt, flagp);
        k_bscan<<<dim3(1), dim3(1), 0, stream>>>(bcnt, bstart, gcur);
        k_binA<<<dim3(NBA), dim3(256), 0, stream>>>(
            src_ii, dst_ii, src_ci, dst_ci, src_cc, dst_cc, src_ic, dst_ic,
            gcur, binII, binCI, binCC, binIC);
        k_binB<<<dim3(NBK_), dim3(512), 0, stream>>>(
            bstart, bcnt, binII, binCI, binCC, binIC,
            rpII, rpCI, rpCC, rpIC, csII, csCI, csCC, csIC);
        // hi0 + both layer-0 item z-gemms, fused
        m_hi0zg<<<dim3((NI_ + 63) / 64), dim3(256), 0, stream>>>(
            item_emb, cate_emb, iid, icate,
            wt_hi, wt_lo,
            wt_hi + WTS(0, 0), wt_lo + WTS(0, 0), VOFF(0, 0), VOFF(0, 0),
            wt_hi + WTS(0, 3), wt_lo + WTS(0, 3), VOFF(0, 3), VOFF(0, 3),
            gat_al, gat_ar, flagp, flagp + 1,
            hi0, zAh, sAl, sAr, zA2h, sl03p, sr03s, NI_);
        m_zgemm2<<<dim3((NC_ + 63) / 64), dim3(256), 0, stream>>>(
            hc0, NC_,
            wt_hi + WTS(0, 1), wt_lo + WTS(0, 1), VOFF(0, 1), VOFF(0, 1), zC2h, sCl,   sCr,
            wt_hi + WTS(0, 2), wt_lo + WTS(0, 2), VOFF(0, 2), VOFF(0, 2), zCh,  sl02p, sr02s,
            gat_al, gat_ar, flagp, flagp + 1);
        // merged layer-0 aggs (item + cate)
        t_gat2<<<dim3((NI_ + 3) / 4 + (NC_ + 3) / 4), dim3(256), 0, stream>>>(
            rpII, csII, sAl, sAr, (const __half2*)zAh,
            rpCI, csCI, sl02p, wars + 0, (const __half2*)zCh,
            hi0, VOFF(0, 0), VOFF(0, 2), HiA,
            rpCC, csCC, sCl, sCr, (const __half2*)zC2h,
            rpIC, csIC, sl03p, wars + 128, (const __half2*)zA2h,
            hc0, VOFF(0, 1), VOFF(0, 3), HcA,
            gat_b, flagp);
        // merged layer-1 z-gemms
        m_zgemm_dual<<<dim3((NI_ + 63) / 64 + (NC_ + 63) / 64), dim3(256), 0, stream>>>(
            HiA, NI_, wt_hi + WTS(1, 0), wt_lo + WTS(1, 0), VOFF(1, 0), VOFF(1, 0), zAh, sAl, sAr,
            HcA, NC_, wt_hi + WTS(1, 2), wt_lo + WTS(1, 2), VOFF(1, 2), VOFF(1, 2), zCh, sCl, sCr,
            gat_al, gat_ar, flagp, flagp + 1);
        t_gat_fused<<<dim3((NI_ + 3) / 4), dim3(256), 0, stream>>>(
            rpII, csII, sAl, sAr, (const __half2*)zAh,
            rpCI, csCI, sCl, wars + 256, (const __half2*)zCh,
            HiA, gat_b, VOFF(1, 0), VOFF(1, 2), flagp, HiB, NI_);
        // HiA now dead: pack attention-phase weights into it
        k_prepw3<<<dim3(48), dim3(256), 0, stream>>>(w_1, glu1_w, lin_w, glu2_w, flagp, wt2_hi, wt2_lo);
        m_gatefeat<<<dim3((NI_ + 63) / 64), dim3(256), 0, stream>>>(
            hi0, HiB, wt_hi + (size_t)4096 * 8, wt_lo + (size_t)4096 * 8, Wg1_b, flagp, flagp + 1, feat, NI_);
        t_attn1n<<<dim3(B_), dim3(128), 0, stream>>>(
            item_emb, seq, alias, mask, feat, x_s, q, ln1_g, ln1_b, flagp, hall0, hsvn);
        m_lin<<<dim3((B_ + 63) / 64), dim3(256), 0, stream>>>(
            hsvn, hall0,
            wt2_hi + (size_t)6144 * 8, wt2_lo + (size_t)6144 * 8,
            wt2_hi + (size_t)10240 * 8, wt2_lo + (size_t)10240 * 8,
            lin_b, flagp, flagp + 1, g2b, B_);
        m_nhglu<<<dim3((B_ * T_ + 63) / 64), dim3(256), 0, stream>>>(
            pos_emb, hall0, wt2_hi, wt2_lo,
            wt2_hi + (size_t)4096 * 8, wt2_lo + (size_t)4096 * 8,
            glu1_b, g2b, w_2, mask, flagp, flagp + 1, betab, B_ * T_);
    } else {
        s_hc0<<<GRL((long)NC_ * 128), dim3(256), 0, stream>>>(cate_emb, cid, flagp, hc0);
        t_hi0<<<dim3(768), dim3(512), 0, stream>>>(item_emb, cate_emb, iid, icate, W_pos, flagp, hi0, NI_);
        s_initacc<<<GRL((long)NI_ * 128), dim3(256), 0, stream>>>(hi0, gat_b, VOFF(0, 0), VOFF(0, 2), flagp, HiA, (long)NI_ * 128);
        s_initacc<<<GRL((long)NC_ * 128), dim3(256), 0, stream>>>(hc0, gat_b, VOFF(0, 1), VOFF(0, 3), flagp, HcA, (long)NC_ * 128);
        t_zgemm<<<dim3(1024), dim3(512), 0, stream>>>(hi0, NI_, gat_W, WOFF(0, 0), gat_al, VOFF(0, 0), gat_ar, VOFF(0, 0), flagp, zAh, sAl, sAr);
        seg(sAl, sAr, src_ii, dst_ii, EII_, NI_, zAh, HiA);
        t_zgemm<<<dim3(625), dim3(512), 0, stream>>>(hc0, NC_, gat_W, WOFF(0, 2), gat_al, VOFF(0, 2), gat_ar, VOFF(0, 2), flagp, zCh, sCl, sCr);
        t_zgemm<<<dim3(1024), dim3(512), 0, stream>>>(hi0, NI_, gat_W, WOFF(0, 2), gat_al, VOFF(0, 2), gat_ar, VOFF(0, 2), flagp, zAh, sAl, sAr);
        seg(sCl, sAr, src_ci, dst_ci, ECI_, NI_, zCh, HiA);
        t_zgemm<<<dim3(625), dim3(512), 0, stream>>>(hc0, NC_, gat_W, WOFF(0, 1), gat_al, VOFF(0, 1), gat_ar, VOFF(0, 1), flagp, zCh, sCl, sCr);
        seg(sCl, sCr, src_cc, dst_cc, ECC_, NC_, zCh, HcA);
        t_zgemm<<<dim3(1024), dim3(512), 0, stream>>>(hi0, NI_, gat_W, WOFF(0, 3), gat_al, VOFF(0, 3), gat_ar, VOFF(0, 3), flagp, zAh, sAl, sAr);
        t_zgemm<<<dim3(625), dim3(512), 0, stream>>>(hc0, NC_, gat_W, WOFF(0, 3), gat_al, VOFF(0, 3), gat_ar, VOFF(0, 3), flagp, zCh, sCl, sCr);
        seg(sAl, sCr, src_ic, dst_ic, EIC_, NC_, zAh, HcA);
        s_initacc<<<GRL((long)NI_ * 128), dim3(256), 0, stream>>>(HiA, gat_b, VOFF(1, 0), VOFF(1, 2), flagp, HiB, (long)NI_ * 128);
        t_zgemm<<<dim3(1024), dim3(512), 0, stream>>>(HiA, NI_, gat_W, WOFF(1, 0), gat_al, VOFF(1, 0), gat_ar, VOFF(1, 0), flagp, zAh, sAl, sAr);
        seg(sAl, sAr, src_ii, dst_ii, EII_, NI_, zAh, HiB);
        t_zgemm<<<dim3(625), dim3(512), 0, stream>>>(HcA, NC_, gat_W, WOFF(1, 2), gat_al, VOFF(1, 2), gat_ar, VOFF(1, 2), flagp, zCh, sCl, sCr);
        t_zgemm<<<dim3(1024), dim3(512), 0, stream>>>(HiA, NI_, gat_W, WOFF(1, 2), gat_al, VOFF(1, 2), gat_ar, VOFF(1, 2), flagp, zAh, sAl, sAr);
        seg(sCl, sAr, src_ci, dst_ci, ECI_, NI_, zCh, HiB);
        t_gatefeat<<<dim3(768), dim3(512), 0, stream>>>(hi0, HiB, Wg1_w, Wg1_b, flagp, feat, NI_);
        t_attn12<<<dim3(B_), dim3(128), 0, stream>>>(
            item_emb, seq, alias, mask, feat, x_s, q,
            ln1_g, ln1_b, lin_w, lin_b, glu2_w, flagp, hall0, g2b);
        int grid = (B_ * T_ + 15) / 16; if (grid > 1024) grid = 1024;
        t_nh<<<dim3(grid), dim3(512), 0, stream>>>(pos_emb, hall0, w_1, flagp, nh, B_ * T_);
        t_glu_beta<<<dim3(grid), dim3(512), 0, stream>>>(nh, glu1_w, glu1_b, g2b, w_2, mask, flagp, betab, B_ * T_);
    }

    t_sel<<<dim3(B_), dim3(128), 0, stream>>>(hall0, betab, ln2_g, ln2_b, feat, lasti, y_s, flagp, hallf, fenmu, outf);
    t_cos<<<dim3(B_), dim3(256), 0, stream>>>(hallf, fenmu, outf + (size_t)B_ * 128);
}